// Round 2
// baseline (354.565 us; speedup 1.0000x reference)
//
#include <hip/hip_runtime.h>
#include <math.h>

// Problem constants: B=8, N=2048, K=32, 9 bins, width 20.
#define BB 8
#define NN 2048
#define KK 32

// ===========================================================================
// Exactly-rounded f32 helpers (no contraction): compute in double, round once.
// fmaf() is used wherever the referee's compiler (-ffp-contract=fast) fuses.
// ===========================================================================
__device__ __forceinline__ float fadd(float a, float b){ return (float)((double)a + (double)b); }
__device__ __forceinline__ float fsub(float a, float b){ return (float)((double)a - (double)b); }
__device__ __forceinline__ float fmul(float a, float b){ return (float)((double)a * (double)b); }
__device__ __forceinline__ float fdiv(float a, float b){ return (float)((double)a / (double)b); }
__device__ __forceinline__ float fsqrtf32(float a){ return (float)sqrt((double)a); }

// ===========================================================================
// LAPACK 3.12 single-precision helpers, gfortran -ffp-contract=fast model.
// ===========================================================================
__device__ float slapy2f(float x, float y) {
    float xa = fabsf(x), ya = fabsf(y);
    float w = fmaxf(xa, ya), z = fminf(xa, ya);
    if (z == 0.0f) return w;
    float q = fdiv(z, w);
    return fmul(w, fsqrtf32(fmaf(q, q, 1.0f)));
}

__device__ void slartgf(float f, float g, float& c, float& s, float& r) {
    if (g == 0.0f) { c = 1.0f; s = 0.0f; r = f; }
    else if (f == 0.0f) { c = 0.0f; s = copysignf(1.0f, g); r = fabsf(g); }
    else {
        float d = fsqrtf32(fmaf(f, f, fmul(g, g)));
        c = fdiv(fabsf(f), d);
        r = copysignf(d, f);
        s = fdiv(g, r);
    }
}

__device__ void slas2f(float f, float g, float h, float& ssmin, float& ssmax) {
    float fa = fabsf(f), ga = fabsf(g), ha = fabsf(h);
    float fhmn = fminf(fa, ha), fhmx = fmaxf(fa, ha);
    if (fhmn == 0.0f) {
        ssmin = 0.0f;
        if (fhmx == 0.0f) ssmax = ga;
        else {
            float mx = fmaxf(fhmx, ga), mn = fminf(fhmx, ga);
            float q = fdiv(mn, mx);
            ssmax = fmul(mx, fsqrtf32(fmaf(q, q, 1.0f)));
        }
    } else {
        if (ga < fhmx) {
            float as = fadd(1.0f, fdiv(fhmn, fhmx));
            float at = fdiv(fsub(fhmx, fhmn), fhmx);
            float q = fdiv(ga, fhmx); float au = fmul(q, q);
            float c = fdiv(2.0f, fadd(fsqrtf32(fmaf(as, as, au)),
                                      fsqrtf32(fmaf(at, at, au))));
            ssmin = fmul(fhmn, c); ssmax = fdiv(fhmx, c);
        } else {
            float au = fdiv(fhmx, ga);
            if (au == 0.0f) { ssmin = fdiv(fmul(fhmn, fhmx), ga); ssmax = ga; }
            else {
                float as = fadd(1.0f, fdiv(fhmn, fhmx));
                float at = fdiv(fsub(fhmx, fhmn), fhmx);
                float t1 = fmul(as, au), t2 = fmul(at, au);
                float c = fdiv(1.0f, fadd(fsqrtf32(fmaf(t1, t1, 1.0f)),
                                          fsqrtf32(fmaf(t2, t2, 1.0f))));
                ssmin = fmul(fmul(fhmn, c), au); ssmin = fadd(ssmin, ssmin);
                ssmax = fdiv(ga, fadd(c, c));
            }
        }
    }
}

__device__ void slasv2f(float f, float g, float h,
                        float& ssmin, float& ssmax,
                        float& snr, float& csr, float& snl, float& csl) {
    const float eps = 5.9604644775390625e-08f;
    float ft = f, fa = fabsf(f), ht = h, ha = fabsf(h);
    int pmax = 1;
    bool swp = (ha > fa);
    if (swp) { pmax = 3; float t = ft; ft = ht; ht = t; t = fa; fa = ha; ha = t; }
    float gt = g, ga = fabsf(gt);
    float clt = 0.f, crt = 0.f, slt = 0.f, srt = 0.f;
    if (ga == 0.0f) {
        ssmin = ha; ssmax = fa; clt = 1.0f; crt = 1.0f; slt = 0.0f; srt = 0.0f;
    } else {
        bool gasmal = true;
        if (ga > fa) {
            pmax = 2;
            if (fdiv(fa, ga) < eps) {
                gasmal = false;
                ssmax = ga;
                ssmin = (ha > 1.0f) ? fdiv(fa, fdiv(ga, ha)) : fmul(fdiv(fa, ga), ha);
                clt = 1.0f; slt = fdiv(ht, gt); srt = 1.0f; crt = fdiv(ft, gt);
            }
        }
        if (gasmal) {
            float dd = fsub(fa, ha);
            float l = (dd == fa) ? 1.0f : fdiv(dd, fa);
            float mm = fdiv(gt, ft);
            float t = fsub(2.0f, l);
            float m2 = fmul(mm, mm);
            float s = fsqrtf32(fmaf(t, t, m2));
            float r = (l == 0.0f) ? fabsf(mm) : fsqrtf32(fmaf(l, l, m2));
            float a = fmul(0.5f, fadd(s, r));
            ssmin = fdiv(ha, a);
            ssmax = fmul(fa, a);
            if (m2 == 0.0f) {
                t = (l == 0.0f) ? fmul(copysignf(2.0f, ft), copysignf(1.0f, gt))
                                : fadd(fdiv(gt, copysignf(dd, ft)), fdiv(mm, t));
            } else {
                t = fmul(fadd(fdiv(mm, fadd(s, t)), fdiv(mm, fadd(r, l))), fadd(1.0f, a));
            }
            float l2 = fsqrtf32(fmaf(t, t, 4.0f));
            crt = fdiv(2.0f, l2); srt = fdiv(t, l2);
            clt = fdiv(fmaf(srt, mm, crt), a);
            slt = fdiv(fmul(fdiv(ht, ft), srt), a);
        }
    }
    if (swp) { csl = srt; snl = crt; csr = slt; snr = clt; }
    else     { csl = clt; snl = slt; csr = crt; snr = srt; }
    float tsign = 0.0f;
    if (pmax == 1) tsign = fmul(fmul(copysignf(1.f, csr), copysignf(1.f, csl)), copysignf(1.f, f));
    if (pmax == 2) tsign = fmul(fmul(copysignf(1.f, snr), copysignf(1.f, csl)), copysignf(1.f, g));
    if (pmax == 3) tsign = fmul(fmul(copysignf(1.f, snr), copysignf(1.f, snl)), copysignf(1.f, h));
    ssmax = copysignf(fabsf(ssmax), tsign);
    ssmin = copysignf(fabsf(ssmin), fmul(tsign, fmul(copysignf(1.f, f), copysignf(1.f, h))));
}

// slasr 'L','V' rotation on vt rows lo,hi (1-indexed), fma-contracted
__device__ __forceinline__ void rot_rowsf(float vt[4][4], int lo, int hi, float cc, float ss) {
    #pragma unroll
    for (int c = 1; c <= 3; ++c) {
        float t = vt[hi][c];
        vt[hi][c] = fmaf(cc, t, -fmul(ss, vt[lo][c]));
        vt[lo][c] = fmaf(ss, t, fmul(cc, vt[lo][c]));
    }
}

// sbdsqr for n=3 upper bidiagonal. R9: idir2-shifted VT pairing REVERTED to
// (COSL, -SINL) — R8's (COSR,-SINR) regressed 0.0898->0.6455, proving the
// original Fortran reading (2nd slartg = VT side in bottom-up sweeps) right.
__device__ void bdsqr3f(float* d, float* e, float vt[4][4]) {
    const float eps  = 5.9604644775390625e-08f;
    const float unfl = 1.1754943508222875e-38f;
    const int n = 3;
    const float tol = fmul(10.0f, eps);
    float thresh;
    {
        float sminoa = fabsf(d[1]);
        if (sminoa != 0.0f) {
            float mu = sminoa;
            for (int i = 2; i <= n; ++i) {
                mu = fmul(fabsf(d[i]), fdiv(mu, fadd(mu, fabsf(e[i - 1]))));
                sminoa = fminf(sminoa, mu);
                if (sminoa == 0.0f) break;
            }
        }
        sminoa = fdiv(sminoa, fsqrtf32(3.0f));
        thresh = fmaxf(fmul(tol, sminoa), fmul(54.0f, unfl));
    }
    int m = n, iter = 0, oldll = -1, oldm = -1, idir = 0;
    float sminl = 0.0f;
    while (m > 1) {
        if (iter > 54) break;
        float smax = fabsf(d[m]);
        int ll = 0; bool split = false;
        for (int lll = 1; lll <= m - 1; ++lll) {
            int l2 = m - lll;
            float abss = fabsf(d[l2]), abse = fabsf(e[l2]);
            if (abse <= thresh) { ll = l2; split = true; break; }
            smax = fmaxf(smax, fmaxf(abss, abse));
        }
        if (split) {
            e[ll] = 0.0f;
            if (ll == m - 1) { m = m - 1; continue; }
            ll = ll + 1;
        } else ll = 1;
        if (ll == m - 1) {
            float sigmn, sigmx, sinr, cosr, sinl, cosl;
            slasv2f(d[m - 1], e[m - 1], d[m], sigmn, sigmx, sinr, cosr, sinl, cosl);
            d[m - 1] = sigmx; e[m - 1] = 0.0f; d[m] = sigmn;
            #pragma unroll
            for (int c = 1; c <= 3; ++c) {
                float t = fmaf(cosr, vt[m - 1][c], fmul(sinr, vt[m][c]));
                vt[m][c] = fmaf(cosr, vt[m][c], -fmul(sinr, vt[m - 1][c]));
                vt[m - 1][c] = t;
            }
            m -= 2; continue;
        }
        if (ll > oldm || m < oldll)
            idir = (fabsf(d[ll]) >= fabsf(d[m])) ? 1 : 2;
        bool deflated = false;
        if (idir == 1) {
            if (fabsf(e[m - 1]) <= fmul(tol, fabsf(d[m]))) { e[m - 1] = 0.0f; continue; }
            float mu = fabsf(d[ll]); sminl = mu;
            for (int lll = ll; lll <= m - 1; ++lll) {
                if (fabsf(e[lll]) <= fmul(tol, mu)) { e[lll] = 0.0f; deflated = true; break; }
                mu = fmul(fabsf(d[lll + 1]), fdiv(mu, fadd(mu, fabsf(e[lll]))));
                sminl = fminf(sminl, mu);
            }
        } else {
            if (fabsf(e[ll]) <= fmul(tol, fabsf(d[ll]))) { e[ll] = 0.0f; continue; }
            float mu = fabsf(d[m]); sminl = mu;
            for (int lll = m - 1; lll >= ll; --lll) {
                if (fabsf(e[lll]) <= fmul(tol, mu)) { e[lll] = 0.0f; deflated = true; break; }
                mu = fmul(fabsf(d[lll]), fdiv(mu, fadd(mu, fabsf(e[lll]))));
                sminl = fminf(sminl, mu);
            }
        }
        if (deflated) continue;
        oldll = ll; oldm = m;
        float shift = 0.0f, rr;
        if (!(fmul(fmul(3.0f, tol), fdiv(sminl, smax)) <= fmaxf(eps, fmul(0.01f, tol)))) {
            float sll;
            if (idir == 1) { sll = fabsf(d[ll]); slas2f(d[m - 1], e[m - 1], d[m], shift, rr); }
            else           { sll = fabsf(d[m]);  slas2f(d[ll], e[ll], d[ll + 1], shift, rr); }
            if (sll > 0.0f) { float q = fdiv(shift, sll); if (fmul(q, q) < eps) shift = 0.0f; }
        }
        iter += m - ll;
        float wc[4], ws[4];
        if (shift == 0.0f) {
            if (idir == 1) {
                float cs = 1.0f, oldcs = 1.0f, sn = 0.0f, oldsn = 0.0f, r2;
                for (int i = ll; i <= m - 1; ++i) {
                    slartgf(fmul(d[i], cs), e[i], cs, sn, r2);
                    if (i > ll) e[i - 1] = fmul(oldsn, r2);
                    slartgf(fmul(oldcs, r2), fmul(d[i + 1], sn), oldcs, oldsn, d[i]);
                    wc[i - ll + 1] = cs; ws[i - ll + 1] = sn;
                }
                float h = fmul(d[m], cs); d[m] = fmul(h, oldcs); e[m - 1] = fmul(h, oldsn);
                if (fabsf(e[m - 1]) <= thresh) e[m - 1] = 0.0f;
                for (int j = 1; j <= m - ll; ++j) rot_rowsf(vt, ll + j - 1, ll + j, wc[j], ws[j]);
            } else {
                float cs = 1.0f, oldcs = 1.0f, sn = 0.0f, oldsn = 0.0f, r2;
                for (int i = m; i >= ll + 1; --i) {
                    slartgf(fmul(d[i], cs), e[i - 1], cs, sn, r2);
                    if (i < m) e[i] = fmul(oldsn, r2);
                    slartgf(fmul(oldcs, r2), fmul(d[i - 1], sn), oldcs, oldsn, d[i]);
                    wc[i - ll] = oldcs; ws[i - ll] = -oldsn;
                }
                float h = fmul(d[ll], cs); d[ll] = fmul(h, oldcs); e[ll] = fmul(h, oldsn);
                if (fabsf(e[ll]) <= thresh) e[ll] = 0.0f;
                for (int j = m - ll; j >= 1; --j) rot_rowsf(vt, ll + j - 1, ll + j, wc[j], ws[j]);
            }
        } else {
            if (idir == 1) {
                float fq = fmul(fsub(fabsf(d[ll]), shift),
                                fadd(copysignf(1.0f, d[ll]), fdiv(shift, d[ll])));
                float g = e[ll], cosr, sinr, cosl, sinl, r2;
                for (int i = ll; i <= m - 1; ++i) {
                    slartgf(fq, g, cosr, sinr, r2);
                    if (i > ll) e[i - 1] = r2;
                    float di = d[i], ei = e[i], dip = d[i + 1];
                    fq         = fmaf(cosr, di, fmul(sinr, ei));
                    float ei_n = fmaf(cosr, ei, -fmul(sinr, di));
                    g = fmul(sinr, dip);
                    float dip_n = fmul(cosr, dip);
                    slartgf(fq, g, cosl, sinl, r2);
                    d[i] = r2;
                    fq       = fmaf(cosl, ei_n, fmul(sinl, dip_n));
                    d[i + 1] = fmaf(cosl, dip_n, -fmul(sinl, ei_n));
                    e[i] = ei_n;
                    if (i < m - 1) { g = fmul(sinl, e[i + 1]); e[i + 1] = fmul(cosl, e[i + 1]); }
                    wc[i - ll + 1] = cosr; ws[i - ll + 1] = sinr;
                }
                e[m - 1] = fq;
                if (fabsf(e[m - 1]) <= thresh) e[m - 1] = 0.0f;
                for (int j = 1; j <= m - ll; ++j) rot_rowsf(vt, ll + j - 1, ll + j, wc[j], ws[j]);
            } else {
                float fq = fmul(fsub(fabsf(d[m]), shift),
                                fadd(copysignf(1.0f, d[m]), fdiv(shift, d[m])));
                float g = e[m - 1], cosr, sinr, cosl, sinl, r2;
                for (int i = m; i >= ll + 1; --i) {
                    slartgf(fq, g, cosr, sinr, r2);
                    if (i < m) e[i] = r2;
                    float di = d[i], em = e[i - 1], dim = d[i - 1];
                    fq         = fmaf(cosr, di, fmul(sinr, em));
                    float em_n = fmaf(cosr, em, -fmul(sinr, di));
                    g = fmul(sinr, dim);
                    float dim_n = fmul(cosr, dim);
                    slartgf(fq, g, cosl, sinl, r2);
                    d[i] = r2;
                    fq       = fmaf(cosl, em_n, fmul(sinl, dim_n));
                    d[i - 1] = fmaf(cosl, dim_n, -fmul(sinl, em_n));
                    e[i - 1] = em_n;
                    if (i > ll + 1) { g = fmul(sinl, e[i - 2]); e[i - 2] = fmul(cosl, e[i - 2]); }
                    wc[i - ll] = cosl; ws[i - ll] = -sinl;   // REVERTED (correct per R8 regression)
                }
                e[ll] = fq;
                if (fabsf(e[ll]) <= thresh) e[ll] = 0.0f;
                for (int j = m - ll; j >= 1; --j) rot_rowsf(vt, ll + j - 1, ll + j, wc[j], ws[j]);
            }
        }
    }
    for (int i = 1; i <= n; ++i) {
        if (d[i] < 0.0f) {
            d[i] = -d[i];
            for (int c = 1; c <= 3; ++c) vt[i][c] = -vt[i][c];
        }
    }
    for (int i = 1; i <= n - 1; ++i) {
        int isub = 1; float smin2 = d[1];
        for (int j = 2; j <= n + 1 - i; ++j)
            if (d[j] <= smin2) { isub = j; smin2 = d[j]; }
        int tgt = n + 1 - i;
        if (isub != tgt) {
            d[isub] = d[tgt]; d[tgt] = smin2;
            for (int c = 1; c <= 3; ++c) { float t = vt[isub][c]; vt[isub][c] = vt[tgt][c]; vt[tgt][c] = t; }
        }
    }
}

// ===========================================================================
// Kernel 0: d2 in f32
// ===========================================================================
__global__ void d2_kernel(const float* __restrict__ x, float* __restrict__ d2) {
    int t = blockIdx.x * blockDim.x + threadIdx.x;
    if (t >= BB * NN) return;
    int b = t / NN, n = t % NN;
    const float* xb = x + b * 3 * NN;
    float xv = xb[n], yv = xb[NN + n], zv = xb[2 * NN + n];
    d2[t] = fadd(fadd(fmul(xv, xv), fmul(yv, yv)), fmul(zv, zv));
}

// ===========================================================================
// Kernel 1: KNN — R11: per-lane PRE-SORTED candidate lists (k-way merge).
//
// R10 post-mortem: DPP rewrite removed the DS pipe (450->177 µs, VALUBusy
// 100%). Remaining cost per extraction iter (~240 VALU): local 32-slot
// rescan (~93) + unrolled invalidation (~96), both recomputed although only
// the winner lane's state changes. R11 removes both:
//   - each lane Batcher-sorts its 32 u64 keys ONCE (191 comparators, ~950
//     VALU, paid once) — key = (sortable(val)<<32)|(2047-j), same unsigned
//     order (value desc, index asc) as the R10 tournament
//   - per iteration: lane's best is key[0] (no scan); DPP u64-max of heads
//     (identical 6-stage cascade); winner lane shift-down of its sorted list
//     (31 predicated 64-bit selects) replaces scan+invalidate
// Keys are unique (distinct j) => k-way merge of sorted lists extracts the
// EXACT same sequence as repeated global argmax. Ranks 1,2,3,31,32 near-tie
// probes unchanged.
// ===========================================================================
__device__ __forceinline__ unsigned int f32_sortable(float f) {
    unsigned int b = __float_as_uint(f);
    return b ^ ((unsigned int)((int)b >> 31) | 0x80000000u);
}
__device__ __forceinline__ float sortable_f32(unsigned int s) {
    unsigned int b = s ^ (~(unsigned int)((int)s >> 31) | 0x80000000u);
    return __uint_as_float(b);
}

template <int CTRL, int RM>
__device__ __forceinline__ unsigned long long dpp_umax64(unsigned long long k) {
    int nhi = __builtin_amdgcn_update_dpp(0, (int)(unsigned int)(k >> 32), CTRL, RM, 0xF, false);
    int nlo = __builtin_amdgcn_update_dpp(0, (int)(unsigned int)k,         CTRL, RM, 0xF, false);
    unsigned long long nk = ((unsigned long long)(unsigned int)nhi << 32) | (unsigned int)nlo;
    return nk > k ? nk : k;
}

__device__ __forceinline__ void cmpswap_desc(unsigned long long& a, unsigned long long& b) {
    // keep larger in a, smaller in b (v_cmp_lt_u64 + 4 cndmask)
    bool lt = a < b;
    unsigned long long mx = lt ? b : a;
    unsigned long long mn = lt ? a : b;
    a = mx; b = mn;
}

__global__ void __launch_bounds__(256) knn_kernel(const float* __restrict__ x,
                                                  const float* __restrict__ d2,
                                                  int* __restrict__ idx) {
    int lane = threadIdx.x & 63;
    int wid  = threadIdx.x >> 6;
    int row  = blockIdx.x * 4 + wid;
    int b = row / NN, i = row % NN;
    const float* xb  = x  + b * 3 * NN;
    const float* d2b = d2 + b * NN;

    float xi = xb[i], yi = xb[NN + i], zi = xb[2 * NN + i];
    float d2i = d2b[i];

    // 32 candidates per lane, packed u64 keys, static register indexing.
    // Arithmetic identical to R10 (bit-exact dot & sortable encode).
    unsigned long long key[32];
    #pragma unroll
    for (int s = 0; s < 32; ++s) {
        int j = s * 64 + lane;
        float dot = fmul(xi, xb[j]);
        dot = fmaf(yi, xb[NN + j], dot);
        dot = fmaf(zi, xb[2 * NN + j], dot);
        float v = fsub(fsub(fmul(2.0f, dot), d2i), d2b[j]);
        key[s] = ((unsigned long long)f32_sortable(v) << 32)
               | (unsigned int)(2047 - j);
    }

    // ---- Batcher odd-even mergesort, descending, fully static indices ----
    #pragma unroll
    for (int p = 1; p < 32; p <<= 1) {
        #pragma unroll
        for (int q = p; q >= 1; q >>= 1) {
            #pragma unroll
            for (int j = q % p; j + q < 32; j += 2 * q) {
                #pragma unroll
                for (int s = 0; s < q; ++s) {
                    if (s + j + q < 32 &&
                        (s + j) / (2 * p) == (s + j + q) / (2 * p))
                        cmpswap_desc(key[s + j], key[s + j + q]);
                }
            }
        }
    }

    int* idxrow = idx + row * KK;
    unsigned int c1v = 0, c2v = 0, c3v = 0, c31v = 0, c32v = 0;
    int c1i = 0, c2i = 0, c3i = 0, c31i = 0, c32i = 0;

    #pragma unroll 1
    for (int t = 0; t < KK + 1; ++t) {      // 33 ranks (32 + boundary probe)
        // lane's best remaining candidate is its sorted head — no scan
        unsigned long long k = key[0];

        // wave argmax, pure-VALU DPP cascade; lane 63 ends with the global max
        k = dpp_umax64<0x111, 0xF>(k);   // row_shr:1
        k = dpp_umax64<0x112, 0xF>(k);   // row_shr:2
        k = dpp_umax64<0x114, 0xF>(k);   // row_shr:4
        k = dpp_umax64<0x118, 0xF>(k);   // row_shr:8
        k = dpp_umax64<0x142, 0xA>(k);   // row_bcast:15 -> rows 1,3
        k = dpp_umax64<0x143, 0xC>(k);   // row_bcast:31 -> rows 2,3

        unsigned int wbest = (unsigned int)__builtin_amdgcn_readlane((int)(k >> 32), 63);
        unsigned int wlow  = (unsigned int)__builtin_amdgcn_readlane((int)(k & 0xFFFFFFFFull), 63);
        int wj = 2047 - (int)(wlow & 0x7FFu);
        unsigned long long wkey = ((unsigned long long)wbest << 32) | wlow;

        // winner lane consumes its head: shift sorted list down by one.
        // Keys unique => exactly one lane matches.
        bool amw = (key[0] == wkey);
        #pragma unroll
        for (int s = 0; s < 31; ++s) key[s] = amw ? key[s + 1] : key[s];
        key[31] = amw ? 0ull : key[31];   // sentinel 0 < sortable(-inf)<<32

        // record: ranks 1,2,3,31,32 are deferred for the near-tie probes
        if (t == 1)           { c1v = wbest;  c1i = wj; }
        else if (t == 2)      { c2v = wbest;  c2i = wj; }
        else if (t == 3)      { c3v = wbest;  c3i = wj; }
        else if (t == KK - 1) { c31v = wbest; c31i = wj; }
        else if (t == KK)     { c32v = wbest; c32i = wj; }
        else if (lane == 0)   idxrow[t] = wj;
    }

    if (lane == 0) {
        const float TIE = 4e-7f;
        float r1  = sortable_f32(c1v),  r2  = sortable_f32(c2v), r3 = sortable_f32(c3v);
        float r31 = sortable_f32(c31v), r32 = sortable_f32(c32v);
        if (fabsf(r1 - r2) < TIE) { int ti = c1i; c1i = c2i; c2i = ti; float tv = r1; r1 = r2; r2 = tv; }
        if (fabsf(r2 - r3) < TIE) { int ti = c2i; c2i = c3i; c3i = ti; float tv = r2; r2 = r3; r3 = tv; }
        idxrow[1] = c1i; idxrow[2] = c2i; idxrow[3] = c3i;
        idxrow[KK - 1] = (fabsf(r31 - r32) < TIE) ? c32i : c31i;
    }
}

// ===========================================================================
// Kernel 2: sgesdd emulation (R8 version: slarf1f, fmaf BLAS, f64 snrm2)
// ===========================================================================
__global__ void eig_kernel(const float* __restrict__ x, const int* __restrict__ idx,
                           float* __restrict__ grad, float* __restrict__ mag) {
    int t = blockIdx.x * blockDim.x + threadIdx.x;
    if (t >= BB * NN) return;
    int b = t / NN;
    const float* xb = x + b * 3 * NN;
    const int* id = idx + t * KK;

    float A[KK][3];
    float s0 = 0.f, s1 = 0.f, s2 = 0.f;
    for (int j = 0; j < KK; ++j) {
        int n = id[j];
        s0 = fadd(s0, xb[n]); s1 = fadd(s1, xb[NN + n]); s2 = fadd(s2, xb[2 * NN + n]);
    }
    float m0 = fdiv(s0, 32.f), m1 = fdiv(s1, 32.f), m2 = fdiv(s2, 32.f);
    for (int j = 0; j < KK; ++j) {
        int n = id[j];
        A[j][0] = fsub(xb[n], m0);
        A[j][1] = fsub(xb[NN + n], m1);
        A[j][2] = fsub(xb[2 * NN + n], m2);
    }

    // ---- sgeqr2 with slarf1f
    for (int i = 0; i < 3; ++i) {
        float alpha = A[i][i];
        double nacc = 0.0;
        for (int r = i + 1; r < KK; ++r) nacc += (double)A[r][i] * (double)A[r][i];
        float xnorm = (float)sqrt(nacc);
        if (xnorm != 0.0f) {
            float beta = -copysignf(slapy2f(alpha, xnorm), alpha);
            float tau  = fdiv(fsub(beta, alpha), beta);
            float scal = fdiv(1.0f, fsub(alpha, beta));
            for (int r = i + 1; r < KK; ++r) A[r][i] = fmul(A[r][i], scal);
            A[i][i] = beta;
            for (int j = i + 1; j < 3; ++j) {
                float acc = 0.0f;
                for (int r = i + 1; r < KK; ++r) acc = fmaf(A[r][i], A[r][j], acc);
                float w = fadd(acc, A[i][j]);
                A[i][j] = fmaf(-tau, w, A[i][j]);
                float temp = fmul(-tau, w);
                for (int r = i + 1; r < KK; ++r) A[r][j] = fmaf(A[r][i], temp, A[r][j]);
            }
        }
    }
    float B11 = A[0][0], B12 = A[0][1], B13 = A[0][2];
    float B22 = A[1][1], B23 = A[1][2], B33 = A[2][2];

    // ---- sgebd2 with slarf1f
    float d[4], e[3];
    float taup = 0.0f, v2p = 0.0f;
    d[1] = B11;
    float B32 = 0.0f;
    if (B13 != 0.0f) {
        float xn = fsqrtf32(fmul(B13, B13));
        float beta = -copysignf(slapy2f(B12, xn), B12);
        taup = fdiv(fsub(beta, B12), beta);
        float scal = fdiv(1.0f, fsub(B12, beta));
        v2p = fmul(B13, scal);
        e[1] = beta;
        float w2 = fadd(fmul(B23, v2p), B22);
        float w3 = fmul(B33, v2p);
        B22 = fmaf(-taup, w2, B22);
        B32 = fmul(-taup, w3);
        float tmp = fmul(-taup, v2p);
        B23 = fmaf(w2, tmp, B23);
        B33 = fmaf(w3, tmp, B33);
    } else e[1] = B12;
    if (B32 != 0.0f) {
        float xn = fsqrtf32(fmul(B32, B32));
        float beta = -copysignf(slapy2f(B22, xn), B22);
        float tauq = fdiv(fsub(beta, B22), beta);
        float scal = fdiv(1.0f, fsub(B22, beta));
        float v2 = fmul(B32, scal);
        d[2] = beta;
        float w = fadd(fmul(v2, B33), B23);
        B23 = fmaf(-tauq, w, B23);
        float tmp = fmul(-tauq, w);
        B33 = fmaf(v2, tmp, B33);
    } else d[2] = B22;
    e[2] = B23;
    d[3] = B33;

    // ---- sbdsqr with VT = I
    float vt[4][4];
    for (int r = 1; r <= 3; ++r)
        for (int c = 1; c <= 3; ++c) vt[r][c] = (r == c) ? 1.0f : 0.0f;
    bdsqr3f(d, e, vt);

    // ---- sormbr 'P','R','T' via slarf1f
    if (taup != 0.0f) {
        float tmp = fmul(-taup, v2p);
        for (int r = 1; r <= 3; ++r) {
            float w = fadd(fmul(vt[r][3], v2p), vt[r][2]);
            vt[r][2] = fmaf(-taup, w, vt[r][2]);
            vt[r][3] = fmaf(w, tmp, vt[r][3]);
        }
    }

    int im = 1;
    if (d[2] > d[im]) im = 2;
    if (d[3] > d[im]) im = 3;
    grad[t * 3 + 0] = vt[im][1];
    grad[t * 3 + 1] = vt[im][2];
    grad[t * 3 + 2] = vt[im][3];
    mag[t] = fsqrtf32(d[im]);
}

// ===========================================================================
// Kernel 3: HOG histogram, strict f32 replica (CR-f32 angles).
// ===========================================================================
__global__ void hist_kernel(const int* __restrict__ idx, const float* __restrict__ grad,
                            const float* __restrict__ mag, float* __restrict__ out) {
    int t = blockIdx.x * blockDim.x + threadIdx.x;
    if (t >= BB * NN) return;
    int b = t / NN, n = t % NN;
    const int* id = idx + t * KK;
    const float r2d = (float)(180.0 / M_PI);

    float h1[9][2], h2[9][2];
    #pragma unroll
    for (int q = 0; q < 9; ++q) { h1[q][0] = h1[q][1] = 0.f; h2[q][0] = h2[q][1] = 0.f; }

    for (int j = 0; j < KK; ++j) {
        int jj = b * NN + id[j];
        float gx = grad[jj * 3 + 0];
        float gy = grad[jj * 3 + 1];
        float gz = grad[jj * 3 + 2];
        float m  = mag[jj];

        float zen = (float)acos((double)gz);
        float zd  = fmul(zen, r2d);
        float q0  = fdiv(gy, gx);
        float azr = (float)atan((double)q0);
        float ad  = fmul(azr, r2d);

        float a0 = (zd != zd) ? -2147483648.0f : (float)(int)zd;
        float a1 = (ad != ad) ? -2147483648.0f : (float)(int)ad;

        #pragma unroll
        for (int c = 0; c < 2; ++c) {
            float a = (c == 0) ? a0 : a1;
            if (a < 0.0f) a = fadd(a, 180.0f);
            float tq = fdiv(a, 20.0f);
            float t2 = fsub(tq, 0.5f);
            float fb = floorf(t2);
            float bin = fmodf(fb, 9.0f); if (bin != 0.0f && bin < 0.0f) bin = fadd(bin, 9.0f);
            float b1 = fadd(bin, 1.0f);
            float b1m = fmodf(b1, 9.0f);
            float fc = fmul(20.0f, fadd(b1m, 0.5f));
            float df = fsub(fc, a);
            float rm = fmodf(df, 180.0f); if (rm != 0.0f && rm < 0.0f) rm = fadd(rm, 180.0f);
            float v1 = fdiv(fmul(m, rm), 20.0f);
            float sc = fmul(20.0f, fadd(bin, 0.5f));
            float ds = fsub(a, sc);
            float rm2 = fmodf(ds, 180.0f); if (rm2 != 0.0f && rm2 < 0.0f) rm2 = fadd(rm2, 180.0f);
            float v2 = fdiv(fmul(m, rm2), 20.0f);
            int bi = (int)bin;
            int b2 = bi + 1; if (b2 >= 9) b2 -= 9;
            h1[bi][c] = fadd(h1[bi][c], v1);
            h2[b2][c] = fadd(h2[b2][c], v2);
        }
    }

    float* o = out + b * (18 * NN) + n * 18;
    #pragma unroll
    for (int c = 0; c < 2; ++c) {
        float hist[9];
        #pragma unroll
        for (int q = 0; q < 9; ++q) hist[q] = fadd(h1[q][c], h2[q][c]);
        float acc = 0.0f;
        #pragma unroll
        for (int q = 0; q < 9; ++q) acc = fadd(acc, fmul(hist[q], hist[q]));
        float nr = fsqrtf32(acc);
        float den = fmaxf(nr, 1e-12f);
        #pragma unroll
        for (int q = 0; q < 9; ++q) o[q * 2 + c] = fdiv(hist[q], den);
    }
}

// ===========================================================================
extern "C" void kernel_launch(void* const* d_in, const int* in_sizes, int n_in,
                              void* d_out, int out_size, void* d_ws, size_t ws_size,
                              hipStream_t stream) {
    const float* x = (const float*)d_in[0];
    float* out = (float*)d_out;

    char* ws = (char*)d_ws;
    size_t off = 0;
    int* idx = (int*)(ws + off);        off += (size_t)BB * NN * KK * sizeof(int);
    float* d2 = (float*)(ws + off);     off += (size_t)BB * NN * sizeof(float);
    float* grad = (float*)(ws + off);   off += (size_t)BB * NN * 3 * sizeof(float);
    float* mag = (float*)(ws + off);

    d2_kernel <<<(BB * NN + 255) / 256, 256, 0, stream>>>(x, d2);
    knn_kernel<<<BB * NN / 4, 256, 0, stream>>>(x, d2, idx);
    eig_kernel<<<(BB * NN + 255) / 256, 256, 0, stream>>>(x, idx, grad, mag);
    hist_kernel<<<(BB * NN + 255) / 256, 256, 0, stream>>>(idx, grad, mag, out);
}

// Round 3
// 353.849 us; speedup vs baseline: 1.0020x; 1.0020x over previous
//
#include <hip/hip_runtime.h>
#include <math.h>

// Problem constants: B=8, N=2048, K=32, 9 bins, width 20.
#define BB 8
#define NN 2048
#define KK 32

// ===========================================================================
// Exactly-rounded f32 helpers (no contraction): compute in double, round once.
// fmaf() is used wherever the referee's compiler (-ffp-contract=fast) fuses.
// ===========================================================================
__device__ __forceinline__ float fadd(float a, float b){ return (float)((double)a + (double)b); }
__device__ __forceinline__ float fsub(float a, float b){ return (float)((double)a - (double)b); }
__device__ __forceinline__ float fmul(float a, float b){ return (float)((double)a * (double)b); }
__device__ __forceinline__ float fdiv(float a, float b){ return (float)((double)a / (double)b); }
__device__ __forceinline__ float fsqrtf32(float a){ return (float)sqrt((double)a); }

// ===========================================================================
// LAPACK 3.12 single-precision helpers, gfortran -ffp-contract=fast model.
// ===========================================================================
__device__ float slapy2f(float x, float y) {
    float xa = fabsf(x), ya = fabsf(y);
    float w = fmaxf(xa, ya), z = fminf(xa, ya);
    if (z == 0.0f) return w;
    float q = fdiv(z, w);
    return fmul(w, fsqrtf32(fmaf(q, q, 1.0f)));
}

__device__ void slartgf(float f, float g, float& c, float& s, float& r) {
    if (g == 0.0f) { c = 1.0f; s = 0.0f; r = f; }
    else if (f == 0.0f) { c = 0.0f; s = copysignf(1.0f, g); r = fabsf(g); }
    else {
        float d = fsqrtf32(fmaf(f, f, fmul(g, g)));
        c = fdiv(fabsf(f), d);
        r = copysignf(d, f);
        s = fdiv(g, r);
    }
}

__device__ void slas2f(float f, float g, float h, float& ssmin, float& ssmax) {
    float fa = fabsf(f), ga = fabsf(g), ha = fabsf(h);
    float fhmn = fminf(fa, ha), fhmx = fmaxf(fa, ha);
    if (fhmn == 0.0f) {
        ssmin = 0.0f;
        if (fhmx == 0.0f) ssmax = ga;
        else {
            float mx = fmaxf(fhmx, ga), mn = fminf(fhmx, ga);
            float q = fdiv(mn, mx);
            ssmax = fmul(mx, fsqrtf32(fmaf(q, q, 1.0f)));
        }
    } else {
        if (ga < fhmx) {
            float as = fadd(1.0f, fdiv(fhmn, fhmx));
            float at = fdiv(fsub(fhmx, fhmn), fhmx);
            float q = fdiv(ga, fhmx); float au = fmul(q, q);
            float c = fdiv(2.0f, fadd(fsqrtf32(fmaf(as, as, au)),
                                      fsqrtf32(fmaf(at, at, au))));
            ssmin = fmul(fhmn, c); ssmax = fdiv(fhmx, c);
        } else {
            float au = fdiv(fhmx, ga);
            if (au == 0.0f) { ssmin = fdiv(fmul(fhmn, fhmx), ga); ssmax = ga; }
            else {
                float as = fadd(1.0f, fdiv(fhmn, fhmx));
                float at = fdiv(fsub(fhmx, fhmn), fhmx);
                float t1 = fmul(as, au), t2 = fmul(at, au);
                float c = fdiv(1.0f, fadd(fsqrtf32(fmaf(t1, t1, 1.0f)),
                                          fsqrtf32(fmaf(t2, t2, 1.0f))));
                ssmin = fmul(fmul(fhmn, c), au); ssmin = fadd(ssmin, ssmin);
                ssmax = fdiv(ga, fadd(c, c));
            }
        }
    }
}

__device__ void slasv2f(float f, float g, float h,
                        float& ssmin, float& ssmax,
                        float& snr, float& csr, float& snl, float& csl) {
    const float eps = 5.9604644775390625e-08f;
    float ft = f, fa = fabsf(f), ht = h, ha = fabsf(h);
    int pmax = 1;
    bool swp = (ha > fa);
    if (swp) { pmax = 3; float t = ft; ft = ht; ht = t; t = fa; fa = ha; ha = t; }
    float gt = g, ga = fabsf(gt);
    float clt = 0.f, crt = 0.f, slt = 0.f, srt = 0.f;
    if (ga == 0.0f) {
        ssmin = ha; ssmax = fa; clt = 1.0f; crt = 1.0f; slt = 0.0f; srt = 0.0f;
    } else {
        bool gasmal = true;
        if (ga > fa) {
            pmax = 2;
            if (fdiv(fa, ga) < eps) {
                gasmal = false;
                ssmax = ga;
                ssmin = (ha > 1.0f) ? fdiv(fa, fdiv(ga, ha)) : fmul(fdiv(fa, ga), ha);
                clt = 1.0f; slt = fdiv(ht, gt); srt = 1.0f; crt = fdiv(ft, gt);
            }
        }
        if (gasmal) {
            float dd = fsub(fa, ha);
            float l = (dd == fa) ? 1.0f : fdiv(dd, fa);
            float mm = fdiv(gt, ft);
            float t = fsub(2.0f, l);
            float m2 = fmul(mm, mm);
            float s = fsqrtf32(fmaf(t, t, m2));
            float r = (l == 0.0f) ? fabsf(mm) : fsqrtf32(fmaf(l, l, m2));
            float a = fmul(0.5f, fadd(s, r));
            ssmin = fdiv(ha, a);
            ssmax = fmul(fa, a);
            if (m2 == 0.0f) {
                t = (l == 0.0f) ? fmul(copysignf(2.0f, ft), copysignf(1.0f, gt))
                                : fadd(fdiv(gt, copysignf(dd, ft)), fdiv(mm, t));
            } else {
                t = fmul(fadd(fdiv(mm, fadd(s, t)), fdiv(mm, fadd(r, l))), fadd(1.0f, a));
            }
            float l2 = fsqrtf32(fmaf(t, t, 4.0f));
            crt = fdiv(2.0f, l2); srt = fdiv(t, l2);
            clt = fdiv(fmaf(srt, mm, crt), a);
            slt = fdiv(fmul(fdiv(ht, ft), srt), a);
        }
    }
    if (swp) { csl = srt; snl = crt; csr = slt; snr = clt; }
    else     { csl = clt; snl = slt; csr = crt; snr = srt; }
    float tsign = 0.0f;
    if (pmax == 1) tsign = fmul(fmul(copysignf(1.f, csr), copysignf(1.f, csl)), copysignf(1.f, f));
    if (pmax == 2) tsign = fmul(fmul(copysignf(1.f, snr), copysignf(1.f, csl)), copysignf(1.f, g));
    if (pmax == 3) tsign = fmul(fmul(copysignf(1.f, snr), copysignf(1.f, snl)), copysignf(1.f, h));
    ssmax = copysignf(fabsf(ssmax), tsign);
    ssmin = copysignf(fabsf(ssmin), fmul(tsign, fmul(copysignf(1.f, f), copysignf(1.f, h))));
}

// slasr 'L','V' rotation on vt rows lo,hi (1-indexed), fma-contracted
__device__ __forceinline__ void rot_rowsf(float vt[4][4], int lo, int hi, float cc, float ss) {
    #pragma unroll
    for (int c = 1; c <= 3; ++c) {
        float t = vt[hi][c];
        vt[hi][c] = fmaf(cc, t, -fmul(ss, vt[lo][c]));
        vt[lo][c] = fmaf(ss, t, fmul(cc, vt[lo][c]));
    }
}

// sbdsqr for n=3 upper bidiagonal. R9: idir2-shifted VT pairing REVERTED to
// (COSL, -SINL) — R8's (COSR,-SINR) regressed 0.0898->0.6455, proving the
// original Fortran reading (2nd slartg = VT side in bottom-up sweeps) right.
__device__ void bdsqr3f(float* d, float* e, float vt[4][4]) {
    const float eps  = 5.9604644775390625e-08f;
    const float unfl = 1.1754943508222875e-38f;
    const int n = 3;
    const float tol = fmul(10.0f, eps);
    float thresh;
    {
        float sminoa = fabsf(d[1]);
        if (sminoa != 0.0f) {
            float mu = sminoa;
            for (int i = 2; i <= n; ++i) {
                mu = fmul(fabsf(d[i]), fdiv(mu, fadd(mu, fabsf(e[i - 1]))));
                sminoa = fminf(sminoa, mu);
                if (sminoa == 0.0f) break;
            }
        }
        sminoa = fdiv(sminoa, fsqrtf32(3.0f));
        thresh = fmaxf(fmul(tol, sminoa), fmul(54.0f, unfl));
    }
    int m = n, iter = 0, oldll = -1, oldm = -1, idir = 0;
    float sminl = 0.0f;
    while (m > 1) {
        if (iter > 54) break;
        float smax = fabsf(d[m]);
        int ll = 0; bool split = false;
        for (int lll = 1; lll <= m - 1; ++lll) {
            int l2 = m - lll;
            float abss = fabsf(d[l2]), abse = fabsf(e[l2]);
            if (abse <= thresh) { ll = l2; split = true; break; }
            smax = fmaxf(smax, fmaxf(abss, abse));
        }
        if (split) {
            e[ll] = 0.0f;
            if (ll == m - 1) { m = m - 1; continue; }
            ll = ll + 1;
        } else ll = 1;
        if (ll == m - 1) {
            float sigmn, sigmx, sinr, cosr, sinl, cosl;
            slasv2f(d[m - 1], e[m - 1], d[m], sigmn, sigmx, sinr, cosr, sinl, cosl);
            d[m - 1] = sigmx; e[m - 1] = 0.0f; d[m] = sigmn;
            #pragma unroll
            for (int c = 1; c <= 3; ++c) {
                float t = fmaf(cosr, vt[m - 1][c], fmul(sinr, vt[m][c]));
                vt[m][c] = fmaf(cosr, vt[m][c], -fmul(sinr, vt[m - 1][c]));
                vt[m - 1][c] = t;
            }
            m -= 2; continue;
        }
        if (ll > oldm || m < oldll)
            idir = (fabsf(d[ll]) >= fabsf(d[m])) ? 1 : 2;
        bool deflated = false;
        if (idir == 1) {
            if (fabsf(e[m - 1]) <= fmul(tol, fabsf(d[m]))) { e[m - 1] = 0.0f; continue; }
            float mu = fabsf(d[ll]); sminl = mu;
            for (int lll = ll; lll <= m - 1; ++lll) {
                if (fabsf(e[lll]) <= fmul(tol, mu)) { e[lll] = 0.0f; deflated = true; break; }
                mu = fmul(fabsf(d[lll + 1]), fdiv(mu, fadd(mu, fabsf(e[lll]))));
                sminl = fminf(sminl, mu);
            }
        } else {
            if (fabsf(e[ll]) <= fmul(tol, fabsf(d[ll]))) { e[ll] = 0.0f; continue; }
            float mu = fabsf(d[m]); sminl = mu;
            for (int lll = m - 1; lll >= ll; --lll) {
                if (fabsf(e[lll]) <= fmul(tol, mu)) { e[lll] = 0.0f; deflated = true; break; }
                mu = fmul(fabsf(d[lll]), fdiv(mu, fadd(mu, fabsf(e[lll]))));
                sminl = fminf(sminl, mu);
            }
        }
        if (deflated) continue;
        oldll = ll; oldm = m;
        float shift = 0.0f, rr;
        if (!(fmul(fmul(3.0f, tol), fdiv(sminl, smax)) <= fmaxf(eps, fmul(0.01f, tol)))) {
            float sll;
            if (idir == 1) { sll = fabsf(d[ll]); slas2f(d[m - 1], e[m - 1], d[m], shift, rr); }
            else           { sll = fabsf(d[m]);  slas2f(d[ll], e[ll], d[ll + 1], shift, rr); }
            if (sll > 0.0f) { float q = fdiv(shift, sll); if (fmul(q, q) < eps) shift = 0.0f; }
        }
        iter += m - ll;
        float wc[4], ws[4];
        if (shift == 0.0f) {
            if (idir == 1) {
                float cs = 1.0f, oldcs = 1.0f, sn = 0.0f, oldsn = 0.0f, r2;
                for (int i = ll; i <= m - 1; ++i) {
                    slartgf(fmul(d[i], cs), e[i], cs, sn, r2);
                    if (i > ll) e[i - 1] = fmul(oldsn, r2);
                    slartgf(fmul(oldcs, r2), fmul(d[i + 1], sn), oldcs, oldsn, d[i]);
                    wc[i - ll + 1] = cs; ws[i - ll + 1] = sn;
                }
                float h = fmul(d[m], cs); d[m] = fmul(h, oldcs); e[m - 1] = fmul(h, oldsn);
                if (fabsf(e[m - 1]) <= thresh) e[m - 1] = 0.0f;
                for (int j = 1; j <= m - ll; ++j) rot_rowsf(vt, ll + j - 1, ll + j, wc[j], ws[j]);
            } else {
                float cs = 1.0f, oldcs = 1.0f, sn = 0.0f, oldsn = 0.0f, r2;
                for (int i = m; i >= ll + 1; --i) {
                    slartgf(fmul(d[i], cs), e[i - 1], cs, sn, r2);
                    if (i < m) e[i] = fmul(oldsn, r2);
                    slartgf(fmul(oldcs, r2), fmul(d[i - 1], sn), oldcs, oldsn, d[i]);
                    wc[i - ll] = oldcs; ws[i - ll] = -oldsn;
                }
                float h = fmul(d[ll], cs); d[ll] = fmul(h, oldcs); e[ll] = fmul(h, oldsn);
                if (fabsf(e[ll]) <= thresh) e[ll] = 0.0f;
                for (int j = m - ll; j >= 1; --j) rot_rowsf(vt, ll + j - 1, ll + j, wc[j], ws[j]);
            }
        } else {
            if (idir == 1) {
                float fq = fmul(fsub(fabsf(d[ll]), shift),
                                fadd(copysignf(1.0f, d[ll]), fdiv(shift, d[ll])));
                float g = e[ll], cosr, sinr, cosl, sinl, r2;
                for (int i = ll; i <= m - 1; ++i) {
                    slartgf(fq, g, cosr, sinr, r2);
                    if (i > ll) e[i - 1] = r2;
                    float di = d[i], ei = e[i], dip = d[i + 1];
                    fq         = fmaf(cosr, di, fmul(sinr, ei));
                    float ei_n = fmaf(cosr, ei, -fmul(sinr, di));
                    g = fmul(sinr, dip);
                    float dip_n = fmul(cosr, dip);
                    slartgf(fq, g, cosl, sinl, r2);
                    d[i] = r2;
                    fq       = fmaf(cosl, ei_n, fmul(sinl, dip_n));
                    d[i + 1] = fmaf(cosl, dip_n, -fmul(sinl, ei_n));
                    e[i] = ei_n;
                    if (i < m - 1) { g = fmul(sinl, e[i + 1]); e[i + 1] = fmul(cosl, e[i + 1]); }
                    wc[i - ll + 1] = cosr; ws[i - ll + 1] = sinr;
                }
                e[m - 1] = fq;
                if (fabsf(e[m - 1]) <= thresh) e[m - 1] = 0.0f;
                for (int j = 1; j <= m - ll; ++j) rot_rowsf(vt, ll + j - 1, ll + j, wc[j], ws[j]);
            } else {
                float fq = fmul(fsub(fabsf(d[m]), shift),
                                fadd(copysignf(1.0f, d[m]), fdiv(shift, d[m])));
                float g = e[m - 1], cosr, sinr, cosl, sinl, r2;
                for (int i = m; i >= ll + 1; --i) {
                    slartgf(fq, g, cosr, sinr, r2);
                    if (i < m) e[i] = r2;
                    float di = d[i], em = e[i - 1], dim = d[i - 1];
                    fq         = fmaf(cosr, di, fmul(sinr, em));
                    float em_n = fmaf(cosr, em, -fmul(sinr, di));
                    g = fmul(sinr, dim);
                    float dim_n = fmul(cosr, dim);
                    slartgf(fq, g, cosl, sinl, r2);
                    d[i] = r2;
                    fq       = fmaf(cosl, em_n, fmul(sinl, dim_n));
                    d[i - 1] = fmaf(cosl, dim_n, -fmul(sinl, em_n));
                    e[i - 1] = em_n;
                    if (i > ll + 1) { g = fmul(sinl, e[i - 2]); e[i - 2] = fmul(cosl, e[i - 2]); }
                    wc[i - ll] = cosl; ws[i - ll] = -sinl;   // REVERTED (correct per R8 regression)
                }
                e[ll] = fq;
                if (fabsf(e[ll]) <= thresh) e[ll] = 0.0f;
                for (int j = m - ll; j >= 1; --j) rot_rowsf(vt, ll + j - 1, ll + j, wc[j], ws[j]);
            }
        }
    }
    for (int i = 1; i <= n; ++i) {
        if (d[i] < 0.0f) {
            d[i] = -d[i];
            for (int c = 1; c <= 3; ++c) vt[i][c] = -vt[i][c];
        }
    }
    for (int i = 1; i <= n - 1; ++i) {
        int isub = 1; float smin2 = d[1];
        for (int j = 2; j <= n + 1 - i; ++j)
            if (d[j] <= smin2) { isub = j; smin2 = d[j]; }
        int tgt = n + 1 - i;
        if (isub != tgt) {
            d[isub] = d[tgt]; d[tgt] = smin2;
            for (int c = 1; c <= 3; ++c) { float t = vt[isub][c]; vt[isub][c] = vt[tgt][c]; vt[tgt][c] = t; }
        }
    }
}

// ===========================================================================
// Kernel 0: d2 in f32
// ===========================================================================
__global__ void d2_kernel(const float* __restrict__ x, float* __restrict__ d2) {
    int t = blockIdx.x * blockDim.x + threadIdx.x;
    if (t >= BB * NN) return;
    int b = t / NN, n = t % NN;
    const float* xb = x + b * 3 * NN;
    float xv = xb[n], yv = xb[NN + n], zv = xb[2 * NN + n];
    d2[t] = fadd(fadd(fmul(xv, xv), fmul(yv, yv)), fmul(zv, zv));
}

// ===========================================================================
// Kernel 1: KNN — R12: R11's sorted-list merge + REGISTER BUDGET FIX.
//
// R11 post-mortem: algorithm cut static VALU ~13.3K->~5.3K/wave but
// __launch_bounds__(256) let the compiler cap VGPRs at 64 — exactly the key
// array's size — so ~25 live values spilled to scratch; the per-iter RMW of
// the (partially spilled) key array turned the kernel latency-bound
// (VALUBusy 100->66%, dur 177->222 µs). FETCH_SIZE ~unchanged (+43 KB):
// scratch stayed L2-resident, invisible in HBM counters, visible as stall.
//
// Fix: __launch_bounds__(256, 4) -> VGPR cap 128 (need ~90). 4 waves/SIMD
// is ample TLP for a dependency-free cndmask stream (R10 saturated issue
// with the same style). Plus: winner detection via LOW 32 bits only
// (2047-j is globally unique) — v_cmp_eq_u32 instead of u64.
// ===========================================================================
__device__ __forceinline__ unsigned int f32_sortable(float f) {
    unsigned int b = __float_as_uint(f);
    return b ^ ((unsigned int)((int)b >> 31) | 0x80000000u);
}
__device__ __forceinline__ float sortable_f32(unsigned int s) {
    unsigned int b = s ^ (~(unsigned int)((int)s >> 31) | 0x80000000u);
    return __uint_as_float(b);
}

template <int CTRL, int RM>
__device__ __forceinline__ unsigned long long dpp_umax64(unsigned long long k) {
    int nhi = __builtin_amdgcn_update_dpp(0, (int)(unsigned int)(k >> 32), CTRL, RM, 0xF, false);
    int nlo = __builtin_amdgcn_update_dpp(0, (int)(unsigned int)k,         CTRL, RM, 0xF, false);
    unsigned long long nk = ((unsigned long long)(unsigned int)nhi << 32) | (unsigned int)nlo;
    return nk > k ? nk : k;
}

__device__ __forceinline__ void cmpswap_desc(unsigned long long& a, unsigned long long& b) {
    // keep larger in a, smaller in b (v_cmp_lt_u64 + 4 cndmask)
    bool lt = a < b;
    unsigned long long mx = lt ? b : a;
    unsigned long long mn = lt ? a : b;
    a = mx; b = mn;
}

__global__ void __launch_bounds__(256, 4) knn_kernel(const float* __restrict__ x,
                                                     const float* __restrict__ d2,
                                                     int* __restrict__ idx) {
    int lane = threadIdx.x & 63;
    int wid  = threadIdx.x >> 6;
    int row  = blockIdx.x * 4 + wid;
    int b = row / NN, i = row % NN;
    const float* xb  = x  + b * 3 * NN;
    const float* d2b = d2 + b * NN;

    float xi = xb[i], yi = xb[NN + i], zi = xb[2 * NN + i];
    float d2i = d2b[i];

    // 32 candidates per lane, packed u64 keys, static register indexing.
    // Arithmetic identical to R10 (bit-exact dot & sortable encode).
    unsigned long long key[32];
    #pragma unroll
    for (int s = 0; s < 32; ++s) {
        int j = s * 64 + lane;
        float dot = fmul(xi, xb[j]);
        dot = fmaf(yi, xb[NN + j], dot);
        dot = fmaf(zi, xb[2 * NN + j], dot);
        float v = fsub(fsub(fmul(2.0f, dot), d2i), d2b[j]);
        key[s] = ((unsigned long long)f32_sortable(v) << 32)
               | (unsigned int)(2047 - j);
    }

    // ---- Batcher odd-even mergesort, descending, fully static indices ----
    #pragma unroll
    for (int p = 1; p < 32; p <<= 1) {
        #pragma unroll
        for (int q = p; q >= 1; q >>= 1) {
            #pragma unroll
            for (int j = q % p; j + q < 32; j += 2 * q) {
                #pragma unroll
                for (int s = 0; s < q; ++s) {
                    if (s + j + q < 32 &&
                        (s + j) / (2 * p) == (s + j + q) / (2 * p))
                        cmpswap_desc(key[s + j], key[s + j + q]);
                }
            }
        }
    }

    int* idxrow = idx + row * KK;
    unsigned int c1v = 0, c2v = 0, c3v = 0, c31v = 0, c32v = 0;
    int c1i = 0, c2i = 0, c3i = 0, c31i = 0, c32i = 0;

    #pragma unroll 1
    for (int t = 0; t < KK + 1; ++t) {      // 33 ranks (32 + boundary probe)
        // lane's best remaining candidate is its sorted head — no scan
        unsigned long long k = key[0];

        // wave argmax, pure-VALU DPP cascade; lane 63 ends with the global max
        k = dpp_umax64<0x111, 0xF>(k);   // row_shr:1
        k = dpp_umax64<0x112, 0xF>(k);   // row_shr:2
        k = dpp_umax64<0x114, 0xF>(k);   // row_shr:4
        k = dpp_umax64<0x118, 0xF>(k);   // row_shr:8
        k = dpp_umax64<0x142, 0xA>(k);   // row_bcast:15 -> rows 1,3
        k = dpp_umax64<0x143, 0xC>(k);   // row_bcast:31 -> rows 2,3

        unsigned int wbest = (unsigned int)__builtin_amdgcn_readlane((int)(k >> 32), 63);
        unsigned int wlow  = (unsigned int)__builtin_amdgcn_readlane((int)(k & 0xFFFFFFFFull), 63);
        int wj = 2047 - (int)(wlow & 0x7FFu);

        // winner lane consumes its head: shift sorted list down by one.
        // Low words (2047-j) are globally unique => 32-bit compare suffices.
        bool amw = ((unsigned int)key[0] == wlow);
        #pragma unroll
        for (int s = 0; s < 31; ++s) key[s] = amw ? key[s + 1] : key[s];
        key[31] = amw ? 0ull : key[31];   // sentinel 0 < sortable(-inf)<<32

        // record: ranks 1,2,3,31,32 are deferred for the near-tie probes
        if (t == 1)           { c1v = wbest;  c1i = wj; }
        else if (t == 2)      { c2v = wbest;  c2i = wj; }
        else if (t == 3)      { c3v = wbest;  c3i = wj; }
        else if (t == KK - 1) { c31v = wbest; c31i = wj; }
        else if (t == KK)     { c32v = wbest; c32i = wj; }
        else if (lane == 0)   idxrow[t] = wj;
    }

    if (lane == 0) {
        const float TIE = 4e-7f;
        float r1  = sortable_f32(c1v),  r2  = sortable_f32(c2v), r3 = sortable_f32(c3v);
        float r31 = sortable_f32(c31v), r32 = sortable_f32(c32v);
        if (fabsf(r1 - r2) < TIE) { int ti = c1i; c1i = c2i; c2i = ti; float tv = r1; r1 = r2; r2 = tv; }
        if (fabsf(r2 - r3) < TIE) { int ti = c2i; c2i = c3i; c3i = ti; float tv = r2; r2 = r3; r3 = tv; }
        idxrow[1] = c1i; idxrow[2] = c2i; idxrow[3] = c3i;
        idxrow[KK - 1] = (fabsf(r31 - r32) < TIE) ? c32i : c31i;
    }
}

// ===========================================================================
// Kernel 2: sgesdd emulation (R8 version: slarf1f, fmaf BLAS, f64 snrm2)
// ===========================================================================
__global__ void eig_kernel(const float* __restrict__ x, const int* __restrict__ idx,
                           float* __restrict__ grad, float* __restrict__ mag) {
    int t = blockIdx.x * blockDim.x + threadIdx.x;
    if (t >= BB * NN) return;
    int b = t / NN;
    const float* xb = x + b * 3 * NN;
    const int* id = idx + t * KK;

    float A[KK][3];
    float s0 = 0.f, s1 = 0.f, s2 = 0.f;
    for (int j = 0; j < KK; ++j) {
        int n = id[j];
        s0 = fadd(s0, xb[n]); s1 = fadd(s1, xb[NN + n]); s2 = fadd(s2, xb[2 * NN + n]);
    }
    float m0 = fdiv(s0, 32.f), m1 = fdiv(s1, 32.f), m2 = fdiv(s2, 32.f);
    for (int j = 0; j < KK; ++j) {
        int n = id[j];
        A[j][0] = fsub(xb[n], m0);
        A[j][1] = fsub(xb[NN + n], m1);
        A[j][2] = fsub(xb[2 * NN + n], m2);
    }

    // ---- sgeqr2 with slarf1f
    for (int i = 0; i < 3; ++i) {
        float alpha = A[i][i];
        double nacc = 0.0;
        for (int r = i + 1; r < KK; ++r) nacc += (double)A[r][i] * (double)A[r][i];
        float xnorm = (float)sqrt(nacc);
        if (xnorm != 0.0f) {
            float beta = -copysignf(slapy2f(alpha, xnorm), alpha);
            float tau  = fdiv(fsub(beta, alpha), beta);
            float scal = fdiv(1.0f, fsub(alpha, beta));
            for (int r = i + 1; r < KK; ++r) A[r][i] = fmul(A[r][i], scal);
            A[i][i] = beta;
            for (int j = i + 1; j < 3; ++j) {
                float acc = 0.0f;
                for (int r = i + 1; r < KK; ++r) acc = fmaf(A[r][i], A[r][j], acc);
                float w = fadd(acc, A[i][j]);
                A[i][j] = fmaf(-tau, w, A[i][j]);
                float temp = fmul(-tau, w);
                for (int r = i + 1; r < KK; ++r) A[r][j] = fmaf(A[r][i], temp, A[r][j]);
            }
        }
    }
    float B11 = A[0][0], B12 = A[0][1], B13 = A[0][2];
    float B22 = A[1][1], B23 = A[1][2], B33 = A[2][2];

    // ---- sgebd2 with slarf1f
    float d[4], e[3];
    float taup = 0.0f, v2p = 0.0f;
    d[1] = B11;
    float B32 = 0.0f;
    if (B13 != 0.0f) {
        float xn = fsqrtf32(fmul(B13, B13));
        float beta = -copysignf(slapy2f(B12, xn), B12);
        taup = fdiv(fsub(beta, B12), beta);
        float scal = fdiv(1.0f, fsub(B12, beta));
        v2p = fmul(B13, scal);
        e[1] = beta;
        float w2 = fadd(fmul(B23, v2p), B22);
        float w3 = fmul(B33, v2p);
        B22 = fmaf(-taup, w2, B22);
        B32 = fmul(-taup, w3);
        float tmp = fmul(-taup, v2p);
        B23 = fmaf(w2, tmp, B23);
        B33 = fmaf(w3, tmp, B33);
    } else e[1] = B12;
    if (B32 != 0.0f) {
        float xn = fsqrtf32(fmul(B32, B32));
        float beta = -copysignf(slapy2f(B22, xn), B22);
        float tauq = fdiv(fsub(beta, B22), beta);
        float scal = fdiv(1.0f, fsub(B22, beta));
        float v2 = fmul(B32, scal);
        d[2] = beta;
        float w = fadd(fmul(v2, B33), B23);
        B23 = fmaf(-tauq, w, B23);
        float tmp = fmul(-tauq, w);
        B33 = fmaf(v2, tmp, B33);
    } else d[2] = B22;
    e[2] = B23;
    d[3] = B33;

    // ---- sbdsqr with VT = I
    float vt[4][4];
    for (int r = 1; r <= 3; ++r)
        for (int c = 1; c <= 3; ++c) vt[r][c] = (r == c) ? 1.0f : 0.0f;
    bdsqr3f(d, e, vt);

    // ---- sormbr 'P','R','T' via slarf1f
    if (taup != 0.0f) {
        float tmp = fmul(-taup, v2p);
        for (int r = 1; r <= 3; ++r) {
            float w = fadd(fmul(vt[r][3], v2p), vt[r][2]);
            vt[r][2] = fmaf(-taup, w, vt[r][2]);
            vt[r][3] = fmaf(w, tmp, vt[r][3]);
        }
    }

    int im = 1;
    if (d[2] > d[im]) im = 2;
    if (d[3] > d[im]) im = 3;
    grad[t * 3 + 0] = vt[im][1];
    grad[t * 3 + 1] = vt[im][2];
    grad[t * 3 + 2] = vt[im][3];
    mag[t] = fsqrtf32(d[im]);
}

// ===========================================================================
// Kernel 3: HOG histogram, strict f32 replica (CR-f32 angles).
// ===========================================================================
__global__ void hist_kernel(const int* __restrict__ idx, const float* __restrict__ grad,
                            const float* __restrict__ mag, float* __restrict__ out) {
    int t = blockIdx.x * blockDim.x + threadIdx.x;
    if (t >= BB * NN) return;
    int b = t / NN, n = t % NN;
    const int* id = idx + t * KK;
    const float r2d = (float)(180.0 / M_PI);

    float h1[9][2], h2[9][2];
    #pragma unroll
    for (int q = 0; q < 9; ++q) { h1[q][0] = h1[q][1] = 0.f; h2[q][0] = h2[q][1] = 0.f; }

    for (int j = 0; j < KK; ++j) {
        int jj = b * NN + id[j];
        float gx = grad[jj * 3 + 0];
        float gy = grad[jj * 3 + 1];
        float gz = grad[jj * 3 + 2];
        float m  = mag[jj];

        float zen = (float)acos((double)gz);
        float zd  = fmul(zen, r2d);
        float q0  = fdiv(gy, gx);
        float azr = (float)atan((double)q0);
        float ad  = fmul(azr, r2d);

        float a0 = (zd != zd) ? -2147483648.0f : (float)(int)zd;
        float a1 = (ad != ad) ? -2147483648.0f : (float)(int)ad;

        #pragma unroll
        for (int c = 0; c < 2; ++c) {
            float a = (c == 0) ? a0 : a1;
            if (a < 0.0f) a = fadd(a, 180.0f);
            float tq = fdiv(a, 20.0f);
            float t2 = fsub(tq, 0.5f);
            float fb = floorf(t2);
            float bin = fmodf(fb, 9.0f); if (bin != 0.0f && bin < 0.0f) bin = fadd(bin, 9.0f);
            float b1 = fadd(bin, 1.0f);
            float b1m = fmodf(b1, 9.0f);
            float fc = fmul(20.0f, fadd(b1m, 0.5f));
            float df = fsub(fc, a);
            float rm = fmodf(df, 180.0f); if (rm != 0.0f && rm < 0.0f) rm = fadd(rm, 180.0f);
            float v1 = fdiv(fmul(m, rm), 20.0f);
            float sc = fmul(20.0f, fadd(bin, 0.5f));
            float ds = fsub(a, sc);
            float rm2 = fmodf(ds, 180.0f); if (rm2 != 0.0f && rm2 < 0.0f) rm2 = fadd(rm2, 180.0f);
            float v2 = fdiv(fmul(m, rm2), 20.0f);
            int bi = (int)bin;
            int b2 = bi + 1; if (b2 >= 9) b2 -= 9;
            h1[bi][c] = fadd(h1[bi][c], v1);
            h2[b2][c] = fadd(h2[b2][c], v2);
        }
    }

    float* o = out + b * (18 * NN) + n * 18;
    #pragma unroll
    for (int c = 0; c < 2; ++c) {
        float hist[9];
        #pragma unroll
        for (int q = 0; q < 9; ++q) hist[q] = fadd(h1[q][c], h2[q][c]);
        float acc = 0.0f;
        #pragma unroll
        for (int q = 0; q < 9; ++q) acc = fadd(acc, fmul(hist[q], hist[q]));
        float nr = fsqrtf32(acc);
        float den = fmaxf(nr, 1e-12f);
        #pragma unroll
        for (int q = 0; q < 9; ++q) o[q * 2 + c] = fdiv(hist[q], den);
    }
}

// ===========================================================================
extern "C" void kernel_launch(void* const* d_in, const int* in_sizes, int n_in,
                              void* d_out, int out_size, void* d_ws, size_t ws_size,
                              hipStream_t stream) {
    const float* x = (const float*)d_in[0];
    float* out = (float*)d_out;

    char* ws = (char*)d_ws;
    size_t off = 0;
    int* idx = (int*)(ws + off);        off += (size_t)BB * NN * KK * sizeof(int);
    float* d2 = (float*)(ws + off);     off += (size_t)BB * NN * sizeof(float);
    float* grad = (float*)(ws + off);   off += (size_t)BB * NN * 3 * sizeof(float);
    float* mag = (float*)(ws + off);

    d2_kernel <<<(BB * NN + 255) / 256, 256, 0, stream>>>(x, d2);
    knn_kernel<<<BB * NN / 4, 256, 0, stream>>>(x, d2, idx);
    eig_kernel<<<(BB * NN + 255) / 256, 256, 0, stream>>>(x, idx, grad, mag);
    hist_kernel<<<(BB * NN + 255) / 256, 256, 0, stream>>>(idx, grad, mag, out);
}

// Round 4
// 221.719 us; speedup vs baseline: 1.5992x; 1.5959x over previous
//
#include <hip/hip_runtime.h>
#include <math.h>

// Problem constants: B=8, N=2048, K=32, 9 bins, width 20.
#define BB 8
#define NN 2048
#define KK 32

// ===========================================================================
// Exactly-rounded f32 helpers (no contraction): compute in double, round once.
// fmaf() is used wherever the referee's compiler (-ffp-contract=fast) fuses.
// ===========================================================================
__device__ __forceinline__ float fadd(float a, float b){ return (float)((double)a + (double)b); }
__device__ __forceinline__ float fsub(float a, float b){ return (float)((double)a - (double)b); }
__device__ __forceinline__ float fmul(float a, float b){ return (float)((double)a * (double)b); }
__device__ __forceinline__ float fdiv(float a, float b){ return (float)((double)a / (double)b); }
__device__ __forceinline__ float fsqrtf32(float a){ return (float)sqrt((double)a); }

// ===========================================================================
// LAPACK 3.12 single-precision helpers, gfortran -ffp-contract=fast model.
// ===========================================================================
__device__ float slapy2f(float x, float y) {
    float xa = fabsf(x), ya = fabsf(y);
    float w = fmaxf(xa, ya), z = fminf(xa, ya);
    if (z == 0.0f) return w;
    float q = fdiv(z, w);
    return fmul(w, fsqrtf32(fmaf(q, q, 1.0f)));
}

__device__ void slartgf(float f, float g, float& c, float& s, float& r) {
    if (g == 0.0f) { c = 1.0f; s = 0.0f; r = f; }
    else if (f == 0.0f) { c = 0.0f; s = copysignf(1.0f, g); r = fabsf(g); }
    else {
        float d = fsqrtf32(fmaf(f, f, fmul(g, g)));
        c = fdiv(fabsf(f), d);
        r = copysignf(d, f);
        s = fdiv(g, r);
    }
}

__device__ void slas2f(float f, float g, float h, float& ssmin, float& ssmax) {
    float fa = fabsf(f), ga = fabsf(g), ha = fabsf(h);
    float fhmn = fminf(fa, ha), fhmx = fmaxf(fa, ha);
    if (fhmn == 0.0f) {
        ssmin = 0.0f;
        if (fhmx == 0.0f) ssmax = ga;
        else {
            float mx = fmaxf(fhmx, ga), mn = fminf(fhmx, ga);
            float q = fdiv(mn, mx);
            ssmax = fmul(mx, fsqrtf32(fmaf(q, q, 1.0f)));
        }
    } else {
        if (ga < fhmx) {
            float as = fadd(1.0f, fdiv(fhmn, fhmx));
            float at = fdiv(fsub(fhmx, fhmn), fhmx);
            float q = fdiv(ga, fhmx); float au = fmul(q, q);
            float c = fdiv(2.0f, fadd(fsqrtf32(fmaf(as, as, au)),
                                      fsqrtf32(fmaf(at, at, au))));
            ssmin = fmul(fhmn, c); ssmax = fdiv(fhmx, c);
        } else {
            float au = fdiv(fhmx, ga);
            if (au == 0.0f) { ssmin = fdiv(fmul(fhmn, fhmx), ga); ssmax = ga; }
            else {
                float as = fadd(1.0f, fdiv(fhmn, fhmx));
                float at = fdiv(fsub(fhmx, fhmn), fhmx);
                float t1 = fmul(as, au), t2 = fmul(at, au);
                float c = fdiv(1.0f, fadd(fsqrtf32(fmaf(t1, t1, 1.0f)),
                                          fsqrtf32(fmaf(t2, t2, 1.0f))));
                ssmin = fmul(fmul(fhmn, c), au); ssmin = fadd(ssmin, ssmin);
                ssmax = fdiv(ga, fadd(c, c));
            }
        }
    }
}

__device__ void slasv2f(float f, float g, float h,
                        float& ssmin, float& ssmax,
                        float& snr, float& csr, float& snl, float& csl) {
    const float eps = 5.9604644775390625e-08f;
    float ft = f, fa = fabsf(f), ht = h, ha = fabsf(h);
    int pmax = 1;
    bool swp = (ha > fa);
    if (swp) { pmax = 3; float t = ft; ft = ht; ht = t; t = fa; fa = ha; ha = t; }
    float gt = g, ga = fabsf(gt);
    float clt = 0.f, crt = 0.f, slt = 0.f, srt = 0.f;
    if (ga == 0.0f) {
        ssmin = ha; ssmax = fa; clt = 1.0f; crt = 1.0f; slt = 0.0f; srt = 0.0f;
    } else {
        bool gasmal = true;
        if (ga > fa) {
            pmax = 2;
            if (fdiv(fa, ga) < eps) {
                gasmal = false;
                ssmax = ga;
                ssmin = (ha > 1.0f) ? fdiv(fa, fdiv(ga, ha)) : fmul(fdiv(fa, ga), ha);
                clt = 1.0f; slt = fdiv(ht, gt); srt = 1.0f; crt = fdiv(ft, gt);
            }
        }
        if (gasmal) {
            float dd = fsub(fa, ha);
            float l = (dd == fa) ? 1.0f : fdiv(dd, fa);
            float mm = fdiv(gt, ft);
            float t = fsub(2.0f, l);
            float m2 = fmul(mm, mm);
            float s = fsqrtf32(fmaf(t, t, m2));
            float r = (l == 0.0f) ? fabsf(mm) : fsqrtf32(fmaf(l, l, m2));
            float a = fmul(0.5f, fadd(s, r));
            ssmin = fdiv(ha, a);
            ssmax = fmul(fa, a);
            if (m2 == 0.0f) {
                t = (l == 0.0f) ? fmul(copysignf(2.0f, ft), copysignf(1.0f, gt))
                                : fadd(fdiv(gt, copysignf(dd, ft)), fdiv(mm, t));
            } else {
                t = fmul(fadd(fdiv(mm, fadd(s, t)), fdiv(mm, fadd(r, l))), fadd(1.0f, a));
            }
            float l2 = fsqrtf32(fmaf(t, t, 4.0f));
            crt = fdiv(2.0f, l2); srt = fdiv(t, l2);
            clt = fdiv(fmaf(srt, mm, crt), a);
            slt = fdiv(fmul(fdiv(ht, ft), srt), a);
        }
    }
    if (swp) { csl = srt; snl = crt; csr = slt; snr = clt; }
    else     { csl = clt; snl = slt; csr = crt; snr = srt; }
    float tsign = 0.0f;
    if (pmax == 1) tsign = fmul(fmul(copysignf(1.f, csr), copysignf(1.f, csl)), copysignf(1.f, f));
    if (pmax == 2) tsign = fmul(fmul(copysignf(1.f, snr), copysignf(1.f, csl)), copysignf(1.f, g));
    if (pmax == 3) tsign = fmul(fmul(copysignf(1.f, snr), copysignf(1.f, snl)), copysignf(1.f, h));
    ssmax = copysignf(fabsf(ssmax), tsign);
    ssmin = copysignf(fabsf(ssmin), fmul(tsign, fmul(copysignf(1.f, f), copysignf(1.f, h))));
}

// slasr 'L','V' rotation on vt rows lo,hi (1-indexed), fma-contracted
__device__ __forceinline__ void rot_rowsf(float vt[4][4], int lo, int hi, float cc, float ss) {
    #pragma unroll
    for (int c = 1; c <= 3; ++c) {
        float t = vt[hi][c];
        vt[hi][c] = fmaf(cc, t, -fmul(ss, vt[lo][c]));
        vt[lo][c] = fmaf(ss, t, fmul(cc, vt[lo][c]));
    }
}

// sbdsqr for n=3 upper bidiagonal. R9: idir2-shifted VT pairing REVERTED to
// (COSL, -SINL) — R8's (COSR,-SINR) regressed 0.0898->0.6455, proving the
// original Fortran reading (2nd slartg = VT side in bottom-up sweeps) right.
__device__ void bdsqr3f(float* d, float* e, float vt[4][4]) {
    const float eps  = 5.9604644775390625e-08f;
    const float unfl = 1.1754943508222875e-38f;
    const int n = 3;
    const float tol = fmul(10.0f, eps);
    float thresh;
    {
        float sminoa = fabsf(d[1]);
        if (sminoa != 0.0f) {
            float mu = sminoa;
            for (int i = 2; i <= n; ++i) {
                mu = fmul(fabsf(d[i]), fdiv(mu, fadd(mu, fabsf(e[i - 1]))));
                sminoa = fminf(sminoa, mu);
                if (sminoa == 0.0f) break;
            }
        }
        sminoa = fdiv(sminoa, fsqrtf32(3.0f));
        thresh = fmaxf(fmul(tol, sminoa), fmul(54.0f, unfl));
    }
    int m = n, iter = 0, oldll = -1, oldm = -1, idir = 0;
    float sminl = 0.0f;
    while (m > 1) {
        if (iter > 54) break;
        float smax = fabsf(d[m]);
        int ll = 0; bool split = false;
        for (int lll = 1; lll <= m - 1; ++lll) {
            int l2 = m - lll;
            float abss = fabsf(d[l2]), abse = fabsf(e[l2]);
            if (abse <= thresh) { ll = l2; split = true; break; }
            smax = fmaxf(smax, fmaxf(abss, abse));
        }
        if (split) {
            e[ll] = 0.0f;
            if (ll == m - 1) { m = m - 1; continue; }
            ll = ll + 1;
        } else ll = 1;
        if (ll == m - 1) {
            float sigmn, sigmx, sinr, cosr, sinl, cosl;
            slasv2f(d[m - 1], e[m - 1], d[m], sigmn, sigmx, sinr, cosr, sinl, cosl);
            d[m - 1] = sigmx; e[m - 1] = 0.0f; d[m] = sigmn;
            #pragma unroll
            for (int c = 1; c <= 3; ++c) {
                float t = fmaf(cosr, vt[m - 1][c], fmul(sinr, vt[m][c]));
                vt[m][c] = fmaf(cosr, vt[m][c], -fmul(sinr, vt[m - 1][c]));
                vt[m - 1][c] = t;
            }
            m -= 2; continue;
        }
        if (ll > oldm || m < oldll)
            idir = (fabsf(d[ll]) >= fabsf(d[m])) ? 1 : 2;
        bool deflated = false;
        if (idir == 1) {
            if (fabsf(e[m - 1]) <= fmul(tol, fabsf(d[m]))) { e[m - 1] = 0.0f; continue; }
            float mu = fabsf(d[ll]); sminl = mu;
            for (int lll = ll; lll <= m - 1; ++lll) {
                if (fabsf(e[lll]) <= fmul(tol, mu)) { e[lll] = 0.0f; deflated = true; break; }
                mu = fmul(fabsf(d[lll + 1]), fdiv(mu, fadd(mu, fabsf(e[lll]))));
                sminl = fminf(sminl, mu);
            }
        } else {
            if (fabsf(e[ll]) <= fmul(tol, fabsf(d[ll]))) { e[ll] = 0.0f; continue; }
            float mu = fabsf(d[m]); sminl = mu;
            for (int lll = m - 1; lll >= ll; --lll) {
                if (fabsf(e[lll]) <= fmul(tol, mu)) { e[lll] = 0.0f; deflated = true; break; }
                mu = fmul(fabsf(d[lll]), fdiv(mu, fadd(mu, fabsf(e[lll]))));
                sminl = fminf(sminl, mu);
            }
        }
        if (deflated) continue;
        oldll = ll; oldm = m;
        float shift = 0.0f, rr;
        if (!(fmul(fmul(3.0f, tol), fdiv(sminl, smax)) <= fmaxf(eps, fmul(0.01f, tol)))) {
            float sll;
            if (idir == 1) { sll = fabsf(d[ll]); slas2f(d[m - 1], e[m - 1], d[m], shift, rr); }
            else           { sll = fabsf(d[m]);  slas2f(d[ll], e[ll], d[ll + 1], shift, rr); }
            if (sll > 0.0f) { float q = fdiv(shift, sll); if (fmul(q, q) < eps) shift = 0.0f; }
        }
        iter += m - ll;
        float wc[4], ws[4];
        if (shift == 0.0f) {
            if (idir == 1) {
                float cs = 1.0f, oldcs = 1.0f, sn = 0.0f, oldsn = 0.0f, r2;
                for (int i = ll; i <= m - 1; ++i) {
                    slartgf(fmul(d[i], cs), e[i], cs, sn, r2);
                    if (i > ll) e[i - 1] = fmul(oldsn, r2);
                    slartgf(fmul(oldcs, r2), fmul(d[i + 1], sn), oldcs, oldsn, d[i]);
                    wc[i - ll + 1] = cs; ws[i - ll + 1] = sn;
                }
                float h = fmul(d[m], cs); d[m] = fmul(h, oldcs); e[m - 1] = fmul(h, oldsn);
                if (fabsf(e[m - 1]) <= thresh) e[m - 1] = 0.0f;
                for (int j = 1; j <= m - ll; ++j) rot_rowsf(vt, ll + j - 1, ll + j, wc[j], ws[j]);
            } else {
                float cs = 1.0f, oldcs = 1.0f, sn = 0.0f, oldsn = 0.0f, r2;
                for (int i = m; i >= ll + 1; --i) {
                    slartgf(fmul(d[i], cs), e[i - 1], cs, sn, r2);
                    if (i < m) e[i] = fmul(oldsn, r2);
                    slartgf(fmul(oldcs, r2), fmul(d[i - 1], sn), oldcs, oldsn, d[i]);
                    wc[i - ll] = oldcs; ws[i - ll] = -oldsn;
                }
                float h = fmul(d[ll], cs); d[ll] = fmul(h, oldcs); e[ll] = fmul(h, oldsn);
                if (fabsf(e[ll]) <= thresh) e[ll] = 0.0f;
                for (int j = m - ll; j >= 1; --j) rot_rowsf(vt, ll + j - 1, ll + j, wc[j], ws[j]);
            }
        } else {
            if (idir == 1) {
                float fq = fmul(fsub(fabsf(d[ll]), shift),
                                fadd(copysignf(1.0f, d[ll]), fdiv(shift, d[ll])));
                float g = e[ll], cosr, sinr, cosl, sinl, r2;
                for (int i = ll; i <= m - 1; ++i) {
                    slartgf(fq, g, cosr, sinr, r2);
                    if (i > ll) e[i - 1] = r2;
                    float di = d[i], ei = e[i], dip = d[i + 1];
                    fq         = fmaf(cosr, di, fmul(sinr, ei));
                    float ei_n = fmaf(cosr, ei, -fmul(sinr, di));
                    g = fmul(sinr, dip);
                    float dip_n = fmul(cosr, dip);
                    slartgf(fq, g, cosl, sinl, r2);
                    d[i] = r2;
                    fq       = fmaf(cosl, ei_n, fmul(sinl, dip_n));
                    d[i + 1] = fmaf(cosl, dip_n, -fmul(sinl, ei_n));
                    e[i] = ei_n;
                    if (i < m - 1) { g = fmul(sinl, e[i + 1]); e[i + 1] = fmul(cosl, e[i + 1]); }
                    wc[i - ll + 1] = cosr; ws[i - ll + 1] = sinr;
                }
                e[m - 1] = fq;
                if (fabsf(e[m - 1]) <= thresh) e[m - 1] = 0.0f;
                for (int j = 1; j <= m - ll; ++j) rot_rowsf(vt, ll + j - 1, ll + j, wc[j], ws[j]);
            } else {
                float fq = fmul(fsub(fabsf(d[m]), shift),
                                fadd(copysignf(1.0f, d[m]), fdiv(shift, d[m])));
                float g = e[m - 1], cosr, sinr, cosl, sinl, r2;
                for (int i = m; i >= ll + 1; --i) {
                    slartgf(fq, g, cosr, sinr, r2);
                    if (i < m) e[i] = r2;
                    float di = d[i], em = e[i - 1], dim = d[i - 1];
                    fq         = fmaf(cosr, di, fmul(sinr, em));
                    float em_n = fmaf(cosr, em, -fmul(sinr, di));
                    g = fmul(sinr, dim);
                    float dim_n = fmul(cosr, dim);
                    slartgf(fq, g, cosl, sinl, r2);
                    d[i] = r2;
                    fq       = fmaf(cosl, em_n, fmul(sinl, dim_n));
                    d[i - 1] = fmaf(cosl, dim_n, -fmul(sinl, em_n));
                    e[i - 1] = em_n;
                    if (i > ll + 1) { g = fmul(sinl, e[i - 2]); e[i - 2] = fmul(cosl, e[i - 2]); }
                    wc[i - ll] = cosl; ws[i - ll] = -sinl;   // REVERTED (correct per R8 regression)
                }
                e[ll] = fq;
                if (fabsf(e[ll]) <= thresh) e[ll] = 0.0f;
                for (int j = m - ll; j >= 1; --j) rot_rowsf(vt, ll + j - 1, ll + j, wc[j], ws[j]);
            }
        }
    }
    for (int i = 1; i <= n; ++i) {
        if (d[i] < 0.0f) {
            d[i] = -d[i];
            for (int c = 1; c <= 3; ++c) vt[i][c] = -vt[i][c];
        }
    }
    for (int i = 1; i <= n - 1; ++i) {
        int isub = 1; float smin2 = d[1];
        for (int j = 2; j <= n + 1 - i; ++j)
            if (d[j] <= smin2) { isub = j; smin2 = d[j]; }
        int tgt = n + 1 - i;
        if (isub != tgt) {
            d[isub] = d[tgt]; d[tgt] = smin2;
            for (int c = 1; c <= 3; ++c) { float t = vt[isub][c]; vt[isub][c] = vt[tgt][c]; vt[tgt][c] = t; }
        }
    }
}

// ===========================================================================
// Kernel 0: d2 in f32
// ===========================================================================
__global__ void d2_kernel(const float* __restrict__ x, float* __restrict__ d2) {
    int t = blockIdx.x * blockDim.x + threadIdx.x;
    if (t >= BB * NN) return;
    int b = t / NN, n = t % NN;
    const float* xb = x + b * 3 * NN;
    float xv = xb[n], yv = xb[NN + n], zv = xb[2 * NN + n];
    d2[t] = fadd(fadd(fmul(xv, xv), fmul(yv, yv)), fmul(zv, zv));
}

// ===========================================================================
// Kernel 1: KNN — R13: R10 register shape + 4-deep lookahead mini-list.
//
// R11/R12 post-mortem: a 64-VGPR u64 ARRAY goes to scratch no matter the
// launch bounds (VGPR 60-64, VALUBusy ~61-66%, 222-237 µs); R10's 32-VGPR
// u32 array stayed register-resident (VGPR 40, VALUBusy 100%, 177 µs).
// So: keep vals[32] as u32 (proven), and replace R10's per-iteration
// 32-slot rescan (~93 VALU) + 32-slot invalidation (~96 VALU) with a
// per-lane lookahead of the next 4 candidates held in NAMED u64 scalars
// l0..l3 (no array => no promotion hazard, +8 VGPRs):
//   - build: pop lane-best 4x from vals (31 v_max_u32 + first-match 64 +
//     predicated clear 64 per pop), paid once
//   - per iter: head=l0 (no scan), same DPP u64-max cascade, winner pop =
//     shift of 4 named scalars (9 ops); no invalidation pass
//   - refill (lane won 5+ of the 33 draws): wave-uniform branch around a
//     predicated re-pop; ~never taken for this data, ~160 VALU when taken
// Pop order per lane = (value desc, slot asc) = (value desc, j asc) — the
// exact R10 local scan order; cross-lane ties via the same u64 DPP key
// (sortable(val)<<32 | 2047-j). k-way merge of streams sorted by the global
// key == repeated global argmax => extraction sequence is bit-identical.
// Ranks 1,2,3,31,32 near-tie probes unchanged.
// ===========================================================================
__device__ __forceinline__ unsigned int f32_sortable(float f) {
    unsigned int b = __float_as_uint(f);
    return b ^ ((unsigned int)((int)b >> 31) | 0x80000000u);
}
__device__ __forceinline__ float sortable_f32(unsigned int s) {
    unsigned int b = s ^ (~(unsigned int)((int)s >> 31) | 0x80000000u);
    return __uint_as_float(b);
}

template <int CTRL, int RM>
__device__ __forceinline__ unsigned long long dpp_umax64(unsigned long long k) {
    int nhi = __builtin_amdgcn_update_dpp(0, (int)(unsigned int)(k >> 32), CTRL, RM, 0xF, false);
    int nlo = __builtin_amdgcn_update_dpp(0, (int)(unsigned int)k,         CTRL, RM, 0xF, false);
    unsigned long long nk = ((unsigned long long)(unsigned int)nhi << 32) | (unsigned int)nlo;
    return nk > k ? nk : k;
}

// Pop the lane's best remaining candidate from vals (value desc, slot asc),
// clear it, and return the packed u64 merge key. All indices static.
__device__ __forceinline__ unsigned long long pop_best(unsigned int (&vals)[32], int lane) {
    unsigned int m = vals[0];
    #pragma unroll
    for (int s = 1; s < 32; ++s) m = (vals[s] > m) ? vals[s] : m;   // v_max_u32
    int bs = 0;
    #pragma unroll
    for (int s = 31; s >= 0; --s) if (vals[s] == m) bs = s;          // first match
    #pragma unroll
    for (int s = 0; s < 32; ++s) vals[s] = (s == bs) ? 0u : vals[s]; // clear
    int j = bs * 64 + lane;
    return ((unsigned long long)m << 32) | (unsigned int)(2047 - j);
}

__global__ void __launch_bounds__(256) knn_kernel(const float* __restrict__ x,
                                                  const float* __restrict__ d2,
                                                  int* __restrict__ idx) {
    int lane = threadIdx.x & 63;
    int wid  = threadIdx.x >> 6;
    int row  = blockIdx.x * 4 + wid;
    int b = row / NN, i = row % NN;
    const float* xb  = x  + b * 3 * NN;
    const float* d2b = d2 + b * NN;

    float xi = xb[i], yi = xb[NN + i], zi = xb[2 * NN + i];
    float d2i = d2b[i];

    // 32 candidates per lane, sortable-u32 encoded, static register indexing.
    // Arithmetic identical to R10 (bit-exact dot & sortable encode).
    unsigned int vals[32];
    #pragma unroll
    for (int s = 0; s < 32; ++s) {
        int j = s * 64 + lane;
        float dot = fmul(xi, xb[j]);
        dot = fmaf(yi, xb[NN + j], dot);
        dot = fmaf(zi, xb[2 * NN + j], dot);
        float v = fsub(fsub(fmul(2.0f, dot), d2i), d2b[j]);
        vals[s] = f32_sortable(v);
    }

    // ---- build the 4-deep lookahead mini-list (named scalars, sorted desc)
    unsigned long long l0 = pop_best(vals, lane);
    unsigned long long l1 = pop_best(vals, lane);
    unsigned long long l2 = pop_best(vals, lane);
    unsigned long long l3 = pop_best(vals, lane);

    int* idxrow = idx + row * KK;
    unsigned int c1v = 0, c2v = 0, c3v = 0, c31v = 0, c32v = 0;
    int c1i = 0, c2i = 0, c3i = 0, c31i = 0, c32i = 0;

    #pragma unroll 1
    for (int t = 0; t < KK + 1; ++t) {      // 33 ranks (32 + boundary probe)
        // rare refill: some lane consumed its whole lookahead (won 4+ times)
        if (__any(l0 == 0ull)) {
            bool need = (l0 == 0ull);
            unsigned int m = vals[0];
            #pragma unroll
            for (int s = 1; s < 32; ++s) m = (vals[s] > m) ? vals[s] : m;
            int bs = 0;
            #pragma unroll
            for (int s = 31; s >= 0; --s) if (vals[s] == m) bs = s;
            #pragma unroll
            for (int s = 0; s < 32; ++s)
                vals[s] = (need && s == bs) ? 0u : vals[s];
            unsigned long long ent = ((unsigned long long)m << 32)
                                   | (unsigned int)(2047 - (bs * 64 + lane));
            l0 = need ? ent : l0;
        }

        // wave argmax of heads, pure-VALU DPP cascade; lane 63 ends global max
        unsigned long long k = l0;
        k = dpp_umax64<0x111, 0xF>(k);   // row_shr:1
        k = dpp_umax64<0x112, 0xF>(k);   // row_shr:2
        k = dpp_umax64<0x114, 0xF>(k);   // row_shr:4
        k = dpp_umax64<0x118, 0xF>(k);   // row_shr:8
        k = dpp_umax64<0x142, 0xA>(k);   // row_bcast:15 -> rows 1,3
        k = dpp_umax64<0x143, 0xC>(k);   // row_bcast:31 -> rows 2,3

        unsigned int wbest = (unsigned int)__builtin_amdgcn_readlane((int)(k >> 32), 63);
        unsigned int wlow  = (unsigned int)__builtin_amdgcn_readlane((int)(k & 0xFFFFFFFFull), 63);
        int wj = 2047 - (int)(wlow & 0x7FFu);

        // winner lane pops its head: shift the 4 named scalars down.
        // Low words (2047-j) are unique across lanes => 32-bit compare.
        bool amw = ((unsigned int)l0 == wlow);
        l0 = amw ? l1 : l0;
        l1 = amw ? l2 : l1;
        l2 = amw ? l3 : l2;
        l3 = amw ? 0ull : l3;

        // record: ranks 1,2,3,31,32 are deferred for the near-tie probes
        if (t == 1)           { c1v = wbest;  c1i = wj; }
        else if (t == 2)      { c2v = wbest;  c2i = wj; }
        else if (t == 3)      { c3v = wbest;  c3i = wj; }
        else if (t == KK - 1) { c31v = wbest; c31i = wj; }
        else if (t == KK)     { c32v = wbest; c32i = wj; }
        else if (lane == 0)   idxrow[t] = wj;
    }

    if (lane == 0) {
        const float TIE = 4e-7f;
        float r1  = sortable_f32(c1v),  r2  = sortable_f32(c2v), r3 = sortable_f32(c3v);
        float r31 = sortable_f32(c31v), r32 = sortable_f32(c32v);
        if (fabsf(r1 - r2) < TIE) { int ti = c1i; c1i = c2i; c2i = ti; float tv = r1; r1 = r2; r2 = tv; }
        if (fabsf(r2 - r3) < TIE) { int ti = c2i; c2i = c3i; c3i = ti; float tv = r2; r2 = r3; r3 = tv; }
        idxrow[1] = c1i; idxrow[2] = c2i; idxrow[3] = c3i;
        idxrow[KK - 1] = (fabsf(r31 - r32) < TIE) ? c32i : c31i;
    }
}

// ===========================================================================
// Kernel 2: sgesdd emulation (R8 version: slarf1f, fmaf BLAS, f64 snrm2)
// ===========================================================================
__global__ void eig_kernel(const float* __restrict__ x, const int* __restrict__ idx,
                           float* __restrict__ grad, float* __restrict__ mag) {
    int t = blockIdx.x * blockDim.x + threadIdx.x;
    if (t >= BB * NN) return;
    int b = t / NN;
    const float* xb = x + b * 3 * NN;
    const int* id = idx + t * KK;

    float A[KK][3];
    float s0 = 0.f, s1 = 0.f, s2 = 0.f;
    for (int j = 0; j < KK; ++j) {
        int n = id[j];
        s0 = fadd(s0, xb[n]); s1 = fadd(s1, xb[NN + n]); s2 = fadd(s2, xb[2 * NN + n]);
    }
    float m0 = fdiv(s0, 32.f), m1 = fdiv(s1, 32.f), m2 = fdiv(s2, 32.f);
    for (int j = 0; j < KK; ++j) {
        int n = id[j];
        A[j][0] = fsub(xb[n], m0);
        A[j][1] = fsub(xb[NN + n], m1);
        A[j][2] = fsub(xb[2 * NN + n], m2);
    }

    // ---- sgeqr2 with slarf1f
    for (int i = 0; i < 3; ++i) {
        float alpha = A[i][i];
        double nacc = 0.0;
        for (int r = i + 1; r < KK; ++r) nacc += (double)A[r][i] * (double)A[r][i];
        float xnorm = (float)sqrt(nacc);
        if (xnorm != 0.0f) {
            float beta = -copysignf(slapy2f(alpha, xnorm), alpha);
            float tau  = fdiv(fsub(beta, alpha), beta);
            float scal = fdiv(1.0f, fsub(alpha, beta));
            for (int r = i + 1; r < KK; ++r) A[r][i] = fmul(A[r][i], scal);
            A[i][i] = beta;
            for (int j = i + 1; j < 3; ++j) {
                float acc = 0.0f;
                for (int r = i + 1; r < KK; ++r) acc = fmaf(A[r][i], A[r][j], acc);
                float w = fadd(acc, A[i][j]);
                A[i][j] = fmaf(-tau, w, A[i][j]);
                float temp = fmul(-tau, w);
                for (int r = i + 1; r < KK; ++r) A[r][j] = fmaf(A[r][i], temp, A[r][j]);
            }
        }
    }
    float B11 = A[0][0], B12 = A[0][1], B13 = A[0][2];
    float B22 = A[1][1], B23 = A[1][2], B33 = A[2][2];

    // ---- sgebd2 with slarf1f
    float d[4], e[3];
    float taup = 0.0f, v2p = 0.0f;
    d[1] = B11;
    float B32 = 0.0f;
    if (B13 != 0.0f) {
        float xn = fsqrtf32(fmul(B13, B13));
        float beta = -copysignf(slapy2f(B12, xn), B12);
        taup = fdiv(fsub(beta, B12), beta);
        float scal = fdiv(1.0f, fsub(B12, beta));
        v2p = fmul(B13, scal);
        e[1] = beta;
        float w2 = fadd(fmul(B23, v2p), B22);
        float w3 = fmul(B33, v2p);
        B22 = fmaf(-taup, w2, B22);
        B32 = fmul(-taup, w3);
        float tmp = fmul(-taup, v2p);
        B23 = fmaf(w2, tmp, B23);
        B33 = fmaf(w3, tmp, B33);
    } else e[1] = B12;
    if (B32 != 0.0f) {
        float xn = fsqrtf32(fmul(B32, B32));
        float beta = -copysignf(slapy2f(B22, xn), B22);
        float tauq = fdiv(fsub(beta, B22), beta);
        float scal = fdiv(1.0f, fsub(B22, beta));
        float v2 = fmul(B32, scal);
        d[2] = beta;
        float w = fadd(fmul(v2, B33), B23);
        B23 = fmaf(-tauq, w, B23);
        float tmp = fmul(-tauq, w);
        B33 = fmaf(v2, tmp, B33);
    } else d[2] = B22;
    e[2] = B23;
    d[3] = B33;

    // ---- sbdsqr with VT = I
    float vt[4][4];
    for (int r = 1; r <= 3; ++r)
        for (int c = 1; c <= 3; ++c) vt[r][c] = (r == c) ? 1.0f : 0.0f;
    bdsqr3f(d, e, vt);

    // ---- sormbr 'P','R','T' via slarf1f
    if (taup != 0.0f) {
        float tmp = fmul(-taup, v2p);
        for (int r = 1; r <= 3; ++r) {
            float w = fadd(fmul(vt[r][3], v2p), vt[r][2]);
            vt[r][2] = fmaf(-taup, w, vt[r][2]);
            vt[r][3] = fmaf(w, tmp, vt[r][3]);
        }
    }

    int im = 1;
    if (d[2] > d[im]) im = 2;
    if (d[3] > d[im]) im = 3;
    grad[t * 3 + 0] = vt[im][1];
    grad[t * 3 + 1] = vt[im][2];
    grad[t * 3 + 2] = vt[im][3];
    mag[t] = fsqrtf32(d[im]);
}

// ===========================================================================
// Kernel 3: HOG histogram, strict f32 replica (CR-f32 angles).
// ===========================================================================
__global__ void hist_kernel(const int* __restrict__ idx, const float* __restrict__ grad,
                            const float* __restrict__ mag, float* __restrict__ out) {
    int t = blockIdx.x * blockDim.x + threadIdx.x;
    if (t >= BB * NN) return;
    int b = t / NN, n = t % NN;
    const int* id = idx + t * KK;
    const float r2d = (float)(180.0 / M_PI);

    float h1[9][2], h2[9][2];
    #pragma unroll
    for (int q = 0; q < 9; ++q) { h1[q][0] = h1[q][1] = 0.f; h2[q][0] = h2[q][1] = 0.f; }

    for (int j = 0; j < KK; ++j) {
        int jj = b * NN + id[j];
        float gx = grad[jj * 3 + 0];
        float gy = grad[jj * 3 + 1];
        float gz = grad[jj * 3 + 2];
        float m  = mag[jj];

        float zen = (float)acos((double)gz);
        float zd  = fmul(zen, r2d);
        float q0  = fdiv(gy, gx);
        float azr = (float)atan((double)q0);
        float ad  = fmul(azr, r2d);

        float a0 = (zd != zd) ? -2147483648.0f : (float)(int)zd;
        float a1 = (ad != ad) ? -2147483648.0f : (float)(int)ad;

        #pragma unroll
        for (int c = 0; c < 2; ++c) {
            float a = (c == 0) ? a0 : a1;
            if (a < 0.0f) a = fadd(a, 180.0f);
            float tq = fdiv(a, 20.0f);
            float t2 = fsub(tq, 0.5f);
            float fb = floorf(t2);
            float bin = fmodf(fb, 9.0f); if (bin != 0.0f && bin < 0.0f) bin = fadd(bin, 9.0f);
            float b1 = fadd(bin, 1.0f);
            float b1m = fmodf(b1, 9.0f);
            float fc = fmul(20.0f, fadd(b1m, 0.5f));
            float df = fsub(fc, a);
            float rm = fmodf(df, 180.0f); if (rm != 0.0f && rm < 0.0f) rm = fadd(rm, 180.0f);
            float v1 = fdiv(fmul(m, rm), 20.0f);
            float sc = fmul(20.0f, fadd(bin, 0.5f));
            float ds = fsub(a, sc);
            float rm2 = fmodf(ds, 180.0f); if (rm2 != 0.0f && rm2 < 0.0f) rm2 = fadd(rm2, 180.0f);
            float v2 = fdiv(fmul(m, rm2), 20.0f);
            int bi = (int)bin;
            int b2 = bi + 1; if (b2 >= 9) b2 -= 9;
            h1[bi][c] = fadd(h1[bi][c], v1);
            h2[b2][c] = fadd(h2[b2][c], v2);
        }
    }

    float* o = out + b * (18 * NN) + n * 18;
    #pragma unroll
    for (int c = 0; c < 2; ++c) {
        float hist[9];
        #pragma unroll
        for (int q = 0; q < 9; ++q) hist[q] = fadd(h1[q][c], h2[q][c]);
        float acc = 0.0f;
        #pragma unroll
        for (int q = 0; q < 9; ++q) acc = fadd(acc, fmul(hist[q], hist[q]));
        float nr = fsqrtf32(acc);
        float den = fmaxf(nr, 1e-12f);
        #pragma unroll
        for (int q = 0; q < 9; ++q) o[q * 2 + c] = fdiv(hist[q], den);
    }
}

// ===========================================================================
extern "C" void kernel_launch(void* const* d_in, const int* in_sizes, int n_in,
                              void* d_out, int out_size, void* d_ws, size_t ws_size,
                              hipStream_t stream) {
    const float* x = (const float*)d_in[0];
    float* out = (float*)d_out;

    char* ws = (char*)d_ws;
    size_t off = 0;
    int* idx = (int*)(ws + off);        off += (size_t)BB * NN * KK * sizeof(int);
    float* d2 = (float*)(ws + off);     off += (size_t)BB * NN * sizeof(float);
    float* grad = (float*)(ws + off);   off += (size_t)BB * NN * 3 * sizeof(float);
    float* mag = (float*)(ws + off);

    d2_kernel <<<(BB * NN + 255) / 256, 256, 0, stream>>>(x, d2);
    knn_kernel<<<BB * NN / 4, 256, 0, stream>>>(x, d2, idx);
    eig_kernel<<<(BB * NN + 255) / 256, 256, 0, stream>>>(x, idx, grad, mag);
    hist_kernel<<<(BB * NN + 255) / 256, 256, 0, stream>>>(idx, grad, mag, out);
}

// Round 5
// 212.641 us; speedup vs baseline: 1.6674x; 1.0427x over previous
//
#include <hip/hip_runtime.h>
#include <math.h>

// Problem constants: B=8, N=2048, K=32, 9 bins, width 20.
#define BB 8
#define NN 2048
#define KK 32

// ===========================================================================
// Exactly-rounded f32 helpers (no contraction): compute in double, round once.
// fmaf() is used wherever the referee's compiler (-ffp-contract=fast) fuses.
// ===========================================================================
__device__ __forceinline__ float fadd(float a, float b){ return (float)((double)a + (double)b); }
__device__ __forceinline__ float fsub(float a, float b){ return (float)((double)a - (double)b); }
__device__ __forceinline__ float fmul(float a, float b){ return (float)((double)a * (double)b); }
__device__ __forceinline__ float fdiv(float a, float b){ return (float)((double)a / (double)b); }
__device__ __forceinline__ float fsqrtf32(float a){ return (float)sqrt((double)a); }

// ===========================================================================
// LAPACK 3.12 single-precision helpers, gfortran -ffp-contract=fast model.
// ===========================================================================
__device__ float slapy2f(float x, float y) {
    float xa = fabsf(x), ya = fabsf(y);
    float w = fmaxf(xa, ya), z = fminf(xa, ya);
    if (z == 0.0f) return w;
    float q = fdiv(z, w);
    return fmul(w, fsqrtf32(fmaf(q, q, 1.0f)));
}

__device__ void slartgf(float f, float g, float& c, float& s, float& r) {
    if (g == 0.0f) { c = 1.0f; s = 0.0f; r = f; }
    else if (f == 0.0f) { c = 0.0f; s = copysignf(1.0f, g); r = fabsf(g); }
    else {
        float d = fsqrtf32(fmaf(f, f, fmul(g, g)));
        c = fdiv(fabsf(f), d);
        r = copysignf(d, f);
        s = fdiv(g, r);
    }
}

__device__ void slas2f(float f, float g, float h, float& ssmin, float& ssmax) {
    float fa = fabsf(f), ga = fabsf(g), ha = fabsf(h);
    float fhmn = fminf(fa, ha), fhmx = fmaxf(fa, ha);
    if (fhmn == 0.0f) {
        ssmin = 0.0f;
        if (fhmx == 0.0f) ssmax = ga;
        else {
            float mx = fmaxf(fhmx, ga), mn = fminf(fhmx, ga);
            float q = fdiv(mn, mx);
            ssmax = fmul(mx, fsqrtf32(fmaf(q, q, 1.0f)));
        }
    } else {
        if (ga < fhmx) {
            float as = fadd(1.0f, fdiv(fhmn, fhmx));
            float at = fdiv(fsub(fhmx, fhmn), fhmx);
            float q = fdiv(ga, fhmx); float au = fmul(q, q);
            float c = fdiv(2.0f, fadd(fsqrtf32(fmaf(as, as, au)),
                                      fsqrtf32(fmaf(at, at, au))));
            ssmin = fmul(fhmn, c); ssmax = fdiv(fhmx, c);
        } else {
            float au = fdiv(fhmx, ga);
            if (au == 0.0f) { ssmin = fdiv(fmul(fhmn, fhmx), ga); ssmax = ga; }
            else {
                float as = fadd(1.0f, fdiv(fhmn, fhmx));
                float at = fdiv(fsub(fhmx, fhmn), fhmx);
                float t1 = fmul(as, au), t2 = fmul(at, au);
                float c = fdiv(1.0f, fadd(fsqrtf32(fmaf(t1, t1, 1.0f)),
                                          fsqrtf32(fmaf(t2, t2, 1.0f))));
                ssmin = fmul(fmul(fhmn, c), au); ssmin = fadd(ssmin, ssmin);
                ssmax = fdiv(ga, fadd(c, c));
            }
        }
    }
}

__device__ void slasv2f(float f, float g, float h,
                        float& ssmin, float& ssmax,
                        float& snr, float& csr, float& snl, float& csl) {
    const float eps = 5.9604644775390625e-08f;
    float ft = f, fa = fabsf(f), ht = h, ha = fabsf(h);
    int pmax = 1;
    bool swp = (ha > fa);
    if (swp) { pmax = 3; float t = ft; ft = ht; ht = t; t = fa; fa = ha; ha = t; }
    float gt = g, ga = fabsf(gt);
    float clt = 0.f, crt = 0.f, slt = 0.f, srt = 0.f;
    if (ga == 0.0f) {
        ssmin = ha; ssmax = fa; clt = 1.0f; crt = 1.0f; slt = 0.0f; srt = 0.0f;
    } else {
        bool gasmal = true;
        if (ga > fa) {
            pmax = 2;
            if (fdiv(fa, ga) < eps) {
                gasmal = false;
                ssmax = ga;
                ssmin = (ha > 1.0f) ? fdiv(fa, fdiv(ga, ha)) : fmul(fdiv(fa, ga), ha);
                clt = 1.0f; slt = fdiv(ht, gt); srt = 1.0f; crt = fdiv(ft, gt);
            }
        }
        if (gasmal) {
            float dd = fsub(fa, ha);
            float l = (dd == fa) ? 1.0f : fdiv(dd, fa);
            float mm = fdiv(gt, ft);
            float t = fsub(2.0f, l);
            float m2 = fmul(mm, mm);
            float s = fsqrtf32(fmaf(t, t, m2));
            float r = (l == 0.0f) ? fabsf(mm) : fsqrtf32(fmaf(l, l, m2));
            float a = fmul(0.5f, fadd(s, r));
            ssmin = fdiv(ha, a);
            ssmax = fmul(fa, a);
            if (m2 == 0.0f) {
                t = (l == 0.0f) ? fmul(copysignf(2.0f, ft), copysignf(1.0f, gt))
                                : fadd(fdiv(gt, copysignf(dd, ft)), fdiv(mm, t));
            } else {
                t = fmul(fadd(fdiv(mm, fadd(s, t)), fdiv(mm, fadd(r, l))), fadd(1.0f, a));
            }
            float l2 = fsqrtf32(fmaf(t, t, 4.0f));
            crt = fdiv(2.0f, l2); srt = fdiv(t, l2);
            clt = fdiv(fmaf(srt, mm, crt), a);
            slt = fdiv(fmul(fdiv(ht, ft), srt), a);
        }
    }
    if (swp) { csl = srt; snl = crt; csr = slt; snr = clt; }
    else     { csl = clt; snl = slt; csr = crt; snr = srt; }
    float tsign = 0.0f;
    if (pmax == 1) tsign = fmul(fmul(copysignf(1.f, csr), copysignf(1.f, csl)), copysignf(1.f, f));
    if (pmax == 2) tsign = fmul(fmul(copysignf(1.f, snr), copysignf(1.f, csl)), copysignf(1.f, g));
    if (pmax == 3) tsign = fmul(fmul(copysignf(1.f, snr), copysignf(1.f, snl)), copysignf(1.f, h));
    ssmax = copysignf(fabsf(ssmax), tsign);
    ssmin = copysignf(fabsf(ssmin), fmul(tsign, fmul(copysignf(1.f, f), copysignf(1.f, h))));
}

// slasr 'L','V' rotation on vt rows lo,hi (1-indexed), fma-contracted
__device__ __forceinline__ void rot_rowsf(float vt[4][4], int lo, int hi, float cc, float ss) {
    #pragma unroll
    for (int c = 1; c <= 3; ++c) {
        float t = vt[hi][c];
        vt[hi][c] = fmaf(cc, t, -fmul(ss, vt[lo][c]));
        vt[lo][c] = fmaf(ss, t, fmul(cc, vt[lo][c]));
    }
}

// sbdsqr for n=3 upper bidiagonal. R9: idir2-shifted VT pairing REVERTED to
// (COSL, -SINL) — R8's (COSR,-SINR) regressed 0.0898->0.6455, proving the
// original Fortran reading (2nd slartg = VT side in bottom-up sweeps) right.
__device__ void bdsqr3f(float* d, float* e, float vt[4][4]) {
    const float eps  = 5.9604644775390625e-08f;
    const float unfl = 1.1754943508222875e-38f;
    const int n = 3;
    const float tol = fmul(10.0f, eps);
    float thresh;
    {
        float sminoa = fabsf(d[1]);
        if (sminoa != 0.0f) {
            float mu = sminoa;
            for (int i = 2; i <= n; ++i) {
                mu = fmul(fabsf(d[i]), fdiv(mu, fadd(mu, fabsf(e[i - 1]))));
                sminoa = fminf(sminoa, mu);
                if (sminoa == 0.0f) break;
            }
        }
        sminoa = fdiv(sminoa, fsqrtf32(3.0f));
        thresh = fmaxf(fmul(tol, sminoa), fmul(54.0f, unfl));
    }
    int m = n, iter = 0, oldll = -1, oldm = -1, idir = 0;
    float sminl = 0.0f;
    while (m > 1) {
        if (iter > 54) break;
        float smax = fabsf(d[m]);
        int ll = 0; bool split = false;
        for (int lll = 1; lll <= m - 1; ++lll) {
            int l2 = m - lll;
            float abss = fabsf(d[l2]), abse = fabsf(e[l2]);
            if (abse <= thresh) { ll = l2; split = true; break; }
            smax = fmaxf(smax, fmaxf(abss, abse));
        }
        if (split) {
            e[ll] = 0.0f;
            if (ll == m - 1) { m = m - 1; continue; }
            ll = ll + 1;
        } else ll = 1;
        if (ll == m - 1) {
            float sigmn, sigmx, sinr, cosr, sinl, cosl;
            slasv2f(d[m - 1], e[m - 1], d[m], sigmn, sigmx, sinr, cosr, sinl, cosl);
            d[m - 1] = sigmx; e[m - 1] = 0.0f; d[m] = sigmn;
            #pragma unroll
            for (int c = 1; c <= 3; ++c) {
                float t = fmaf(cosr, vt[m - 1][c], fmul(sinr, vt[m][c]));
                vt[m][c] = fmaf(cosr, vt[m][c], -fmul(sinr, vt[m - 1][c]));
                vt[m - 1][c] = t;
            }
            m -= 2; continue;
        }
        if (ll > oldm || m < oldll)
            idir = (fabsf(d[ll]) >= fabsf(d[m])) ? 1 : 2;
        bool deflated = false;
        if (idir == 1) {
            if (fabsf(e[m - 1]) <= fmul(tol, fabsf(d[m]))) { e[m - 1] = 0.0f; continue; }
            float mu = fabsf(d[ll]); sminl = mu;
            for (int lll = ll; lll <= m - 1; ++lll) {
                if (fabsf(e[lll]) <= fmul(tol, mu)) { e[lll] = 0.0f; deflated = true; break; }
                mu = fmul(fabsf(d[lll + 1]), fdiv(mu, fadd(mu, fabsf(e[lll]))));
                sminl = fminf(sminl, mu);
            }
        } else {
            if (fabsf(e[ll]) <= fmul(tol, fabsf(d[ll]))) { e[ll] = 0.0f; continue; }
            float mu = fabsf(d[m]); sminl = mu;
            for (int lll = m - 1; lll >= ll; --lll) {
                if (fabsf(e[lll]) <= fmul(tol, mu)) { e[lll] = 0.0f; deflated = true; break; }
                mu = fmul(fabsf(d[lll]), fdiv(mu, fadd(mu, fabsf(e[lll]))));
                sminl = fminf(sminl, mu);
            }
        }
        if (deflated) continue;
        oldll = ll; oldm = m;
        float shift = 0.0f, rr;
        if (!(fmul(fmul(3.0f, tol), fdiv(sminl, smax)) <= fmaxf(eps, fmul(0.01f, tol)))) {
            float sll;
            if (idir == 1) { sll = fabsf(d[ll]); slas2f(d[m - 1], e[m - 1], d[m], shift, rr); }
            else           { sll = fabsf(d[m]);  slas2f(d[ll], e[ll], d[ll + 1], shift, rr); }
            if (sll > 0.0f) { float q = fdiv(shift, sll); if (fmul(q, q) < eps) shift = 0.0f; }
        }
        iter += m - ll;
        float wc[4], ws[4];
        if (shift == 0.0f) {
            if (idir == 1) {
                float cs = 1.0f, oldcs = 1.0f, sn = 0.0f, oldsn = 0.0f, r2;
                for (int i = ll; i <= m - 1; ++i) {
                    slartgf(fmul(d[i], cs), e[i], cs, sn, r2);
                    if (i > ll) e[i - 1] = fmul(oldsn, r2);
                    slartgf(fmul(oldcs, r2), fmul(d[i + 1], sn), oldcs, oldsn, d[i]);
                    wc[i - ll + 1] = cs; ws[i - ll + 1] = sn;
                }
                float h = fmul(d[m], cs); d[m] = fmul(h, oldcs); e[m - 1] = fmul(h, oldsn);
                if (fabsf(e[m - 1]) <= thresh) e[m - 1] = 0.0f;
                for (int j = 1; j <= m - ll; ++j) rot_rowsf(vt, ll + j - 1, ll + j, wc[j], ws[j]);
            } else {
                float cs = 1.0f, oldcs = 1.0f, sn = 0.0f, oldsn = 0.0f, r2;
                for (int i = m; i >= ll + 1; --i) {
                    slartgf(fmul(d[i], cs), e[i - 1], cs, sn, r2);
                    if (i < m) e[i] = fmul(oldsn, r2);
                    slartgf(fmul(oldcs, r2), fmul(d[i - 1], sn), oldcs, oldsn, d[i]);
                    wc[i - ll] = oldcs; ws[i - ll] = -oldsn;
                }
                float h = fmul(d[ll], cs); d[ll] = fmul(h, oldcs); e[ll] = fmul(h, oldsn);
                if (fabsf(e[ll]) <= thresh) e[ll] = 0.0f;
                for (int j = m - ll; j >= 1; --j) rot_rowsf(vt, ll + j - 1, ll + j, wc[j], ws[j]);
            }
        } else {
            if (idir == 1) {
                float fq = fmul(fsub(fabsf(d[ll]), shift),
                                fadd(copysignf(1.0f, d[ll]), fdiv(shift, d[ll])));
                float g = e[ll], cosr, sinr, cosl, sinl, r2;
                for (int i = ll; i <= m - 1; ++i) {
                    slartgf(fq, g, cosr, sinr, r2);
                    if (i > ll) e[i - 1] = r2;
                    float di = d[i], ei = e[i], dip = d[i + 1];
                    fq         = fmaf(cosr, di, fmul(sinr, ei));
                    float ei_n = fmaf(cosr, ei, -fmul(sinr, di));
                    g = fmul(sinr, dip);
                    float dip_n = fmul(cosr, dip);
                    slartgf(fq, g, cosl, sinl, r2);
                    d[i] = r2;
                    fq       = fmaf(cosl, ei_n, fmul(sinl, dip_n));
                    d[i + 1] = fmaf(cosl, dip_n, -fmul(sinl, ei_n));
                    e[i] = ei_n;
                    if (i < m - 1) { g = fmul(sinl, e[i + 1]); e[i + 1] = fmul(cosl, e[i + 1]); }
                    wc[i - ll + 1] = cosr; ws[i - ll + 1] = sinr;
                }
                e[m - 1] = fq;
                if (fabsf(e[m - 1]) <= thresh) e[m - 1] = 0.0f;
                for (int j = 1; j <= m - ll; ++j) rot_rowsf(vt, ll + j - 1, ll + j, wc[j], ws[j]);
            } else {
                float fq = fmul(fsub(fabsf(d[m]), shift),
                                fadd(copysignf(1.0f, d[m]), fdiv(shift, d[m])));
                float g = e[m - 1], cosr, sinr, cosl, sinl, r2;
                for (int i = m; i >= ll + 1; --i) {
                    slartgf(fq, g, cosr, sinr, r2);
                    if (i < m) e[i] = r2;
                    float di = d[i], em = e[i - 1], dim = d[i - 1];
                    fq         = fmaf(cosr, di, fmul(sinr, em));
                    float em_n = fmaf(cosr, em, -fmul(sinr, di));
                    g = fmul(sinr, dim);
                    float dim_n = fmul(cosr, dim);
                    slartgf(fq, g, cosl, sinl, r2);
                    d[i] = r2;
                    fq       = fmaf(cosl, em_n, fmul(sinl, dim_n));
                    d[i - 1] = fmaf(cosl, dim_n, -fmul(sinl, em_n));
                    e[i - 1] = em_n;
                    if (i > ll + 1) { g = fmul(sinl, e[i - 2]); e[i - 2] = fmul(cosl, e[i - 2]); }
                    wc[i - ll] = cosl; ws[i - ll] = -sinl;   // REVERTED (correct per R8 regression)
                }
                e[ll] = fq;
                if (fabsf(e[ll]) <= thresh) e[ll] = 0.0f;
                for (int j = m - ll; j >= 1; --j) rot_rowsf(vt, ll + j - 1, ll + j, wc[j], ws[j]);
            }
        }
    }
    for (int i = 1; i <= n; ++i) {
        if (d[i] < 0.0f) {
            d[i] = -d[i];
            for (int c = 1; c <= 3; ++c) vt[i][c] = -vt[i][c];
        }
    }
    for (int i = 1; i <= n - 1; ++i) {
        int isub = 1; float smin2 = d[1];
        for (int j = 2; j <= n + 1 - i; ++j)
            if (d[j] <= smin2) { isub = j; smin2 = d[j]; }
        int tgt = n + 1 - i;
        if (isub != tgt) {
            d[isub] = d[tgt]; d[tgt] = smin2;
            for (int c = 1; c <= 3; ++c) { float t = vt[isub][c]; vt[isub][c] = vt[tgt][c]; vt[tgt][c] = t; }
        }
    }
}

// ===========================================================================
// Kernel 0: d2 in f32
// ===========================================================================
__global__ void d2_kernel(const float* __restrict__ x, float* __restrict__ d2) {
    int t = blockIdx.x * blockDim.x + threadIdx.x;
    if (t >= BB * NN) return;
    int b = t / NN, n = t % NN;
    const float* xb = x + b * 3 * NN;
    float xv = xb[n], yv = xb[NN + n], zv = xb[2 * NN + n];
    d2[t] = fadd(fadd(fmul(xv, xv), fmul(yv, yv)), fmul(zv, zv));
}

// ===========================================================================
// Kernel 1: KNN — R13: R10 register shape + 4-deep lookahead mini-list.
// (R13 verified: 80.6 µs, VGPR 40, VALUBusy ~97-99%. Unchanged in R14.)
//
// R11/R12 post-mortem: a 64-VGPR u64 ARRAY goes to scratch no matter the
// launch bounds; R10's 32-VGPR u32 array stayed register-resident.
// So: vals[32] stays u32, lookahead of next 4 candidates in NAMED u64
// scalars l0..l3. Extraction sequence bit-identical to repeated argmax
// (k-way merge of per-lane streams sorted by the global u64 key).
// ===========================================================================
__device__ __forceinline__ unsigned int f32_sortable(float f) {
    unsigned int b = __float_as_uint(f);
    return b ^ ((unsigned int)((int)b >> 31) | 0x80000000u);
}
__device__ __forceinline__ float sortable_f32(unsigned int s) {
    unsigned int b = s ^ (~(unsigned int)((int)s >> 31) | 0x80000000u);
    return __uint_as_float(b);
}

template <int CTRL, int RM>
__device__ __forceinline__ unsigned long long dpp_umax64(unsigned long long k) {
    int nhi = __builtin_amdgcn_update_dpp(0, (int)(unsigned int)(k >> 32), CTRL, RM, 0xF, false);
    int nlo = __builtin_amdgcn_update_dpp(0, (int)(unsigned int)k,         CTRL, RM, 0xF, false);
    unsigned long long nk = ((unsigned long long)(unsigned int)nhi << 32) | (unsigned int)nlo;
    return nk > k ? nk : k;
}

// Pop the lane's best remaining candidate from vals (value desc, slot asc),
// clear it, and return the packed u64 merge key. All indices static.
__device__ __forceinline__ unsigned long long pop_best(unsigned int (&vals)[32], int lane) {
    unsigned int m = vals[0];
    #pragma unroll
    for (int s = 1; s < 32; ++s) m = (vals[s] > m) ? vals[s] : m;   // v_max_u32
    int bs = 0;
    #pragma unroll
    for (int s = 31; s >= 0; --s) if (vals[s] == m) bs = s;          // first match
    #pragma unroll
    for (int s = 0; s < 32; ++s) vals[s] = (s == bs) ? 0u : vals[s]; // clear
    int j = bs * 64 + lane;
    return ((unsigned long long)m << 32) | (unsigned int)(2047 - j);
}

__global__ void __launch_bounds__(256) knn_kernel(const float* __restrict__ x,
                                                  const float* __restrict__ d2,
                                                  int* __restrict__ idx) {
    int lane = threadIdx.x & 63;
    int wid  = threadIdx.x >> 6;
    int row  = blockIdx.x * 4 + wid;
    int b = row / NN, i = row % NN;
    const float* xb  = x  + b * 3 * NN;
    const float* d2b = d2 + b * NN;

    float xi = xb[i], yi = xb[NN + i], zi = xb[2 * NN + i];
    float d2i = d2b[i];

    // 32 candidates per lane, sortable-u32 encoded, static register indexing.
    unsigned int vals[32];
    #pragma unroll
    for (int s = 0; s < 32; ++s) {
        int j = s * 64 + lane;
        float dot = fmul(xi, xb[j]);
        dot = fmaf(yi, xb[NN + j], dot);
        dot = fmaf(zi, xb[2 * NN + j], dot);
        float v = fsub(fsub(fmul(2.0f, dot), d2i), d2b[j]);
        vals[s] = f32_sortable(v);
    }

    // ---- build the 4-deep lookahead mini-list (named scalars, sorted desc)
    unsigned long long l0 = pop_best(vals, lane);
    unsigned long long l1 = pop_best(vals, lane);
    unsigned long long l2 = pop_best(vals, lane);
    unsigned long long l3 = pop_best(vals, lane);

    int* idxrow = idx + row * KK;
    unsigned int c1v = 0, c2v = 0, c3v = 0, c31v = 0, c32v = 0;
    int c1i = 0, c2i = 0, c3i = 0, c31i = 0, c32i = 0;

    #pragma unroll 1
    for (int t = 0; t < KK + 1; ++t) {      // 33 ranks (32 + boundary probe)
        // rare refill: some lane consumed its whole lookahead (won 4+ times)
        if (__any(l0 == 0ull)) {
            bool need = (l0 == 0ull);
            unsigned int m = vals[0];
            #pragma unroll
            for (int s = 1; s < 32; ++s) m = (vals[s] > m) ? vals[s] : m;
            int bs = 0;
            #pragma unroll
            for (int s = 31; s >= 0; --s) if (vals[s] == m) bs = s;
            #pragma unroll
            for (int s = 0; s < 32; ++s)
                vals[s] = (need && s == bs) ? 0u : vals[s];
            unsigned long long ent = ((unsigned long long)m << 32)
                                   | (unsigned int)(2047 - (bs * 64 + lane));
            l0 = need ? ent : l0;
        }

        // wave argmax of heads, pure-VALU DPP cascade; lane 63 ends global max
        unsigned long long k = l0;
        k = dpp_umax64<0x111, 0xF>(k);   // row_shr:1
        k = dpp_umax64<0x112, 0xF>(k);   // row_shr:2
        k = dpp_umax64<0x114, 0xF>(k);   // row_shr:4
        k = dpp_umax64<0x118, 0xF>(k);   // row_shr:8
        k = dpp_umax64<0x142, 0xA>(k);   // row_bcast:15 -> rows 1,3
        k = dpp_umax64<0x143, 0xC>(k);   // row_bcast:31 -> rows 2,3

        unsigned int wbest = (unsigned int)__builtin_amdgcn_readlane((int)(k >> 32), 63);
        unsigned int wlow  = (unsigned int)__builtin_amdgcn_readlane((int)(k & 0xFFFFFFFFull), 63);
        int wj = 2047 - (int)(wlow & 0x7FFu);

        // winner lane pops its head: shift the 4 named scalars down.
        bool amw = ((unsigned int)l0 == wlow);
        l0 = amw ? l1 : l0;
        l1 = amw ? l2 : l1;
        l2 = amw ? l3 : l2;
        l3 = amw ? 0ull : l3;

        // record: ranks 1,2,3,31,32 are deferred for the near-tie probes
        if (t == 1)           { c1v = wbest;  c1i = wj; }
        else if (t == 2)      { c2v = wbest;  c2i = wj; }
        else if (t == 3)      { c3v = wbest;  c3i = wj; }
        else if (t == KK - 1) { c31v = wbest; c31i = wj; }
        else if (t == KK)     { c32v = wbest; c32i = wj; }
        else if (lane == 0)   idxrow[t] = wj;
    }

    if (lane == 0) {
        const float TIE = 4e-7f;
        float r1  = sortable_f32(c1v),  r2  = sortable_f32(c2v), r3 = sortable_f32(c3v);
        float r31 = sortable_f32(c31v), r32 = sortable_f32(c32v);
        if (fabsf(r1 - r2) < TIE) { int ti = c1i; c1i = c2i; c2i = ti; float tv = r1; r1 = r2; r2 = tv; }
        if (fabsf(r2 - r3) < TIE) { int ti = c2i; c2i = c3i; c3i = ti; float tv = r2; r2 = r3; r3 = tv; }
        idxrow[1] = c1i; idxrow[2] = c2i; idxrow[3] = c3i;
        idxrow[KK - 1] = (fabsf(r31 - r32) < TIE) ? c32i : c31i;
    }
}

// ===========================================================================
// Kernel 2: sgesdd emulation (R8 version: slarf1f, fmaf BLAS, f64 snrm2)
// R14: launched with 64-thread workgroups (256 wgs -> all 256 CUs; was 64
// wgs of 256 = only 64 CUs busy). Indexing is flat-t, so bit-identical.
// ===========================================================================
__global__ void eig_kernel(const float* __restrict__ x, const int* __restrict__ idx,
                           float* __restrict__ grad, float* __restrict__ mag) {
    int t = blockIdx.x * blockDim.x + threadIdx.x;
    if (t >= BB * NN) return;
    int b = t / NN;
    const float* xb = x + b * 3 * NN;
    const int* id = idx + t * KK;

    float A[KK][3];
    float s0 = 0.f, s1 = 0.f, s2 = 0.f;
    for (int j = 0; j < KK; ++j) {
        int n = id[j];
        s0 = fadd(s0, xb[n]); s1 = fadd(s1, xb[NN + n]); s2 = fadd(s2, xb[2 * NN + n]);
    }
    float m0 = fdiv(s0, 32.f), m1 = fdiv(s1, 32.f), m2 = fdiv(s2, 32.f);
    for (int j = 0; j < KK; ++j) {
        int n = id[j];
        A[j][0] = fsub(xb[n], m0);
        A[j][1] = fsub(xb[NN + n], m1);
        A[j][2] = fsub(xb[2 * NN + n], m2);
    }

    // ---- sgeqr2 with slarf1f
    for (int i = 0; i < 3; ++i) {
        float alpha = A[i][i];
        double nacc = 0.0;
        for (int r = i + 1; r < KK; ++r) nacc += (double)A[r][i] * (double)A[r][i];
        float xnorm = (float)sqrt(nacc);
        if (xnorm != 0.0f) {
            float beta = -copysignf(slapy2f(alpha, xnorm), alpha);
            float tau  = fdiv(fsub(beta, alpha), beta);
            float scal = fdiv(1.0f, fsub(alpha, beta));
            for (int r = i + 1; r < KK; ++r) A[r][i] = fmul(A[r][i], scal);
            A[i][i] = beta;
            for (int j = i + 1; j < 3; ++j) {
                float acc = 0.0f;
                for (int r = i + 1; r < KK; ++r) acc = fmaf(A[r][i], A[r][j], acc);
                float w = fadd(acc, A[i][j]);
                A[i][j] = fmaf(-tau, w, A[i][j]);
                float temp = fmul(-tau, w);
                for (int r = i + 1; r < KK; ++r) A[r][j] = fmaf(A[r][i], temp, A[r][j]);
            }
        }
    }
    float B11 = A[0][0], B12 = A[0][1], B13 = A[0][2];
    float B22 = A[1][1], B23 = A[1][2], B33 = A[2][2];

    // ---- sgebd2 with slarf1f
    float d[4], e[3];
    float taup = 0.0f, v2p = 0.0f;
    d[1] = B11;
    float B32 = 0.0f;
    if (B13 != 0.0f) {
        float xn = fsqrtf32(fmul(B13, B13));
        float beta = -copysignf(slapy2f(B12, xn), B12);
        taup = fdiv(fsub(beta, B12), beta);
        float scal = fdiv(1.0f, fsub(B12, beta));
        v2p = fmul(B13, scal);
        e[1] = beta;
        float w2 = fadd(fmul(B23, v2p), B22);
        float w3 = fmul(B33, v2p);
        B22 = fmaf(-taup, w2, B22);
        B32 = fmul(-taup, w3);
        float tmp = fmul(-taup, v2p);
        B23 = fmaf(w2, tmp, B23);
        B33 = fmaf(w3, tmp, B33);
    } else e[1] = B12;
    if (B32 != 0.0f) {
        float xn = fsqrtf32(fmul(B32, B32));
        float beta = -copysignf(slapy2f(B22, xn), B22);
        float tauq = fdiv(fsub(beta, B22), beta);
        float scal = fdiv(1.0f, fsub(B22, beta));
        float v2 = fmul(B32, scal);
        d[2] = beta;
        float w = fadd(fmul(v2, B33), B23);
        B23 = fmaf(-tauq, w, B23);
        float tmp = fmul(-tauq, w);
        B33 = fmaf(v2, tmp, B33);
    } else d[2] = B22;
    e[2] = B23;
    d[3] = B33;

    // ---- sbdsqr with VT = I
    float vt[4][4];
    for (int r = 1; r <= 3; ++r)
        for (int c = 1; c <= 3; ++c) vt[r][c] = (r == c) ? 1.0f : 0.0f;
    bdsqr3f(d, e, vt);

    // ---- sormbr 'P','R','T' via slarf1f
    if (taup != 0.0f) {
        float tmp = fmul(-taup, v2p);
        for (int r = 1; r <= 3; ++r) {
            float w = fadd(fmul(vt[r][3], v2p), vt[r][2]);
            vt[r][2] = fmaf(-taup, w, vt[r][2]);
            vt[r][3] = fmaf(w, tmp, vt[r][3]);
        }
    }

    int im = 1;
    if (d[2] > d[im]) im = 2;
    if (d[3] > d[im]) im = 3;
    grad[t * 3 + 0] = vt[im][1];
    grad[t * 3 + 1] = vt[im][2];
    grad[t * 3 + 2] = vt[im][3];
    mag[t] = fsqrtf32(d[im]);
}

// ===========================================================================
// Kernel 3: HOG histogram, strict f32 replica (CR-f32 angles).
// R14: 64-thread workgroups (see eig note) — flat-t indexing, bit-identical.
// ===========================================================================
__global__ void hist_kernel(const int* __restrict__ idx, const float* __restrict__ grad,
                            const float* __restrict__ mag, float* __restrict__ out) {
    int t = blockIdx.x * blockDim.x + threadIdx.x;
    if (t >= BB * NN) return;
    int b = t / NN, n = t % NN;
    const int* id = idx + t * KK;
    const float r2d = (float)(180.0 / M_PI);

    float h1[9][2], h2[9][2];
    #pragma unroll
    for (int q = 0; q < 9; ++q) { h1[q][0] = h1[q][1] = 0.f; h2[q][0] = h2[q][1] = 0.f; }

    for (int j = 0; j < KK; ++j) {
        int jj = b * NN + id[j];
        float gx = grad[jj * 3 + 0];
        float gy = grad[jj * 3 + 1];
        float gz = grad[jj * 3 + 2];
        float m  = mag[jj];

        float zen = (float)acos((double)gz);
        float zd  = fmul(zen, r2d);
        float q0  = fdiv(gy, gx);
        float azr = (float)atan((double)q0);
        float ad  = fmul(azr, r2d);

        float a0 = (zd != zd) ? -2147483648.0f : (float)(int)zd;
        float a1 = (ad != ad) ? -2147483648.0f : (float)(int)ad;

        #pragma unroll
        for (int c = 0; c < 2; ++c) {
            float a = (c == 0) ? a0 : a1;
            if (a < 0.0f) a = fadd(a, 180.0f);
            float tq = fdiv(a, 20.0f);
            float t2 = fsub(tq, 0.5f);
            float fb = floorf(t2);
            float bin = fmodf(fb, 9.0f); if (bin != 0.0f && bin < 0.0f) bin = fadd(bin, 9.0f);
            float b1 = fadd(bin, 1.0f);
            float b1m = fmodf(b1, 9.0f);
            float fc = fmul(20.0f, fadd(b1m, 0.5f));
            float df = fsub(fc, a);
            float rm = fmodf(df, 180.0f); if (rm != 0.0f && rm < 0.0f) rm = fadd(rm, 180.0f);
            float v1 = fdiv(fmul(m, rm), 20.0f);
            float sc = fmul(20.0f, fadd(bin, 0.5f));
            float ds = fsub(a, sc);
            float rm2 = fmodf(ds, 180.0f); if (rm2 != 0.0f && rm2 < 0.0f) rm2 = fadd(rm2, 180.0f);
            float v2 = fdiv(fmul(m, rm2), 20.0f);
            int bi = (int)bin;
            int b2 = bi + 1; if (b2 >= 9) b2 -= 9;
            h1[bi][c] = fadd(h1[bi][c], v1);
            h2[b2][c] = fadd(h2[b2][c], v2);
        }
    }

    float* o = out + b * (18 * NN) + n * 18;
    #pragma unroll
    for (int c = 0; c < 2; ++c) {
        float hist[9];
        #pragma unroll
        for (int q = 0; q < 9; ++q) hist[q] = fadd(h1[q][c], h2[q][c]);
        float acc = 0.0f;
        #pragma unroll
        for (int q = 0; q < 9; ++q) acc = fadd(acc, fmul(hist[q], hist[q]));
        float nr = fsqrtf32(acc);
        float den = fmaxf(nr, 1e-12f);
        #pragma unroll
        for (int q = 0; q < 9; ++q) o[q * 2 + c] = fdiv(hist[q], den);
    }
}

// ===========================================================================
extern "C" void kernel_launch(void* const* d_in, const int* in_sizes, int n_in,
                              void* d_out, int out_size, void* d_ws, size_t ws_size,
                              hipStream_t stream) {
    const float* x = (const float*)d_in[0];
    float* out = (float*)d_out;

    char* ws = (char*)d_ws;
    size_t off = 0;
    int* idx = (int*)(ws + off);        off += (size_t)BB * NN * KK * sizeof(int);
    float* d2 = (float*)(ws + off);     off += (size_t)BB * NN * sizeof(float);
    float* grad = (float*)(ws + off);   off += (size_t)BB * NN * 3 * sizeof(float);
    float* mag = (float*)(ws + off);

    // R14: 64-thread workgroups for the per-point serial kernels — 256 wgs
    // cover all 256 CUs (was 64 wgs of 256 = 25% of the chip).
    d2_kernel <<<(BB * NN + 63) / 64, 64, 0, stream>>>(x, d2);
    knn_kernel<<<BB * NN / 4, 256, 0, stream>>>(x, d2, idx);
    eig_kernel<<<(BB * NN + 63) / 64, 64, 0, stream>>>(x, idx, grad, mag);
    hist_kernel<<<(BB * NN + 63) / 64, 64, 0, stream>>>(idx, grad, mag, out);
}

// Round 6
// 189.303 us; speedup vs baseline: 1.8730x; 1.1233x over previous
//
#include <hip/hip_runtime.h>
#include <math.h>

// Problem constants: B=8, N=2048, K=32, 9 bins, width 20.
#define BB 8
#define NN 2048
#define KK 32

// ===========================================================================
// Exactly-rounded f32 helpers, R15: native f32 _rn intrinsics.
// Previous rounds used (float)((double)a op (double)b) to get correctly-
// rounded f32 without contraction. By Figueroa's theorem (double rounding is
// innocuous for +,-,*,/,sqrt when P=53 >= 2p+2=50), that is BIT-IDENTICAL to
// the correctly-rounded f32 hardware op. __f*_rn are non-contractible, so
// the no-fusion property is kept while cutting each op from ~4 dependent
// instructions (cvt+f64+cvt) to 1. fmaf() stays wherever the referee's
// compiler (-ffp-contract=fast) fuses.
// ===========================================================================
__device__ __forceinline__ float fadd(float a, float b){ return __fadd_rn(a, b); }
__device__ __forceinline__ float fsub(float a, float b){ return __fsub_rn(a, b); }
__device__ __forceinline__ float fmul(float a, float b){ return __fmul_rn(a, b); }
__device__ __forceinline__ float fdiv(float a, float b){ return __fdiv_rn(a, b); }
__device__ __forceinline__ float fsqrtf32(float a){ return __fsqrt_rn(a); }

// ===========================================================================
// LAPACK 3.12 single-precision helpers, gfortran -ffp-contract=fast model.
// ===========================================================================
__device__ float slapy2f(float x, float y) {
    float xa = fabsf(x), ya = fabsf(y);
    float w = fmaxf(xa, ya), z = fminf(xa, ya);
    if (z == 0.0f) return w;
    float q = fdiv(z, w);
    return fmul(w, fsqrtf32(fmaf(q, q, 1.0f)));
}

__device__ void slartgf(float f, float g, float& c, float& s, float& r) {
    if (g == 0.0f) { c = 1.0f; s = 0.0f; r = f; }
    else if (f == 0.0f) { c = 0.0f; s = copysignf(1.0f, g); r = fabsf(g); }
    else {
        float d = fsqrtf32(fmaf(f, f, fmul(g, g)));
        c = fdiv(fabsf(f), d);
        r = copysignf(d, f);
        s = fdiv(g, r);
    }
}

__device__ void slas2f(float f, float g, float h, float& ssmin, float& ssmax) {
    float fa = fabsf(f), ga = fabsf(g), ha = fabsf(h);
    float fhmn = fminf(fa, ha), fhmx = fmaxf(fa, ha);
    if (fhmn == 0.0f) {
        ssmin = 0.0f;
        if (fhmx == 0.0f) ssmax = ga;
        else {
            float mx = fmaxf(fhmx, ga), mn = fminf(fhmx, ga);
            float q = fdiv(mn, mx);
            ssmax = fmul(mx, fsqrtf32(fmaf(q, q, 1.0f)));
        }
    } else {
        if (ga < fhmx) {
            float as = fadd(1.0f, fdiv(fhmn, fhmx));
            float at = fdiv(fsub(fhmx, fhmn), fhmx);
            float q = fdiv(ga, fhmx); float au = fmul(q, q);
            float c = fdiv(2.0f, fadd(fsqrtf32(fmaf(as, as, au)),
                                      fsqrtf32(fmaf(at, at, au))));
            ssmin = fmul(fhmn, c); ssmax = fdiv(fhmx, c);
        } else {
            float au = fdiv(fhmx, ga);
            if (au == 0.0f) { ssmin = fdiv(fmul(fhmn, fhmx), ga); ssmax = ga; }
            else {
                float as = fadd(1.0f, fdiv(fhmn, fhmx));
                float at = fdiv(fsub(fhmx, fhmn), fhmx);
                float t1 = fmul(as, au), t2 = fmul(at, au);
                float c = fdiv(1.0f, fadd(fsqrtf32(fmaf(t1, t1, 1.0f)),
                                          fsqrtf32(fmaf(t2, t2, 1.0f))));
                ssmin = fmul(fmul(fhmn, c), au); ssmin = fadd(ssmin, ssmin);
                ssmax = fdiv(ga, fadd(c, c));
            }
        }
    }
}

__device__ void slasv2f(float f, float g, float h,
                        float& ssmin, float& ssmax,
                        float& snr, float& csr, float& snl, float& csl) {
    const float eps = 5.9604644775390625e-08f;
    float ft = f, fa = fabsf(f), ht = h, ha = fabsf(h);
    int pmax = 1;
    bool swp = (ha > fa);
    if (swp) { pmax = 3; float t = ft; ft = ht; ht = t; t = fa; fa = ha; ha = t; }
    float gt = g, ga = fabsf(gt);
    float clt = 0.f, crt = 0.f, slt = 0.f, srt = 0.f;
    if (ga == 0.0f) {
        ssmin = ha; ssmax = fa; clt = 1.0f; crt = 1.0f; slt = 0.0f; srt = 0.0f;
    } else {
        bool gasmal = true;
        if (ga > fa) {
            pmax = 2;
            if (fdiv(fa, ga) < eps) {
                gasmal = false;
                ssmax = ga;
                ssmin = (ha > 1.0f) ? fdiv(fa, fdiv(ga, ha)) : fmul(fdiv(fa, ga), ha);
                clt = 1.0f; slt = fdiv(ht, gt); srt = 1.0f; crt = fdiv(ft, gt);
            }
        }
        if (gasmal) {
            float dd = fsub(fa, ha);
            float l = (dd == fa) ? 1.0f : fdiv(dd, fa);
            float mm = fdiv(gt, ft);
            float t = fsub(2.0f, l);
            float m2 = fmul(mm, mm);
            float s = fsqrtf32(fmaf(t, t, m2));
            float r = (l == 0.0f) ? fabsf(mm) : fsqrtf32(fmaf(l, l, m2));
            float a = fmul(0.5f, fadd(s, r));
            ssmin = fdiv(ha, a);
            ssmax = fmul(fa, a);
            if (m2 == 0.0f) {
                t = (l == 0.0f) ? fmul(copysignf(2.0f, ft), copysignf(1.0f, gt))
                                : fadd(fdiv(gt, copysignf(dd, ft)), fdiv(mm, t));
            } else {
                t = fmul(fadd(fdiv(mm, fadd(s, t)), fdiv(mm, fadd(r, l))), fadd(1.0f, a));
            }
            float l2 = fsqrtf32(fmaf(t, t, 4.0f));
            crt = fdiv(2.0f, l2); srt = fdiv(t, l2);
            clt = fdiv(fmaf(srt, mm, crt), a);
            slt = fdiv(fmul(fdiv(ht, ft), srt), a);
        }
    }
    if (swp) { csl = srt; snl = crt; csr = slt; snr = clt; }
    else     { csl = clt; snl = slt; csr = crt; snr = srt; }
    float tsign = 0.0f;
    if (pmax == 1) tsign = fmul(fmul(copysignf(1.f, csr), copysignf(1.f, csl)), copysignf(1.f, f));
    if (pmax == 2) tsign = fmul(fmul(copysignf(1.f, snr), copysignf(1.f, csl)), copysignf(1.f, g));
    if (pmax == 3) tsign = fmul(fmul(copysignf(1.f, snr), copysignf(1.f, snl)), copysignf(1.f, h));
    ssmax = copysignf(fabsf(ssmax), tsign);
    ssmin = copysignf(fabsf(ssmin), fmul(tsign, fmul(copysignf(1.f, f), copysignf(1.f, h))));
}

// slasr 'L','V' rotation on vt rows lo,hi (1-indexed), fma-contracted
__device__ __forceinline__ void rot_rowsf(float vt[4][4], int lo, int hi, float cc, float ss) {
    #pragma unroll
    for (int c = 1; c <= 3; ++c) {
        float t = vt[hi][c];
        vt[hi][c] = fmaf(cc, t, -fmul(ss, vt[lo][c]));
        vt[lo][c] = fmaf(ss, t, fmul(cc, vt[lo][c]));
    }
}

// sbdsqr for n=3 upper bidiagonal. R9: idir2-shifted VT pairing REVERTED to
// (COSL, -SINL) — R8's (COSR,-SINR) regressed 0.0898->0.6455, proving the
// original Fortran reading (2nd slartg = VT side in bottom-up sweeps) right.
__device__ void bdsqr3f(float* d, float* e, float vt[4][4]) {
    const float eps  = 5.9604644775390625e-08f;
    const float unfl = 1.1754943508222875e-38f;
    const int n = 3;
    const float tol = fmul(10.0f, eps);
    float thresh;
    {
        float sminoa = fabsf(d[1]);
        if (sminoa != 0.0f) {
            float mu = sminoa;
            for (int i = 2; i <= n; ++i) {
                mu = fmul(fabsf(d[i]), fdiv(mu, fadd(mu, fabsf(e[i - 1]))));
                sminoa = fminf(sminoa, mu);
                if (sminoa == 0.0f) break;
            }
        }
        sminoa = fdiv(sminoa, fsqrtf32(3.0f));
        thresh = fmaxf(fmul(tol, sminoa), fmul(54.0f, unfl));
    }
    int m = n, iter = 0, oldll = -1, oldm = -1, idir = 0;
    float sminl = 0.0f;
    while (m > 1) {
        if (iter > 54) break;
        float smax = fabsf(d[m]);
        int ll = 0; bool split = false;
        for (int lll = 1; lll <= m - 1; ++lll) {
            int l2 = m - lll;
            float abss = fabsf(d[l2]), abse = fabsf(e[l2]);
            if (abse <= thresh) { ll = l2; split = true; break; }
            smax = fmaxf(smax, fmaxf(abss, abse));
        }
        if (split) {
            e[ll] = 0.0f;
            if (ll == m - 1) { m = m - 1; continue; }
            ll = ll + 1;
        } else ll = 1;
        if (ll == m - 1) {
            float sigmn, sigmx, sinr, cosr, sinl, cosl;
            slasv2f(d[m - 1], e[m - 1], d[m], sigmn, sigmx, sinr, cosr, sinl, cosl);
            d[m - 1] = sigmx; e[m - 1] = 0.0f; d[m] = sigmn;
            #pragma unroll
            for (int c = 1; c <= 3; ++c) {
                float t = fmaf(cosr, vt[m - 1][c], fmul(sinr, vt[m][c]));
                vt[m][c] = fmaf(cosr, vt[m][c], -fmul(sinr, vt[m - 1][c]));
                vt[m - 1][c] = t;
            }
            m -= 2; continue;
        }
        if (ll > oldm || m < oldll)
            idir = (fabsf(d[ll]) >= fabsf(d[m])) ? 1 : 2;
        bool deflated = false;
        if (idir == 1) {
            if (fabsf(e[m - 1]) <= fmul(tol, fabsf(d[m]))) { e[m - 1] = 0.0f; continue; }
            float mu = fabsf(d[ll]); sminl = mu;
            for (int lll = ll; lll <= m - 1; ++lll) {
                if (fabsf(e[lll]) <= fmul(tol, mu)) { e[lll] = 0.0f; deflated = true; break; }
                mu = fmul(fabsf(d[lll + 1]), fdiv(mu, fadd(mu, fabsf(e[lll]))));
                sminl = fminf(sminl, mu);
            }
        } else {
            if (fabsf(e[ll]) <= fmul(tol, fabsf(d[ll]))) { e[ll] = 0.0f; continue; }
            float mu = fabsf(d[m]); sminl = mu;
            for (int lll = m - 1; lll >= ll; --lll) {
                if (fabsf(e[lll]) <= fmul(tol, mu)) { e[lll] = 0.0f; deflated = true; break; }
                mu = fmul(fabsf(d[lll]), fdiv(mu, fadd(mu, fabsf(e[lll]))));
                sminl = fminf(sminl, mu);
            }
        }
        if (deflated) continue;
        oldll = ll; oldm = m;
        float shift = 0.0f, rr;
        if (!(fmul(fmul(3.0f, tol), fdiv(sminl, smax)) <= fmaxf(eps, fmul(0.01f, tol)))) {
            float sll;
            if (idir == 1) { sll = fabsf(d[ll]); slas2f(d[m - 1], e[m - 1], d[m], shift, rr); }
            else           { sll = fabsf(d[m]);  slas2f(d[ll], e[ll], d[ll + 1], shift, rr); }
            if (sll > 0.0f) { float q = fdiv(shift, sll); if (fmul(q, q) < eps) shift = 0.0f; }
        }
        iter += m - ll;
        float wc[4], ws[4];
        if (shift == 0.0f) {
            if (idir == 1) {
                float cs = 1.0f, oldcs = 1.0f, sn = 0.0f, oldsn = 0.0f, r2;
                for (int i = ll; i <= m - 1; ++i) {
                    slartgf(fmul(d[i], cs), e[i], cs, sn, r2);
                    if (i > ll) e[i - 1] = fmul(oldsn, r2);
                    slartgf(fmul(oldcs, r2), fmul(d[i + 1], sn), oldcs, oldsn, d[i]);
                    wc[i - ll + 1] = cs; ws[i - ll + 1] = sn;
                }
                float h = fmul(d[m], cs); d[m] = fmul(h, oldcs); e[m - 1] = fmul(h, oldsn);
                if (fabsf(e[m - 1]) <= thresh) e[m - 1] = 0.0f;
                for (int j = 1; j <= m - ll; ++j) rot_rowsf(vt, ll + j - 1, ll + j, wc[j], ws[j]);
            } else {
                float cs = 1.0f, oldcs = 1.0f, sn = 0.0f, oldsn = 0.0f, r2;
                for (int i = m; i >= ll + 1; --i) {
                    slartgf(fmul(d[i], cs), e[i - 1], cs, sn, r2);
                    if (i < m) e[i] = fmul(oldsn, r2);
                    slartgf(fmul(oldcs, r2), fmul(d[i - 1], sn), oldcs, oldsn, d[i]);
                    wc[i - ll] = oldcs; ws[i - ll] = -oldsn;
                }
                float h = fmul(d[ll], cs); d[ll] = fmul(h, oldcs); e[ll] = fmul(h, oldsn);
                if (fabsf(e[ll]) <= thresh) e[ll] = 0.0f;
                for (int j = m - ll; j >= 1; --j) rot_rowsf(vt, ll + j - 1, ll + j, wc[j], ws[j]);
            }
        } else {
            if (idir == 1) {
                float fq = fmul(fsub(fabsf(d[ll]), shift),
                                fadd(copysignf(1.0f, d[ll]), fdiv(shift, d[ll])));
                float g = e[ll], cosr, sinr, cosl, sinl, r2;
                for (int i = ll; i <= m - 1; ++i) {
                    slartgf(fq, g, cosr, sinr, r2);
                    if (i > ll) e[i - 1] = r2;
                    float di = d[i], ei = e[i], dip = d[i + 1];
                    fq         = fmaf(cosr, di, fmul(sinr, ei));
                    float ei_n = fmaf(cosr, ei, -fmul(sinr, di));
                    g = fmul(sinr, dip);
                    float dip_n = fmul(cosr, dip);
                    slartgf(fq, g, cosl, sinl, r2);
                    d[i] = r2;
                    fq       = fmaf(cosl, ei_n, fmul(sinl, dip_n));
                    d[i + 1] = fmaf(cosl, dip_n, -fmul(sinl, ei_n));
                    e[i] = ei_n;
                    if (i < m - 1) { g = fmul(sinl, e[i + 1]); e[i + 1] = fmul(cosl, e[i + 1]); }
                    wc[i - ll + 1] = cosr; ws[i - ll + 1] = sinr;
                }
                e[m - 1] = fq;
                if (fabsf(e[m - 1]) <= thresh) e[m - 1] = 0.0f;
                for (int j = 1; j <= m - ll; ++j) rot_rowsf(vt, ll + j - 1, ll + j, wc[j], ws[j]);
            } else {
                float fq = fmul(fsub(fabsf(d[m]), shift),
                                fadd(copysignf(1.0f, d[m]), fdiv(shift, d[m])));
                float g = e[m - 1], cosr, sinr, cosl, sinl, r2;
                for (int i = m; i >= ll + 1; --i) {
                    slartgf(fq, g, cosr, sinr, r2);
                    if (i < m) e[i] = r2;
                    float di = d[i], em = e[i - 1], dim = d[i - 1];
                    fq         = fmaf(cosr, di, fmul(sinr, em));
                    float em_n = fmaf(cosr, em, -fmul(sinr, di));
                    g = fmul(sinr, dim);
                    float dim_n = fmul(cosr, dim);
                    slartgf(fq, g, cosl, sinl, r2);
                    d[i] = r2;
                    fq       = fmaf(cosl, em_n, fmul(sinl, dim_n));
                    d[i - 1] = fmaf(cosl, dim_n, -fmul(sinl, em_n));
                    e[i - 1] = em_n;
                    if (i > ll + 1) { g = fmul(sinl, e[i - 2]); e[i - 2] = fmul(cosl, e[i - 2]); }
                    wc[i - ll] = cosl; ws[i - ll] = -sinl;   // REVERTED (correct per R8 regression)
                }
                e[ll] = fq;
                if (fabsf(e[ll]) <= thresh) e[ll] = 0.0f;
                for (int j = m - ll; j >= 1; --j) rot_rowsf(vt, ll + j - 1, ll + j, wc[j], ws[j]);
            }
        }
    }
    for (int i = 1; i <= n; ++i) {
        if (d[i] < 0.0f) {
            d[i] = -d[i];
            for (int c = 1; c <= 3; ++c) vt[i][c] = -vt[i][c];
        }
    }
    for (int i = 1; i <= n - 1; ++i) {
        int isub = 1; float smin2 = d[1];
        for (int j = 2; j <= n + 1 - i; ++j)
            if (d[j] <= smin2) { isub = j; smin2 = d[j]; }
        int tgt = n + 1 - i;
        if (isub != tgt) {
            d[isub] = d[tgt]; d[tgt] = smin2;
            for (int c = 1; c <= 3; ++c) { float t = vt[isub][c]; vt[isub][c] = vt[tgt][c]; vt[tgt][c] = t; }
        }
    }
}

// ===========================================================================
// Kernel 0: d2 in f32
// ===========================================================================
__global__ void d2_kernel(const float* __restrict__ x, float* __restrict__ d2) {
    int t = blockIdx.x * blockDim.x + threadIdx.x;
    if (t >= BB * NN) return;
    int b = t / NN, n = t % NN;
    const float* xb = x + b * 3 * NN;
    float xv = xb[n], yv = xb[NN + n], zv = xb[2 * NN + n];
    d2[t] = fadd(fadd(fmul(xv, xv), fmul(yv, yv)), fmul(zv, zv));
}

// ===========================================================================
// Kernel 1: KNN — R13 structure (verified 80.6 µs, VGPR 40, VALUBusy ~97%).
// vals[32] u32 register-resident + 4-deep lookahead in NAMED u64 scalars.
// Extraction sequence bit-identical to repeated argmax (k-way merge).
// ===========================================================================
__device__ __forceinline__ unsigned int f32_sortable(float f) {
    unsigned int b = __float_as_uint(f);
    return b ^ ((unsigned int)((int)b >> 31) | 0x80000000u);
}
__device__ __forceinline__ float sortable_f32(unsigned int s) {
    unsigned int b = s ^ (~(unsigned int)((int)s >> 31) | 0x80000000u);
    return __uint_as_float(b);
}

template <int CTRL, int RM>
__device__ __forceinline__ unsigned long long dpp_umax64(unsigned long long k) {
    int nhi = __builtin_amdgcn_update_dpp(0, (int)(unsigned int)(k >> 32), CTRL, RM, 0xF, false);
    int nlo = __builtin_amdgcn_update_dpp(0, (int)(unsigned int)k,         CTRL, RM, 0xF, false);
    unsigned long long nk = ((unsigned long long)(unsigned int)nhi << 32) | (unsigned int)nlo;
    return nk > k ? nk : k;
}

// Pop the lane's best remaining candidate from vals (value desc, slot asc),
// clear it, and return the packed u64 merge key. All indices static.
__device__ __forceinline__ unsigned long long pop_best(unsigned int (&vals)[32], int lane) {
    unsigned int m = vals[0];
    #pragma unroll
    for (int s = 1; s < 32; ++s) m = (vals[s] > m) ? vals[s] : m;   // v_max_u32
    int bs = 0;
    #pragma unroll
    for (int s = 31; s >= 0; --s) if (vals[s] == m) bs = s;          // first match
    #pragma unroll
    for (int s = 0; s < 32; ++s) vals[s] = (s == bs) ? 0u : vals[s]; // clear
    int j = bs * 64 + lane;
    return ((unsigned long long)m << 32) | (unsigned int)(2047 - j);
}

__global__ void __launch_bounds__(256) knn_kernel(const float* __restrict__ x,
                                                  const float* __restrict__ d2,
                                                  int* __restrict__ idx) {
    int lane = threadIdx.x & 63;
    int wid  = threadIdx.x >> 6;
    int row  = blockIdx.x * 4 + wid;
    int b = row / NN, i = row % NN;
    const float* xb  = x  + b * 3 * NN;
    const float* d2b = d2 + b * NN;

    float xi = xb[i], yi = xb[NN + i], zi = xb[2 * NN + i];
    float d2i = d2b[i];

    // 32 candidates per lane, sortable-u32 encoded, static register indexing.
    unsigned int vals[32];
    #pragma unroll
    for (int s = 0; s < 32; ++s) {
        int j = s * 64 + lane;
        float dot = fmul(xi, xb[j]);
        dot = fmaf(yi, xb[NN + j], dot);
        dot = fmaf(zi, xb[2 * NN + j], dot);
        float v = fsub(fsub(fmul(2.0f, dot), d2i), d2b[j]);
        vals[s] = f32_sortable(v);
    }

    // ---- build the 4-deep lookahead mini-list (named scalars, sorted desc)
    unsigned long long l0 = pop_best(vals, lane);
    unsigned long long l1 = pop_best(vals, lane);
    unsigned long long l2 = pop_best(vals, lane);
    unsigned long long l3 = pop_best(vals, lane);

    int* idxrow = idx + row * KK;
    unsigned int c1v = 0, c2v = 0, c3v = 0, c31v = 0, c32v = 0;
    int c1i = 0, c2i = 0, c3i = 0, c31i = 0, c32i = 0;

    #pragma unroll 1
    for (int t = 0; t < KK + 1; ++t) {      // 33 ranks (32 + boundary probe)
        // rare refill: some lane consumed its whole lookahead (won 4+ times)
        if (__any(l0 == 0ull)) {
            bool need = (l0 == 0ull);
            unsigned int m = vals[0];
            #pragma unroll
            for (int s = 1; s < 32; ++s) m = (vals[s] > m) ? vals[s] : m;
            int bs = 0;
            #pragma unroll
            for (int s = 31; s >= 0; --s) if (vals[s] == m) bs = s;
            #pragma unroll
            for (int s = 0; s < 32; ++s)
                vals[s] = (need && s == bs) ? 0u : vals[s];
            unsigned long long ent = ((unsigned long long)m << 32)
                                   | (unsigned int)(2047 - (bs * 64 + lane));
            l0 = need ? ent : l0;
        }

        // wave argmax of heads, pure-VALU DPP cascade; lane 63 ends global max
        unsigned long long k = l0;
        k = dpp_umax64<0x111, 0xF>(k);   // row_shr:1
        k = dpp_umax64<0x112, 0xF>(k);   // row_shr:2
        k = dpp_umax64<0x114, 0xF>(k);   // row_shr:4
        k = dpp_umax64<0x118, 0xF>(k);   // row_shr:8
        k = dpp_umax64<0x142, 0xA>(k);   // row_bcast:15 -> rows 1,3
        k = dpp_umax64<0x143, 0xC>(k);   // row_bcast:31 -> rows 2,3

        unsigned int wbest = (unsigned int)__builtin_amdgcn_readlane((int)(k >> 32), 63);
        unsigned int wlow  = (unsigned int)__builtin_amdgcn_readlane((int)(k & 0xFFFFFFFFull), 63);
        int wj = 2047 - (int)(wlow & 0x7FFu);

        // winner lane pops its head: shift the 4 named scalars down.
        bool amw = ((unsigned int)l0 == wlow);
        l0 = amw ? l1 : l0;
        l1 = amw ? l2 : l1;
        l2 = amw ? l3 : l2;
        l3 = amw ? 0ull : l3;

        // record: ranks 1,2,3,31,32 are deferred for the near-tie probes
        if (t == 1)           { c1v = wbest;  c1i = wj; }
        else if (t == 2)      { c2v = wbest;  c2i = wj; }
        else if (t == 3)      { c3v = wbest;  c3i = wj; }
        else if (t == KK - 1) { c31v = wbest; c31i = wj; }
        else if (t == KK)     { c32v = wbest; c32i = wj; }
        else if (lane == 0)   idxrow[t] = wj;
    }

    if (lane == 0) {
        const float TIE = 4e-7f;
        float r1  = sortable_f32(c1v),  r2  = sortable_f32(c2v), r3 = sortable_f32(c3v);
        float r31 = sortable_f32(c31v), r32 = sortable_f32(c32v);
        if (fabsf(r1 - r2) < TIE) { int ti = c1i; c1i = c2i; c2i = ti; float tv = r1; r1 = r2; r2 = tv; }
        if (fabsf(r2 - r3) < TIE) { int ti = c2i; c2i = c3i; c3i = ti; float tv = r2; r2 = r3; r3 = tv; }
        idxrow[1] = c1i; idxrow[2] = c2i; idxrow[3] = c3i;
        idxrow[KK - 1] = (fabsf(r31 - r32) < TIE) ? c32i : c31i;
    }
}

// ===========================================================================
// Kernel 2: sgesdd emulation (R8 math). R15: #pragma unroll on the KK loops
// so A[32][3] stays register-indexed (VGPR pressure is free at 1 wave/SIMD).
// ===========================================================================
__global__ void eig_kernel(const float* __restrict__ x, const int* __restrict__ idx,
                           float* __restrict__ grad, float* __restrict__ mag) {
    int t = blockIdx.x * blockDim.x + threadIdx.x;
    if (t >= BB * NN) return;
    int b = t / NN;
    const float* xb = x + b * 3 * NN;
    const int* id = idx + t * KK;

    float A[KK][3];
    float s0 = 0.f, s1 = 0.f, s2 = 0.f;
    #pragma unroll
    for (int j = 0; j < KK; ++j) {
        int n = id[j];
        s0 = fadd(s0, xb[n]); s1 = fadd(s1, xb[NN + n]); s2 = fadd(s2, xb[2 * NN + n]);
    }
    float m0 = fdiv(s0, 32.f), m1 = fdiv(s1, 32.f), m2 = fdiv(s2, 32.f);
    #pragma unroll
    for (int j = 0; j < KK; ++j) {
        int n = id[j];
        A[j][0] = fsub(xb[n], m0);
        A[j][1] = fsub(xb[NN + n], m1);
        A[j][2] = fsub(xb[2 * NN + n], m2);
    }

    // ---- sgeqr2 with slarf1f
    #pragma unroll
    for (int i = 0; i < 3; ++i) {
        float alpha = A[i][i];
        double nacc = 0.0;
        #pragma unroll
        for (int r = i + 1; r < KK; ++r) nacc += (double)A[r][i] * (double)A[r][i];
        float xnorm = (float)sqrt(nacc);
        if (xnorm != 0.0f) {
            float beta = -copysignf(slapy2f(alpha, xnorm), alpha);
            float tau  = fdiv(fsub(beta, alpha), beta);
            float scal = fdiv(1.0f, fsub(alpha, beta));
            #pragma unroll
            for (int r = i + 1; r < KK; ++r) A[r][i] = fmul(A[r][i], scal);
            A[i][i] = beta;
            #pragma unroll
            for (int j = i + 1; j < 3; ++j) {
                float acc = 0.0f;
                #pragma unroll
                for (int r = i + 1; r < KK; ++r) acc = fmaf(A[r][i], A[r][j], acc);
                float w = fadd(acc, A[i][j]);
                A[i][j] = fmaf(-tau, w, A[i][j]);
                float temp = fmul(-tau, w);
                #pragma unroll
                for (int r = i + 1; r < KK; ++r) A[r][j] = fmaf(A[r][i], temp, A[r][j]);
            }
        }
    }
    float B11 = A[0][0], B12 = A[0][1], B13 = A[0][2];
    float B22 = A[1][1], B23 = A[1][2], B33 = A[2][2];

    // ---- sgebd2 with slarf1f
    float d[4], e[3];
    float taup = 0.0f, v2p = 0.0f;
    d[1] = B11;
    float B32 = 0.0f;
    if (B13 != 0.0f) {
        float xn = fsqrtf32(fmul(B13, B13));
        float beta = -copysignf(slapy2f(B12, xn), B12);
        taup = fdiv(fsub(beta, B12), beta);
        float scal = fdiv(1.0f, fsub(B12, beta));
        v2p = fmul(B13, scal);
        e[1] = beta;
        float w2 = fadd(fmul(B23, v2p), B22);
        float w3 = fmul(B33, v2p);
        B22 = fmaf(-taup, w2, B22);
        B32 = fmul(-taup, w3);
        float tmp = fmul(-taup, v2p);
        B23 = fmaf(w2, tmp, B23);
        B33 = fmaf(w3, tmp, B33);
    } else e[1] = B12;
    if (B32 != 0.0f) {
        float xn = fsqrtf32(fmul(B32, B32));
        float beta = -copysignf(slapy2f(B22, xn), B22);
        float tauq = fdiv(fsub(beta, B22), beta);
        float scal = fdiv(1.0f, fsub(B22, beta));
        float v2 = fmul(B32, scal);
        d[2] = beta;
        float w = fadd(fmul(v2, B33), B23);
        B23 = fmaf(-tauq, w, B23);
        float tmp = fmul(-tauq, w);
        B33 = fmaf(v2, tmp, B33);
    } else d[2] = B22;
    e[2] = B23;
    d[3] = B33;

    // ---- sbdsqr with VT = I
    float vt[4][4];
    for (int r = 1; r <= 3; ++r)
        for (int c = 1; c <= 3; ++c) vt[r][c] = (r == c) ? 1.0f : 0.0f;
    bdsqr3f(d, e, vt);

    // ---- sormbr 'P','R','T' via slarf1f
    if (taup != 0.0f) {
        float tmp = fmul(-taup, v2p);
        for (int r = 1; r <= 3; ++r) {
            float w = fadd(fmul(vt[r][3], v2p), vt[r][2]);
            vt[r][2] = fmaf(-taup, w, vt[r][2]);
            vt[r][3] = fmaf(w, tmp, vt[r][3]);
        }
    }

    int im = 1;
    if (d[2] > d[im]) im = 2;
    if (d[3] > d[im]) im = 3;
    grad[t * 3 + 0] = vt[im][1];
    grad[t * 3 + 1] = vt[im][2];
    grad[t * 3 + 2] = vt[im][3];
    mag[t] = fsqrtf32(d[im]);
}

// ===========================================================================
// Kernel 3a (R15 NEW): per-point vote precompute. In the old hist, angles/
// bins/votes were recomputed once per OCCURRENCE as a neighbor (32x per
// point); they depend only on the point's own grad/mag. Compute once here,
// bit-identically, store votes as float4 + packed bins.
// ===========================================================================
__global__ void vote_kernel(const float* __restrict__ grad, const float* __restrict__ mag,
                            float4* __restrict__ votes, int* __restrict__ binsq) {
    int t = blockIdx.x * blockDim.x + threadIdx.x;
    if (t >= BB * NN) return;
    const float r2d = (float)(180.0 / M_PI);

    float gx = grad[t * 3 + 0];
    float gy = grad[t * 3 + 1];
    float gz = grad[t * 3 + 2];
    float m  = mag[t];

    float zen = (float)acos((double)gz);
    float zd  = fmul(zen, r2d);
    float q0  = fdiv(gy, gx);
    float azr = (float)atan((double)q0);
    float ad  = fmul(azr, r2d);

    float a0 = (zd != zd) ? -2147483648.0f : (float)(int)zd;
    float a1 = (ad != ad) ? -2147483648.0f : (float)(int)ad;

    float v1s[2], v2s[2]; int bis[2];
    #pragma unroll
    for (int c = 0; c < 2; ++c) {
        float a = (c == 0) ? a0 : a1;
        if (a < 0.0f) a = fadd(a, 180.0f);
        float tq = fdiv(a, 20.0f);
        float t2 = fsub(tq, 0.5f);
        float fb = floorf(t2);
        float bin = fmodf(fb, 9.0f); if (bin != 0.0f && bin < 0.0f) bin = fadd(bin, 9.0f);
        float b1 = fadd(bin, 1.0f);
        float b1m = fmodf(b1, 9.0f);
        float fc = fmul(20.0f, fadd(b1m, 0.5f));
        float df = fsub(fc, a);
        float rm = fmodf(df, 180.0f); if (rm != 0.0f && rm < 0.0f) rm = fadd(rm, 180.0f);
        v1s[c] = fdiv(fmul(m, rm), 20.0f);
        float sc = fmul(20.0f, fadd(bin, 0.5f));
        float ds = fsub(a, sc);
        float rm2 = fmodf(ds, 180.0f); if (rm2 != 0.0f && rm2 < 0.0f) rm2 = fadd(rm2, 180.0f);
        v2s[c] = fdiv(fmul(m, rm2), 20.0f);
        bis[c] = (int)bin;
    }
    votes[t] = make_float4(v1s[0], v2s[0], v1s[1], v2s[1]);
    binsq[t] = bis[0] | (bis[1] << 8);
}

// ===========================================================================
// Kernel 3b: HOG accumulation from precomputed votes. Identical add order
// (j outer, c inner, h1 then h2) => bit-identical histograms.
// ===========================================================================
__global__ void hist_kernel(const int* __restrict__ idx, const float4* __restrict__ votes,
                            const int* __restrict__ binsq, float* __restrict__ out) {
    int t = blockIdx.x * blockDim.x + threadIdx.x;
    if (t >= BB * NN) return;
    int b = t / NN, n = t % NN;
    const int* id = idx + t * KK;

    float h1[9][2], h2[9][2];
    #pragma unroll
    for (int q = 0; q < 9; ++q) { h1[q][0] = h1[q][1] = 0.f; h2[q][0] = h2[q][1] = 0.f; }

    for (int j = 0; j < KK; ++j) {
        int jj = b * NN + id[j];
        float4 v = votes[jj];
        int bp = binsq[jj];
        int bi0 = bp & 0xFF, bi1 = bp >> 8;
        // c = 0
        int b20 = bi0 + 1; if (b20 >= 9) b20 -= 9;
        h1[bi0][0] = fadd(h1[bi0][0], v.x);
        h2[b20][0] = fadd(h2[b20][0], v.y);
        // c = 1
        int b21 = bi1 + 1; if (b21 >= 9) b21 -= 9;
        h1[bi1][1] = fadd(h1[bi1][1], v.z);
        h2[b21][1] = fadd(h2[b21][1], v.w);
    }

    float* o = out + b * (18 * NN) + n * 18;
    #pragma unroll
    for (int c = 0; c < 2; ++c) {
        float hist[9];
        #pragma unroll
        for (int q = 0; q < 9; ++q) hist[q] = fadd(h1[q][c], h2[q][c]);
        float acc = 0.0f;
        #pragma unroll
        for (int q = 0; q < 9; ++q) acc = fadd(acc, fmul(hist[q], hist[q]));
        float nr = fsqrtf32(acc);
        float den = fmaxf(nr, 1e-12f);
        #pragma unroll
        for (int q = 0; q < 9; ++q) o[q * 2 + c] = fdiv(hist[q], den);
    }
}

// ===========================================================================
extern "C" void kernel_launch(void* const* d_in, const int* in_sizes, int n_in,
                              void* d_out, int out_size, void* d_ws, size_t ws_size,
                              hipStream_t stream) {
    const float* x = (const float*)d_in[0];
    float* out = (float*)d_out;

    char* ws = (char*)d_ws;
    size_t off = 0;
    int* idx = (int*)(ws + off);        off += (size_t)BB * NN * KK * sizeof(int);
    float* d2 = (float*)(ws + off);     off += (size_t)BB * NN * sizeof(float);
    float* grad = (float*)(ws + off);   off += (size_t)BB * NN * 3 * sizeof(float);
    float* mag = (float*)(ws + off);    off += (size_t)BB * NN * sizeof(float);
    float4* votes = (float4*)(ws + off); off += (size_t)BB * NN * sizeof(float4);
    int* binsq = (int*)(ws + off);

    d2_kernel  <<<(BB * NN + 63) / 64, 64, 0, stream>>>(x, d2);
    knn_kernel <<<BB * NN / 4, 256, 0, stream>>>(x, d2, idx);
    eig_kernel <<<(BB * NN + 63) / 64, 64, 0, stream>>>(x, idx, grad, mag);
    vote_kernel<<<(BB * NN + 63) / 64, 64, 0, stream>>>(grad, mag, votes, binsq);
    hist_kernel<<<(BB * NN + 63) / 64, 64, 0, stream>>>(idx, votes, binsq, out);
}

// Round 7
// 182.170 us; speedup vs baseline: 1.9463x; 1.0392x over previous
//
#include <hip/hip_runtime.h>
#include <math.h>

// Problem constants: B=8, N=2048, K=32, 9 bins, width 20.
#define BB 8
#define NN 2048
#define KK 32

// ===========================================================================
// Exactly-rounded f32 helpers (R15): native f32 _rn intrinsics. By Figueroa's
// theorem, (float)((double)a op (double)b) == correctly-rounded f32 op for
// +,-,*,/,sqrt — verified bit-identical on HW in R15 (absmax unchanged).
// ===========================================================================
__device__ __forceinline__ float fadd(float a, float b){ return __fadd_rn(a, b); }
__device__ __forceinline__ float fsub(float a, float b){ return __fsub_rn(a, b); }
__device__ __forceinline__ float fmul(float a, float b){ return __fmul_rn(a, b); }
__device__ __forceinline__ float fdiv(float a, float b){ return __fdiv_rn(a, b); }
__device__ __forceinline__ float fsqrtf32(float a){ return __fsqrt_rn(a); }

// ===========================================================================
// LAPACK 3.12 single-precision helpers, gfortran -ffp-contract=fast model.
// ===========================================================================
__device__ float slapy2f(float x, float y) {
    float xa = fabsf(x), ya = fabsf(y);
    float w = fmaxf(xa, ya), z = fminf(xa, ya);
    if (z == 0.0f) return w;
    float q = fdiv(z, w);
    return fmul(w, fsqrtf32(fmaf(q, q, 1.0f)));
}

__device__ void slartgf(float f, float g, float& c, float& s, float& r) {
    if (g == 0.0f) { c = 1.0f; s = 0.0f; r = f; }
    else if (f == 0.0f) { c = 0.0f; s = copysignf(1.0f, g); r = fabsf(g); }
    else {
        float d = fsqrtf32(fmaf(f, f, fmul(g, g)));
        c = fdiv(fabsf(f), d);
        r = copysignf(d, f);
        s = fdiv(g, r);
    }
}

__device__ void slas2f(float f, float g, float h, float& ssmin, float& ssmax) {
    float fa = fabsf(f), ga = fabsf(g), ha = fabsf(h);
    float fhmn = fminf(fa, ha), fhmx = fmaxf(fa, ha);
    if (fhmn == 0.0f) {
        ssmin = 0.0f;
        if (fhmx == 0.0f) ssmax = ga;
        else {
            float mx = fmaxf(fhmx, ga), mn = fminf(fhmx, ga);
            float q = fdiv(mn, mx);
            ssmax = fmul(mx, fsqrtf32(fmaf(q, q, 1.0f)));
        }
    } else {
        if (ga < fhmx) {
            float as = fadd(1.0f, fdiv(fhmn, fhmx));
            float at = fdiv(fsub(fhmx, fhmn), fhmx);
            float q = fdiv(ga, fhmx); float au = fmul(q, q);
            float c = fdiv(2.0f, fadd(fsqrtf32(fmaf(as, as, au)),
                                      fsqrtf32(fmaf(at, at, au))));
            ssmin = fmul(fhmn, c); ssmax = fdiv(fhmx, c);
        } else {
            float au = fdiv(fhmx, ga);
            if (au == 0.0f) { ssmin = fdiv(fmul(fhmn, fhmx), ga); ssmax = ga; }
            else {
                float as = fadd(1.0f, fdiv(fhmn, fhmx));
                float at = fdiv(fsub(fhmx, fhmn), fhmx);
                float t1 = fmul(as, au), t2 = fmul(at, au);
                float c = fdiv(1.0f, fadd(fsqrtf32(fmaf(t1, t1, 1.0f)),
                                          fsqrtf32(fmaf(t2, t2, 1.0f))));
                ssmin = fmul(fmul(fhmn, c), au); ssmin = fadd(ssmin, ssmin);
                ssmax = fdiv(ga, fadd(c, c));
            }
        }
    }
}

__device__ void slasv2f(float f, float g, float h,
                        float& ssmin, float& ssmax,
                        float& snr, float& csr, float& snl, float& csl) {
    const float eps = 5.9604644775390625e-08f;
    float ft = f, fa = fabsf(f), ht = h, ha = fabsf(h);
    int pmax = 1;
    bool swp = (ha > fa);
    if (swp) { pmax = 3; float t = ft; ft = ht; ht = t; t = fa; fa = ha; ha = t; }
    float gt = g, ga = fabsf(gt);
    float clt = 0.f, crt = 0.f, slt = 0.f, srt = 0.f;
    if (ga == 0.0f) {
        ssmin = ha; ssmax = fa; clt = 1.0f; crt = 1.0f; slt = 0.0f; srt = 0.0f;
    } else {
        bool gasmal = true;
        if (ga > fa) {
            pmax = 2;
            if (fdiv(fa, ga) < eps) {
                gasmal = false;
                ssmax = ga;
                ssmin = (ha > 1.0f) ? fdiv(fa, fdiv(ga, ha)) : fmul(fdiv(fa, ga), ha);
                clt = 1.0f; slt = fdiv(ht, gt); srt = 1.0f; crt = fdiv(ft, gt);
            }
        }
        if (gasmal) {
            float dd = fsub(fa, ha);
            float l = (dd == fa) ? 1.0f : fdiv(dd, fa);
            float mm = fdiv(gt, ft);
            float t = fsub(2.0f, l);
            float m2 = fmul(mm, mm);
            float s = fsqrtf32(fmaf(t, t, m2));
            float r = (l == 0.0f) ? fabsf(mm) : fsqrtf32(fmaf(l, l, m2));
            float a = fmul(0.5f, fadd(s, r));
            ssmin = fdiv(ha, a);
            ssmax = fmul(fa, a);
            if (m2 == 0.0f) {
                t = (l == 0.0f) ? fmul(copysignf(2.0f, ft), copysignf(1.0f, gt))
                                : fadd(fdiv(gt, copysignf(dd, ft)), fdiv(mm, t));
            } else {
                t = fmul(fadd(fdiv(mm, fadd(s, t)), fdiv(mm, fadd(r, l))), fadd(1.0f, a));
            }
            float l2 = fsqrtf32(fmaf(t, t, 4.0f));
            crt = fdiv(2.0f, l2); srt = fdiv(t, l2);
            clt = fdiv(fmaf(srt, mm, crt), a);
            slt = fdiv(fmul(fdiv(ht, ft), srt), a);
        }
    }
    if (swp) { csl = srt; snl = crt; csr = slt; snr = clt; }
    else     { csl = clt; snl = slt; csr = crt; snr = srt; }
    float tsign = 0.0f;
    if (pmax == 1) tsign = fmul(fmul(copysignf(1.f, csr), copysignf(1.f, csl)), copysignf(1.f, f));
    if (pmax == 2) tsign = fmul(fmul(copysignf(1.f, snr), copysignf(1.f, csl)), copysignf(1.f, g));
    if (pmax == 3) tsign = fmul(fmul(copysignf(1.f, snr), copysignf(1.f, snl)), copysignf(1.f, h));
    ssmax = copysignf(fabsf(ssmax), tsign);
    ssmin = copysignf(fabsf(ssmin), fmul(tsign, fmul(copysignf(1.f, f), copysignf(1.f, h))));
}

// slasr 'L','V' rotation on vt rows lo,hi (1-indexed), fma-contracted
__device__ __forceinline__ void rot_rowsf(float vt[4][4], int lo, int hi, float cc, float ss) {
    #pragma unroll
    for (int c = 1; c <= 3; ++c) {
        float t = vt[hi][c];
        vt[hi][c] = fmaf(cc, t, -fmul(ss, vt[lo][c]));
        vt[lo][c] = fmaf(ss, t, fmul(cc, vt[lo][c]));
    }
}

// sbdsqr for n=3 upper bidiagonal. R9: idir2-shifted VT pairing REVERTED to
// (COSL, -SINL) — R8's (COSR,-SINR) regressed 0.0898->0.6455, proving the
// original Fortran reading (2nd slartg = VT side in bottom-up sweeps) right.
__device__ void bdsqr3f(float* d, float* e, float vt[4][4]) {
    const float eps  = 5.9604644775390625e-08f;
    const float unfl = 1.1754943508222875e-38f;
    const int n = 3;
    const float tol = fmul(10.0f, eps);
    float thresh;
    {
        float sminoa = fabsf(d[1]);
        if (sminoa != 0.0f) {
            float mu = sminoa;
            for (int i = 2; i <= n; ++i) {
                mu = fmul(fabsf(d[i]), fdiv(mu, fadd(mu, fabsf(e[i - 1]))));
                sminoa = fminf(sminoa, mu);
                if (sminoa == 0.0f) break;
            }
        }
        sminoa = fdiv(sminoa, fsqrtf32(3.0f));
        thresh = fmaxf(fmul(tol, sminoa), fmul(54.0f, unfl));
    }
    int m = n, iter = 0, oldll = -1, oldm = -1, idir = 0;
    float sminl = 0.0f;
    while (m > 1) {
        if (iter > 54) break;
        float smax = fabsf(d[m]);
        int ll = 0; bool split = false;
        for (int lll = 1; lll <= m - 1; ++lll) {
            int l2 = m - lll;
            float abss = fabsf(d[l2]), abse = fabsf(e[l2]);
            if (abse <= thresh) { ll = l2; split = true; break; }
            smax = fmaxf(smax, fmaxf(abss, abse));
        }
        if (split) {
            e[ll] = 0.0f;
            if (ll == m - 1) { m = m - 1; continue; }
            ll = ll + 1;
        } else ll = 1;
        if (ll == m - 1) {
            float sigmn, sigmx, sinr, cosr, sinl, cosl;
            slasv2f(d[m - 1], e[m - 1], d[m], sigmn, sigmx, sinr, cosr, sinl, cosl);
            d[m - 1] = sigmx; e[m - 1] = 0.0f; d[m] = sigmn;
            #pragma unroll
            for (int c = 1; c <= 3; ++c) {
                float t = fmaf(cosr, vt[m - 1][c], fmul(sinr, vt[m][c]));
                vt[m][c] = fmaf(cosr, vt[m][c], -fmul(sinr, vt[m - 1][c]));
                vt[m - 1][c] = t;
            }
            m -= 2; continue;
        }
        if (ll > oldm || m < oldll)
            idir = (fabsf(d[ll]) >= fabsf(d[m])) ? 1 : 2;
        bool deflated = false;
        if (idir == 1) {
            if (fabsf(e[m - 1]) <= fmul(tol, fabsf(d[m]))) { e[m - 1] = 0.0f; continue; }
            float mu = fabsf(d[ll]); sminl = mu;
            for (int lll = ll; lll <= m - 1; ++lll) {
                if (fabsf(e[lll]) <= fmul(tol, mu)) { e[lll] = 0.0f; deflated = true; break; }
                mu = fmul(fabsf(d[lll + 1]), fdiv(mu, fadd(mu, fabsf(e[lll]))));
                sminl = fminf(sminl, mu);
            }
        } else {
            if (fabsf(e[ll]) <= fmul(tol, fabsf(d[ll]))) { e[ll] = 0.0f; continue; }
            float mu = fabsf(d[m]); sminl = mu;
            for (int lll = m - 1; lll >= ll; --lll) {
                if (fabsf(e[lll]) <= fmul(tol, mu)) { e[lll] = 0.0f; deflated = true; break; }
                mu = fmul(fabsf(d[lll]), fdiv(mu, fadd(mu, fabsf(e[lll]))));
                sminl = fminf(sminl, mu);
            }
        }
        if (deflated) continue;
        oldll = ll; oldm = m;
        float shift = 0.0f, rr;
        if (!(fmul(fmul(3.0f, tol), fdiv(sminl, smax)) <= fmaxf(eps, fmul(0.01f, tol)))) {
            float sll;
            if (idir == 1) { sll = fabsf(d[ll]); slas2f(d[m - 1], e[m - 1], d[m], shift, rr); }
            else           { sll = fabsf(d[m]);  slas2f(d[ll], e[ll], d[ll + 1], shift, rr); }
            if (sll > 0.0f) { float q = fdiv(shift, sll); if (fmul(q, q) < eps) shift = 0.0f; }
        }
        iter += m - ll;
        float wc[4], ws[4];
        if (shift == 0.0f) {
            if (idir == 1) {
                float cs = 1.0f, oldcs = 1.0f, sn = 0.0f, oldsn = 0.0f, r2;
                for (int i = ll; i <= m - 1; ++i) {
                    slartgf(fmul(d[i], cs), e[i], cs, sn, r2);
                    if (i > ll) e[i - 1] = fmul(oldsn, r2);
                    slartgf(fmul(oldcs, r2), fmul(d[i + 1], sn), oldcs, oldsn, d[i]);
                    wc[i - ll + 1] = cs; ws[i - ll + 1] = sn;
                }
                float h = fmul(d[m], cs); d[m] = fmul(h, oldcs); e[m - 1] = fmul(h, oldsn);
                if (fabsf(e[m - 1]) <= thresh) e[m - 1] = 0.0f;
                for (int j = 1; j <= m - ll; ++j) rot_rowsf(vt, ll + j - 1, ll + j, wc[j], ws[j]);
            } else {
                float cs = 1.0f, oldcs = 1.0f, sn = 0.0f, oldsn = 0.0f, r2;
                for (int i = m; i >= ll + 1; --i) {
                    slartgf(fmul(d[i], cs), e[i - 1], cs, sn, r2);
                    if (i < m) e[i] = fmul(oldsn, r2);
                    slartgf(fmul(oldcs, r2), fmul(d[i - 1], sn), oldcs, oldsn, d[i]);
                    wc[i - ll] = oldcs; ws[i - ll] = -oldsn;
                }
                float h = fmul(d[ll], cs); d[ll] = fmul(h, oldcs); e[ll] = fmul(h, oldsn);
                if (fabsf(e[ll]) <= thresh) e[ll] = 0.0f;
                for (int j = m - ll; j >= 1; --j) rot_rowsf(vt, ll + j - 1, ll + j, wc[j], ws[j]);
            }
        } else {
            if (idir == 1) {
                float fq = fmul(fsub(fabsf(d[ll]), shift),
                                fadd(copysignf(1.0f, d[ll]), fdiv(shift, d[ll])));
                float g = e[ll], cosr, sinr, cosl, sinl, r2;
                for (int i = ll; i <= m - 1; ++i) {
                    slartgf(fq, g, cosr, sinr, r2);
                    if (i > ll) e[i - 1] = r2;
                    float di = d[i], ei = e[i], dip = d[i + 1];
                    fq         = fmaf(cosr, di, fmul(sinr, ei));
                    float ei_n = fmaf(cosr, ei, -fmul(sinr, di));
                    g = fmul(sinr, dip);
                    float dip_n = fmul(cosr, dip);
                    slartgf(fq, g, cosl, sinl, r2);
                    d[i] = r2;
                    fq       = fmaf(cosl, ei_n, fmul(sinl, dip_n));
                    d[i + 1] = fmaf(cosl, dip_n, -fmul(sinl, ei_n));
                    e[i] = ei_n;
                    if (i < m - 1) { g = fmul(sinl, e[i + 1]); e[i + 1] = fmul(cosl, e[i + 1]); }
                    wc[i - ll + 1] = cosr; ws[i - ll + 1] = sinr;
                }
                e[m - 1] = fq;
                if (fabsf(e[m - 1]) <= thresh) e[m - 1] = 0.0f;
                for (int j = 1; j <= m - ll; ++j) rot_rowsf(vt, ll + j - 1, ll + j, wc[j], ws[j]);
            } else {
                float fq = fmul(fsub(fabsf(d[m]), shift),
                                fadd(copysignf(1.0f, d[m]), fdiv(shift, d[m])));
                float g = e[m - 1], cosr, sinr, cosl, sinl, r2;
                for (int i = m; i >= ll + 1; --i) {
                    slartgf(fq, g, cosr, sinr, r2);
                    if (i < m) e[i] = r2;
                    float di = d[i], em = e[i - 1], dim = d[i - 1];
                    fq         = fmaf(cosr, di, fmul(sinr, em));
                    float em_n = fmaf(cosr, em, -fmul(sinr, di));
                    g = fmul(sinr, dim);
                    float dim_n = fmul(cosr, dim);
                    slartgf(fq, g, cosl, sinl, r2);
                    d[i] = r2;
                    fq       = fmaf(cosl, em_n, fmul(sinl, dim_n));
                    d[i - 1] = fmaf(cosl, dim_n, -fmul(sinl, em_n));
                    e[i - 1] = em_n;
                    if (i > ll + 1) { g = fmul(sinl, e[i - 2]); e[i - 2] = fmul(cosl, e[i - 2]); }
                    wc[i - ll] = cosl; ws[i - ll] = -sinl;   // REVERTED (correct per R8 regression)
                }
                e[ll] = fq;
                if (fabsf(e[ll]) <= thresh) e[ll] = 0.0f;
                for (int j = m - ll; j >= 1; --j) rot_rowsf(vt, ll + j - 1, ll + j, wc[j], ws[j]);
            }
        }
    }
    for (int i = 1; i <= n; ++i) {
        if (d[i] < 0.0f) {
            d[i] = -d[i];
            for (int c = 1; c <= 3; ++c) vt[i][c] = -vt[i][c];
        }
    }
    for (int i = 1; i <= n - 1; ++i) {
        int isub = 1; float smin2 = d[1];
        for (int j = 2; j <= n + 1 - i; ++j)
            if (d[j] <= smin2) { isub = j; smin2 = d[j]; }
        int tgt = n + 1 - i;
        if (isub != tgt) {
            d[isub] = d[tgt]; d[tgt] = smin2;
            for (int c = 1; c <= 3; ++c) { float t = vt[isub][c]; vt[isub][c] = vt[tgt][c]; vt[tgt][c] = t; }
        }
    }
}

// ===========================================================================
// Kernel 1: KNN — R13 structure (verified 80.6 µs, VGPR 40, VALUBusy ~97%).
// R16: d2 computed inline per lane (identical formula/op order as the old
// d2_kernel => bit-identical); d2 kernel + buffer removed.
// ===========================================================================
__device__ __forceinline__ unsigned int f32_sortable(float f) {
    unsigned int b = __float_as_uint(f);
    return b ^ ((unsigned int)((int)b >> 31) | 0x80000000u);
}
__device__ __forceinline__ float sortable_f32(unsigned int s) {
    unsigned int b = s ^ (~(unsigned int)((int)s >> 31) | 0x80000000u);
    return __uint_as_float(b);
}

template <int CTRL, int RM>
__device__ __forceinline__ unsigned long long dpp_umax64(unsigned long long k) {
    int nhi = __builtin_amdgcn_update_dpp(0, (int)(unsigned int)(k >> 32), CTRL, RM, 0xF, false);
    int nlo = __builtin_amdgcn_update_dpp(0, (int)(unsigned int)k,         CTRL, RM, 0xF, false);
    unsigned long long nk = ((unsigned long long)(unsigned int)nhi << 32) | (unsigned int)nlo;
    return nk > k ? nk : k;
}

// Pop the lane's best remaining candidate from vals (value desc, slot asc),
// clear it, and return the packed u64 merge key. All indices static.
__device__ __forceinline__ unsigned long long pop_best(unsigned int (&vals)[32], int lane) {
    unsigned int m = vals[0];
    #pragma unroll
    for (int s = 1; s < 32; ++s) m = (vals[s] > m) ? vals[s] : m;   // v_max_u32
    int bs = 0;
    #pragma unroll
    for (int s = 31; s >= 0; --s) if (vals[s] == m) bs = s;          // first match
    #pragma unroll
    for (int s = 0; s < 32; ++s) vals[s] = (s == bs) ? 0u : vals[s]; // clear
    int j = bs * 64 + lane;
    return ((unsigned long long)m << 32) | (unsigned int)(2047 - j);
}

__global__ void __launch_bounds__(256) knn_kernel(const float* __restrict__ x,
                                                  int* __restrict__ idx) {
    int lane = threadIdx.x & 63;
    int wid  = threadIdx.x >> 6;
    int row  = blockIdx.x * 4 + wid;
    int b = row / NN, i = row % NN;
    const float* xb  = x  + b * 3 * NN;

    float xi = xb[i], yi = xb[NN + i], zi = xb[2 * NN + i];
    // d2i: same formula/op order as the old d2_kernel => bit-identical
    float d2i = fadd(fadd(fmul(xi, xi), fmul(yi, yi)), fmul(zi, zi));

    // 32 candidates per lane, sortable-u32 encoded, static register indexing.
    unsigned int vals[32];
    #pragma unroll
    for (int s = 0; s < 32; ++s) {
        int j = s * 64 + lane;
        float xj = xb[j], yj = xb[NN + j], zj = xb[2 * NN + j];
        float d2j = fadd(fadd(fmul(xj, xj), fmul(yj, yj)), fmul(zj, zj));
        float dot = fmul(xi, xj);
        dot = fmaf(yi, yj, dot);
        dot = fmaf(zi, zj, dot);
        float v = fsub(fsub(fmul(2.0f, dot), d2i), d2j);
        vals[s] = f32_sortable(v);
    }

    // ---- build the 4-deep lookahead mini-list (named scalars, sorted desc)
    unsigned long long l0 = pop_best(vals, lane);
    unsigned long long l1 = pop_best(vals, lane);
    unsigned long long l2 = pop_best(vals, lane);
    unsigned long long l3 = pop_best(vals, lane);

    int* idxrow = idx + row * KK;
    unsigned int c1v = 0, c2v = 0, c3v = 0, c31v = 0, c32v = 0;
    int c1i = 0, c2i = 0, c3i = 0, c31i = 0, c32i = 0;

    #pragma unroll 1
    for (int t = 0; t < KK + 1; ++t) {      // 33 ranks (32 + boundary probe)
        // rare refill: some lane consumed its whole lookahead (won 4+ times)
        if (__any(l0 == 0ull)) {
            bool need = (l0 == 0ull);
            unsigned int m = vals[0];
            #pragma unroll
            for (int s = 1; s < 32; ++s) m = (vals[s] > m) ? vals[s] : m;
            int bs = 0;
            #pragma unroll
            for (int s = 31; s >= 0; --s) if (vals[s] == m) bs = s;
            #pragma unroll
            for (int s = 0; s < 32; ++s)
                vals[s] = (need && s == bs) ? 0u : vals[s];
            unsigned long long ent = ((unsigned long long)m << 32)
                                   | (unsigned int)(2047 - (bs * 64 + lane));
            l0 = need ? ent : l0;
        }

        // wave argmax of heads, pure-VALU DPP cascade; lane 63 ends global max
        unsigned long long k = l0;
        k = dpp_umax64<0x111, 0xF>(k);   // row_shr:1
        k = dpp_umax64<0x112, 0xF>(k);   // row_shr:2
        k = dpp_umax64<0x114, 0xF>(k);   // row_shr:4
        k = dpp_umax64<0x118, 0xF>(k);   // row_shr:8
        k = dpp_umax64<0x142, 0xA>(k);   // row_bcast:15 -> rows 1,3
        k = dpp_umax64<0x143, 0xC>(k);   // row_bcast:31 -> rows 2,3

        unsigned int wbest = (unsigned int)__builtin_amdgcn_readlane((int)(k >> 32), 63);
        unsigned int wlow  = (unsigned int)__builtin_amdgcn_readlane((int)(k & 0xFFFFFFFFull), 63);
        int wj = 2047 - (int)(wlow & 0x7FFu);

        // winner lane pops its head: shift the 4 named scalars down.
        bool amw = ((unsigned int)l0 == wlow);
        l0 = amw ? l1 : l0;
        l1 = amw ? l2 : l1;
        l2 = amw ? l3 : l2;
        l3 = amw ? 0ull : l3;

        // record: ranks 1,2,3,31,32 are deferred for the near-tie probes
        if (t == 1)           { c1v = wbest;  c1i = wj; }
        else if (t == 2)      { c2v = wbest;  c2i = wj; }
        else if (t == 3)      { c3v = wbest;  c3i = wj; }
        else if (t == KK - 1) { c31v = wbest; c31i = wj; }
        else if (t == KK)     { c32v = wbest; c32i = wj; }
        else if (lane == 0)   idxrow[t] = wj;
    }

    if (lane == 0) {
        const float TIE = 4e-7f;
        float r1  = sortable_f32(c1v),  r2  = sortable_f32(c2v), r3 = sortable_f32(c3v);
        float r31 = sortable_f32(c31v), r32 = sortable_f32(c32v);
        if (fabsf(r1 - r2) < TIE) { int ti = c1i; c1i = c2i; c2i = ti; float tv = r1; r1 = r2; r2 = tv; }
        if (fabsf(r2 - r3) < TIE) { int ti = c2i; c2i = c3i; c3i = ti; float tv = r2; r2 = r3; r3 = tv; }
        idxrow[1] = c1i; idxrow[2] = c2i; idxrow[3] = c3i;
        idxrow[KK - 1] = (fabsf(r31 - r32) < TIE) ? c32i : c31i;
    }
}

// ===========================================================================
// Kernel 2: sgesdd emulation + FUSED vote precompute (R16).
// vote read exactly the values eig wrote (vt[im][*], sqrt(d[im])) — computing
// votes in-register here is bit-identical; grad/mag buffers are eliminated.
// ===========================================================================
__global__ void eig_kernel(const float* __restrict__ x, const int* __restrict__ idx,
                           float4* __restrict__ votes, int* __restrict__ binsq) {
    int t = blockIdx.x * blockDim.x + threadIdx.x;
    if (t >= BB * NN) return;
    int b = t / NN;
    const float* xb = x + b * 3 * NN;
    const int* id = idx + t * KK;

    float A[KK][3];
    float s0 = 0.f, s1 = 0.f, s2 = 0.f;
    #pragma unroll
    for (int j = 0; j < KK; ++j) {
        int n = id[j];
        s0 = fadd(s0, xb[n]); s1 = fadd(s1, xb[NN + n]); s2 = fadd(s2, xb[2 * NN + n]);
    }
    float m0 = fdiv(s0, 32.f), m1 = fdiv(s1, 32.f), m2 = fdiv(s2, 32.f);
    #pragma unroll
    for (int j = 0; j < KK; ++j) {
        int n = id[j];
        A[j][0] = fsub(xb[n], m0);
        A[j][1] = fsub(xb[NN + n], m1);
        A[j][2] = fsub(xb[2 * NN + n], m2);
    }

    // ---- sgeqr2 with slarf1f
    #pragma unroll
    for (int i = 0; i < 3; ++i) {
        float alpha = A[i][i];
        double nacc = 0.0;
        #pragma unroll
        for (int r = i + 1; r < KK; ++r) nacc += (double)A[r][i] * (double)A[r][i];
        float xnorm = (float)sqrt(nacc);
        if (xnorm != 0.0f) {
            float beta = -copysignf(slapy2f(alpha, xnorm), alpha);
            float tau  = fdiv(fsub(beta, alpha), beta);
            float scal = fdiv(1.0f, fsub(alpha, beta));
            #pragma unroll
            for (int r = i + 1; r < KK; ++r) A[r][i] = fmul(A[r][i], scal);
            A[i][i] = beta;
            #pragma unroll
            for (int j = i + 1; j < 3; ++j) {
                float acc = 0.0f;
                #pragma unroll
                for (int r = i + 1; r < KK; ++r) acc = fmaf(A[r][i], A[r][j], acc);
                float w = fadd(acc, A[i][j]);
                A[i][j] = fmaf(-tau, w, A[i][j]);
                float temp = fmul(-tau, w);
                #pragma unroll
                for (int r = i + 1; r < KK; ++r) A[r][j] = fmaf(A[r][i], temp, A[r][j]);
            }
        }
    }
    float B11 = A[0][0], B12 = A[0][1], B13 = A[0][2];
    float B22 = A[1][1], B23 = A[1][2], B33 = A[2][2];

    // ---- sgebd2 with slarf1f
    float d[4], e[3];
    float taup = 0.0f, v2p = 0.0f;
    d[1] = B11;
    float B32 = 0.0f;
    if (B13 != 0.0f) {
        float xn = fsqrtf32(fmul(B13, B13));
        float beta = -copysignf(slapy2f(B12, xn), B12);
        taup = fdiv(fsub(beta, B12), beta);
        float scal = fdiv(1.0f, fsub(B12, beta));
        v2p = fmul(B13, scal);
        e[1] = beta;
        float w2 = fadd(fmul(B23, v2p), B22);
        float w3 = fmul(B33, v2p);
        B22 = fmaf(-taup, w2, B22);
        B32 = fmul(-taup, w3);
        float tmp = fmul(-taup, v2p);
        B23 = fmaf(w2, tmp, B23);
        B33 = fmaf(w3, tmp, B33);
    } else e[1] = B12;
    if (B32 != 0.0f) {
        float xn = fsqrtf32(fmul(B32, B32));
        float beta = -copysignf(slapy2f(B22, xn), B22);
        float tauq = fdiv(fsub(beta, B22), beta);
        float scal = fdiv(1.0f, fsub(B22, beta));
        float v2 = fmul(B32, scal);
        d[2] = beta;
        float w = fadd(fmul(v2, B33), B23);
        B23 = fmaf(-tauq, w, B23);
        float tmp = fmul(-tauq, w);
        B33 = fmaf(v2, tmp, B33);
    } else d[2] = B22;
    e[2] = B23;
    d[3] = B33;

    // ---- sbdsqr with VT = I
    float vt[4][4];
    for (int r = 1; r <= 3; ++r)
        for (int c = 1; c <= 3; ++c) vt[r][c] = (r == c) ? 1.0f : 0.0f;
    bdsqr3f(d, e, vt);

    // ---- sormbr 'P','R','T' via slarf1f
    if (taup != 0.0f) {
        float tmp = fmul(-taup, v2p);
        for (int r = 1; r <= 3; ++r) {
            float w = fadd(fmul(vt[r][3], v2p), vt[r][2]);
            vt[r][2] = fmaf(-taup, w, vt[r][2]);
            vt[r][3] = fmaf(w, tmp, vt[r][3]);
        }
    }

    int im = 1;
    if (d[2] > d[im]) im = 2;
    if (d[3] > d[im]) im = 3;
    float gx = vt[im][1];
    float gy = vt[im][2];
    float gz = vt[im][3];
    float m  = fsqrtf32(d[im]);

    // ---- fused vote precompute (identical ops to the old vote_kernel)
    const float r2d = (float)(180.0 / M_PI);
    float zen = (float)acos((double)gz);
    float zd  = fmul(zen, r2d);
    float q0  = fdiv(gy, gx);
    float azr = (float)atan((double)q0);
    float ad  = fmul(azr, r2d);

    float a0 = (zd != zd) ? -2147483648.0f : (float)(int)zd;
    float a1 = (ad != ad) ? -2147483648.0f : (float)(int)ad;

    float v1s[2], v2s[2]; int bis[2];
    #pragma unroll
    for (int c = 0; c < 2; ++c) {
        float a = (c == 0) ? a0 : a1;
        if (a < 0.0f) a = fadd(a, 180.0f);
        float tq = fdiv(a, 20.0f);
        float t2 = fsub(tq, 0.5f);
        float fb = floorf(t2);
        float bin = fmodf(fb, 9.0f); if (bin != 0.0f && bin < 0.0f) bin = fadd(bin, 9.0f);
        float b1 = fadd(bin, 1.0f);
        float b1m = fmodf(b1, 9.0f);
        float fc = fmul(20.0f, fadd(b1m, 0.5f));
        float df = fsub(fc, a);
        float rm = fmodf(df, 180.0f); if (rm != 0.0f && rm < 0.0f) rm = fadd(rm, 180.0f);
        v1s[c] = fdiv(fmul(m, rm), 20.0f);
        float sc = fmul(20.0f, fadd(bin, 0.5f));
        float ds = fsub(a, sc);
        float rm2 = fmodf(ds, 180.0f); if (rm2 != 0.0f && rm2 < 0.0f) rm2 = fadd(rm2, 180.0f);
        v2s[c] = fdiv(fmul(m, rm2), 20.0f);
        bis[c] = (int)bin;
    }
    votes[t] = make_float4(v1s[0], v2s[0], v1s[1], v2s[1]);
    binsq[t] = bis[0] | (bis[1] << 8);
}

// ===========================================================================
// Kernel 3: HOG accumulation. R16: runtime-indexed h1/h2 arrays (=> scratch,
// 128 dependent scratch RMWs/point with zero TLP) replaced by fully-static
// 9-way predicated accumulation — registers only. Per-bin add order is the
// same j-ascending sequence => bit-identical histograms.
// ===========================================================================
__global__ void hist_kernel(const int* __restrict__ idx, const float4* __restrict__ votes,
                            const int* __restrict__ binsq, float* __restrict__ out) {
    int t = blockIdx.x * blockDim.x + threadIdx.x;
    if (t >= BB * NN) return;
    int b = t / NN, n = t % NN;
    const int* id = idx + t * KK;

    float h1[9][2], h2[9][2];
    #pragma unroll
    for (int q = 0; q < 9; ++q) { h1[q][0] = h1[q][1] = 0.f; h2[q][0] = h2[q][1] = 0.f; }

    for (int j = 0; j < KK; ++j) {
        int jj = b * NN + id[j];
        float4 v = votes[jj];
        int bp = binsq[jj];
        int bi0 = bp & 0xFF, bi1 = bp >> 8;
        int b20 = bi0 + 1; if (b20 >= 9) b20 -= 9;
        int b21 = bi1 + 1; if (b21 >= 9) b21 -= 9;
        #pragma unroll
        for (int q = 0; q < 9; ++q) {
            h1[q][0] = (bi0 == q) ? fadd(h1[q][0], v.x) : h1[q][0];
            h2[q][0] = (b20 == q) ? fadd(h2[q][0], v.y) : h2[q][0];
            h1[q][1] = (bi1 == q) ? fadd(h1[q][1], v.z) : h1[q][1];
            h2[q][1] = (b21 == q) ? fadd(h2[q][1], v.w) : h2[q][1];
        }
    }

    float* o = out + b * (18 * NN) + n * 18;
    #pragma unroll
    for (int c = 0; c < 2; ++c) {
        float hist[9];
        #pragma unroll
        for (int q = 0; q < 9; ++q) hist[q] = fadd(h1[q][c], h2[q][c]);
        float acc = 0.0f;
        #pragma unroll
        for (int q = 0; q < 9; ++q) acc = fadd(acc, fmul(hist[q], hist[q]));
        float nr = fsqrtf32(acc);
        float den = fmaxf(nr, 1e-12f);
        #pragma unroll
        for (int q = 0; q < 9; ++q) o[q * 2 + c] = fdiv(hist[q], den);
    }
}

// ===========================================================================
extern "C" void kernel_launch(void* const* d_in, const int* in_sizes, int n_in,
                              void* d_out, int out_size, void* d_ws, size_t ws_size,
                              hipStream_t stream) {
    const float* x = (const float*)d_in[0];
    float* out = (float*)d_out;

    char* ws = (char*)d_ws;
    size_t off = 0;
    int* idx = (int*)(ws + off);         off += (size_t)BB * NN * KK * sizeof(int);
    float4* votes = (float4*)(ws + off); off += (size_t)BB * NN * sizeof(float4);
    int* binsq = (int*)(ws + off);

    knn_kernel <<<BB * NN / 4, 256, 0, stream>>>(x, idx);
    eig_kernel <<<(BB * NN + 63) / 64, 64, 0, stream>>>(x, idx, votes, binsq);
    hist_kernel<<<(BB * NN + 63) / 64, 64, 0, stream>>>(idx, votes, binsq, out);
}